// Round 2
// baseline (763.040 us; speedup 1.0000x reference)
//
#include <hip/hip_runtime.h>

#define NN 100000
#define NE 1600000
#define MP 100096   // padded node count (multiple of 64, >= 1564*64)

typedef short  short8 __attribute__((ext_vector_type(8)));   // 8 bf16 (4 VGPRs)
typedef float  f32x4  __attribute__((ext_vector_type(4)));

__device__ __forceinline__ unsigned short f2bf(float f){
  unsigned int u = __float_as_uint(f);
  u += 0x7fffu + ((u >> 16) & 1u);          // RNE
  return (unsigned short)(u >> 16);
}
__device__ __forceinline__ float bfl(unsigned int v){ return __uint_as_float((v & 0xffffu) << 16); }
__device__ __forceinline__ float bfh(unsigned int v){ return __uint_as_float(v & 0xffff0000u); }
__device__ __forceinline__ float bf1(unsigned short v){ return __uint_as_float(((unsigned int)v) << 16); }

// ---------------- graph build ----------------

__global__ __launch_bounds__(256) void k_hist(const int* __restrict__ dst, int* __restrict__ deg){
  int e = blockIdx.x * 256 + threadIdx.x;
  if (e < NE) atomicAdd(&deg[dst[e]], 1);
}

__global__ __launch_bounds__(256) void k_scan1(const int* __restrict__ deg, int* __restrict__ rp,
                                               int* __restrict__ part){
  __shared__ int sh[256];
  int t = threadIdx.x;
  int base = blockIdx.x * 1024 + t * 4;
  int v0 = (base     < NN) ? deg[base]     : 0;
  int v1 = (base + 1 < NN) ? deg[base + 1] : 0;
  int v2 = (base + 2 < NN) ? deg[base + 2] : 0;
  int v3 = (base + 3 < NN) ? deg[base + 3] : 0;
  int s = v0 + v1 + v2 + v3;
  sh[t] = s; __syncthreads();
  for (int off = 1; off < 256; off <<= 1){
    int val = sh[t];
    int add = (t >= off) ? sh[t - off] : 0;
    __syncthreads();
    sh[t] = val + add;
    __syncthreads();
  }
  int excl = sh[t] - s;
  if (t == 255) part[blockIdx.x] = sh[255];
  if (base     < NN) rp[base]     = excl;
  if (base + 1 < NN) rp[base + 1] = excl + v0;
  if (base + 2 < NN) rp[base + 2] = excl + v0 + v1;
  if (base + 3 < NN) rp[base + 3] = excl + v0 + v1 + v2;
}

__global__ __launch_bounds__(128) void k_scan2(int* __restrict__ part, int* __restrict__ rp, int nb){
  __shared__ int sh[128];
  int t = threadIdx.x;
  int v = (t < nb) ? part[t] : 0;
  sh[t] = v; __syncthreads();
  for (int off = 1; off < 128; off <<= 1){
    int val = sh[t];
    int add = (t >= off) ? sh[t - off] : 0;
    __syncthreads();
    sh[t] = val + add;
    __syncthreads();
  }
  if (t < nb) part[t] = sh[t] - v;     // exclusive
  if (t == 0) rp[NN] = NE;
}

__global__ __launch_bounds__(256) void k_scan3(int* __restrict__ rp, const int* __restrict__ part,
                                               int* __restrict__ cursor){
  int i = blockIdx.x * 256 + threadIdx.x;
  if (i >= NN) return;
  int v = rp[i] + part[i >> 10];
  rp[i] = v;
  cursor[i] = v;
}

__global__ __launch_bounds__(256) void k_dinv(const int* __restrict__ deg, float* __restrict__ dinv){
  int i = blockIdx.x * 256 + threadIdx.x;
  if (i < NN) dinv[i] = rsqrtf((float)deg[i] + 1.0f);
}

__global__ __launch_bounds__(256) void k_fill(const int* __restrict__ src, const int* __restrict__ dst,
                                              int* __restrict__ cursor, const float* __restrict__ dinv,
                                              int2* __restrict__ cw){
  int e = blockIdx.x * 256 + threadIdx.x;
  if (e >= NE) return;
  int s = src[e], d = dst[e];
  int p = atomicAdd(&cursor[d], 1);
  cw[p] = make_int2(s, __float_as_int(dinv[s]));
}

// ---------------- weight repack to MFMA B-frag order ----------------
// layout: idx = ((ks*(Np/16)+nt)*64 + lane)*8 + j ; element = W[ks*32+(lane>>4)*8+j][nt*16+(lane&15)]

__global__ __launch_bounds__(256) void k_pack(const float* __restrict__ W, unsigned short* __restrict__ dst,
                                              int din, int dout, int Np, int total){
  int idx = blockIdx.x * 256 + threadIdx.x;
  if (idx >= total) return;
  int j = idx & 7;
  int l = (idx >> 3) & 63;
  int f = idx >> 9;
  int ntiles = Np >> 4;
  int nt = f % ntiles;
  int ks = f / ntiles;
  int k = ks * 32 + (l >> 4) * 8 + j;
  int n = nt * 16 + (l & 15);
  float v = (k < din && n < dout) ? W[k * dout + n] : 0.0f;
  dst[idx] = f2bf(v);
}

// ---------------- aggregation: out = dinv[i]*sum_e dinv[src]*row(src) + dinv[i]^2*row(i) (+bias, relu) --------

__global__ __launch_bounds__(256) void k_agg_x(const float* __restrict__ x, const int* __restrict__ rp,
                                               const int2* __restrict__ cw, const float* __restrict__ dinv,
                                               unsigned short* __restrict__ out){
  int g = blockIdx.x * 16 + (threadIdx.x >> 4);
  int c = threadIdx.x & 15;
  if (g >= NN) return;
  int e0 = rp[g], e1 = rp[g + 1];
  float a0 = 0.f, a1 = 0.f, a2 = 0.f;
  for (int e = e0; e < e1; ++e){
    int2 p = cw[e];
    float wt = __int_as_float(p.y);
    const float* xr = x + p.x * 35;
    a0 += wt * xr[c];
    a1 += wt * xr[c + 16];
    if (c < 3) a2 += wt * xr[c + 32];
  }
  float di = dinv[g], d2 = di * di;
  const float* xs = x + g * 35;
  float o0 = a0 * di + d2 * xs[c];
  float o1 = a1 * di + d2 * xs[c + 16];
  float o2 = (c < 3) ? (a2 * di + d2 * xs[c + 32]) : 0.0f;
  unsigned short* orow = out + (size_t)g * 64;
  orow[c]      = f2bf(o0);
  orow[c + 16] = f2bf(o1);
  orow[c + 32] = f2bf(o2);
  orow[c + 48] = 0;
}

template<int SP, int DOUT, bool BR>
__global__ __launch_bounds__(256) void k_agg(const unsigned short* __restrict__ Hin,
                                             unsigned short* __restrict__ Hout,
                                             const int* __restrict__ rp, const int2* __restrict__ cw,
                                             const float* __restrict__ dinv, const float* __restrict__ bias){
  constexpr int U  = SP / 2;    // u32 per row
  constexpr int CH = U / 16;    // chunks per 16-lane group
  int g = blockIdx.x * 16 + (threadIdx.x >> 4);
  int c = threadIdx.x & 15;
  if (g >= NN) return;
  int e0 = rp[g], e1 = rp[g + 1];
  const unsigned int* H32 = (const unsigned int*)Hin;
  float ax[CH], ay[CH];
  #pragma unroll
  for (int ch = 0; ch < CH; ++ch){ ax[ch] = 0.f; ay[ch] = 0.f; }
  for (int e = e0; e < e1; ++e){
    int2 p = cw[e];
    float wt = __int_as_float(p.y);
    const unsigned int* r = H32 + (size_t)p.x * U;
    #pragma unroll
    for (int ch = 0; ch < CH; ++ch){
      unsigned int v = r[ch * 16 + c];
      ax[ch] += wt * bfl(v);
      ay[ch] += wt * bfh(v);
    }
  }
  float di = dinv[g], d2 = di * di;
  const unsigned int* sr = H32 + (size_t)g * U;
  unsigned int* orow = (unsigned int*)Hout + (size_t)g * U;
  #pragma unroll
  for (int ch = 0; ch < CH; ++ch){
    unsigned int sv = sr[ch * 16 + c];
    float fx = ax[ch] * di + d2 * bfl(sv);
    float fy = ay[ch] * di + d2 * bfh(sv);
    if (BR){
      int fidx = 2 * (ch * 16 + c);
      fx += (fidx     < DOUT) ? bias[fidx]     : 0.0f;
      fy += (fidx + 1 < DOUT) ? bias[fidx + 1] : 0.0f;
      fx = fmaxf(fx, 0.0f);
      fy = fmaxf(fy, 0.0f);
    }
    orow[ch * 16 + c] = (unsigned int)f2bf(fx) | ((unsigned int)f2bf(fy) << 16);
  }
}

// ---------------- MFMA matmul: C[M,NP] = A[M,SPA(K)] * Bpacked, optional bias+relu ----------------

template<int K, int NP, int DOUT, int SPA, bool BIAS, bool RELU>
__global__ __launch_bounds__(256) void k_mm(const unsigned short* __restrict__ A,
                                            const unsigned short* __restrict__ Bp,
                                            const float* __restrict__ bias,
                                            unsigned short* __restrict__ C){
  constexpr int NT  = NP / 16;
  constexpr int NT2 = NP / 32;   // tiles per col-wave
  int l   = threadIdx.x & 63;
  int wid = threadIdx.x >> 6;
  int wr = wid >> 1, wc = wid & 1;
  int r0 = blockIdx.x * 64 + wr * 32;
  int n0 = wc * (NP / 2);
  int lr = l & 15, lk = l >> 4;
  const short8* __restrict__ Af = (const short8*)A;
  const short8* __restrict__ Bf = (const short8*)Bp;
  f32x4 acc[2][NT2];
  #pragma unroll
  for (int m = 0; m < 2; ++m)
    #pragma unroll
    for (int t = 0; t < NT2; ++t) acc[m][t] = (f32x4){0.f, 0.f, 0.f, 0.f};

  for (int ks = 0; ks < K / 32; ++ks){
    short8 a0 = Af[((r0      + lr) * SPA + ks * 32 + lk * 8) >> 3];
    short8 a1 = Af[((r0 + 16 + lr) * SPA + ks * 32 + lk * 8) >> 3];
    const short8* bp = Bf + (ks * NT + (n0 >> 4)) * 64 + l;
    #pragma unroll
    for (int t = 0; t < NT2; ++t){
      short8 b = bp[t * 64];
      acc[0][t] = __builtin_amdgcn_mfma_f32_16x16x32_bf16(a0, b, acc[0][t], 0, 0, 0);
      acc[1][t] = __builtin_amdgcn_mfma_f32_16x16x32_bf16(a1, b, acc[1][t], 0, 0, 0);
    }
  }
  // C/D layout: col = lane&15, row = (lane>>4)*4 + j   [m89-verified]
  int rb = lk * 4;
  #pragma unroll
  for (int m = 0; m < 2; ++m){
    #pragma unroll
    for (int t = 0; t < NT2; ++t){
      int col = n0 + t * 16 + lr;
      float bv = 0.0f;
      if (BIAS) bv = (col < DOUT) ? bias[col] : 0.0f;
      #pragma unroll
      for (int j = 0; j < 4; ++j){
        int row = r0 + m * 16 + rb + j;
        if (row < NN){
          float v = acc[m][t][j] + bv;
          if (RELU) v = fmaxf(v, 0.0f);
          C[(size_t)row * NP + col] = f2bf(v);
        }
      }
    }
  }
}

// ---------------- final: mu/logstd matmuls + reparam + log_softmax ----------------

__global__ __launch_bounds__(256) void k_final(const unsigned short* __restrict__ aggh4,
                                               const float* __restrict__ Wmu, const float* __restrict__ bmu,
                                               const float* __restrict__ Wls, const float* __restrict__ bls,
                                               const float* __restrict__ eps, float* __restrict__ out){
  __shared__ float sWmu[42 * 21];
  __shared__ float sWls[42 * 21];
  __shared__ float sbmu[21];
  __shared__ float sbls[21];
  for (int u = threadIdx.x; u < 882; u += 256){ sWmu[u] = Wmu[u]; sWls[u] = Wls[u]; }
  if (threadIdx.x < 21){ sbmu[threadIdx.x] = bmu[threadIdx.x]; sbls[threadIdx.x] = bls[threadIdx.x]; }
  __syncthreads();

  int i = blockIdx.x * 256 + threadIdx.x;
  if (i >= NN) return;

  float mu[21], ls[21];
  #pragma unroll
  for (int j = 0; j < 21; ++j){ mu[j] = sbmu[j]; ls[j] = sbls[j]; }

  const unsigned short* arow = aggh4 + (size_t)i * 64;
  for (int k = 0; k < 42; ++k){
    float ak = bf1(arow[k]);
    #pragma unroll
    for (int j = 0; j < 21; ++j){
      mu[j] += ak * sWmu[k * 21 + j];
      ls[j] += ak * sWls[k * 21 + j];
    }
  }
  float zv[21];
  float mx = -3.4e38f;
  #pragma unroll
  for (int j = 0; j < 21; ++j){
    float l2 = fminf(ls[j], 10.0f);
    float zj = mu[j] + eps[(size_t)i * 21 + j] * __expf(l2);
    zv[j] = zj;
    mx = fmaxf(mx, zj);
  }
  float ssum = 0.f;
  #pragma unroll
  for (int j = 0; j < 21; ++j) ssum += __expf(zv[j] - mx);
  float lse = mx + __logf(ssum);
  #pragma unroll
  for (int j = 0; j < 21; ++j) out[(size_t)i * 21 + j] = zv[j] - lse;
}

// ---------------- launch ----------------

// workspace offsets (bytes, 512-aligned)
constexpr size_t OFF_ROWPTR = 0;           // (NN+1)*4
constexpr size_t OFF_CURSOR = 401408;
constexpr size_t OFF_DEG    = 802816;
constexpr size_t OFF_DINV   = 1204224;
constexpr size_t OFF_PART   = 1605632;
constexpr size_t OFF_CW     = 1606656;     // NE*8 = 12,800,000
constexpr size_t OFF_WB1    = 14406656;    // 45056
constexpr size_t OFF_WB2    = 14451712;    // 135168
constexpr size_t OFF_WB3    = 14586880;    // 36864
constexpr size_t OFF_WB4    = 14623744;    // 12288
constexpr size_t OFF_AGGX   = 14636032;    // MP*64*2  = 12,812,288
constexpr size_t OFF_R1     = 27448320;    // MP*352*2 = 70,467,584 (h1; later t3/h3/t4/h4)
constexpr size_t OFF_T3     = OFF_R1;                    // MP*96*2 = 19,218,432
constexpr size_t OFF_H3     = OFF_R1 + 19218432;
constexpr size_t OFF_T4     = OFF_R1 + 38436864;         // MP*64*2
constexpr size_t OFF_H4     = OFF_R1 + 51249152;
constexpr size_t OFF_T2     = 97915904;    // MP*192*2 = 38,436,864 (later aggh4)
constexpr size_t OFF_AGGH4  = OFF_T2;
constexpr size_t OFF_H2     = 136352768;   // 38,436,864 ; end ~174.8 MB

extern "C" void kernel_launch(void* const* d_in, const int* in_sizes, int n_in,
                              void* d_out, int out_size, void* d_ws, size_t ws_size,
                              hipStream_t stream){
  (void)in_sizes; (void)n_in; (void)out_size; (void)ws_size;
  const float* x    = (const float*)d_in[0];
  const int*   ei   = (const int*)d_in[1];
  const float* eps  = (const float*)d_in[2];
  const float* W1   = (const float*)d_in[3];  const float* b1  = (const float*)d_in[4];
  const float* W2   = (const float*)d_in[5];  const float* b2  = (const float*)d_in[6];
  const float* W3   = (const float*)d_in[7];  const float* b3  = (const float*)d_in[8];
  const float* W4   = (const float*)d_in[9];  const float* b4  = (const float*)d_in[10];
  const float* Wmu  = (const float*)d_in[11]; const float* bmu = (const float*)d_in[12];
  const float* Wls  = (const float*)d_in[13]; const float* bls = (const float*)d_in[14];

  char* ws = (char*)d_ws;
  int*   rowptr = (int*)(ws + OFF_ROWPTR);
  int*   cursor = (int*)(ws + OFF_CURSOR);
  int*   deg    = (int*)(ws + OFF_DEG);
  float* dinv   = (float*)(ws + OFF_DINV);
  int*   part   = (int*)(ws + OFF_PART);
  int2*  cw     = (int2*)(ws + OFF_CW);
  unsigned short* wb1   = (unsigned short*)(ws + OFF_WB1);
  unsigned short* wb2   = (unsigned short*)(ws + OFF_WB2);
  unsigned short* wb3   = (unsigned short*)(ws + OFF_WB3);
  unsigned short* wb4   = (unsigned short*)(ws + OFF_WB4);
  unsigned short* aggx  = (unsigned short*)(ws + OFF_AGGX);
  unsigned short* h1    = (unsigned short*)(ws + OFF_R1);
  unsigned short* t2    = (unsigned short*)(ws + OFF_T2);
  unsigned short* h2    = (unsigned short*)(ws + OFF_H2);
  unsigned short* t3    = (unsigned short*)(ws + OFF_T3);
  unsigned short* h3    = (unsigned short*)(ws + OFF_H3);
  unsigned short* t4    = (unsigned short*)(ws + OFF_T4);
  unsigned short* h4    = (unsigned short*)(ws + OFF_H4);
  unsigned short* aggh4 = (unsigned short*)(ws + OFF_AGGH4);

  const int* src = ei;
  const int* dst = ei + NE;

  hipMemsetAsync(deg, 0, NN * sizeof(int), stream);
  k_hist <<<6250, 256, 0, stream>>>(dst, deg);
  k_scan1<<<98,   256, 0, stream>>>(deg, rowptr, part);
  k_scan2<<<1,    128, 0, stream>>>(part, rowptr, 98);
  k_scan3<<<391,  256, 0, stream>>>(rowptr, part, cursor);
  k_dinv <<<391,  256, 0, stream>>>(deg, dinv);
  k_fill <<<6250, 256, 0, stream>>>(src, dst, cursor, dinv, cw);

  k_pack<<<88,  256, 0, stream>>>(W1, wb1, 35, 336, 352, 22528);
  k_pack<<<264, 256, 0, stream>>>(W2, wb2, 336, 168, 192, 67584);
  k_pack<<<72,  256, 0, stream>>>(W3, wb3, 168, 84, 96, 18432);
  k_pack<<<24,  256, 0, stream>>>(W4, wb4, 84, 42, 64, 6144);

  // conv1: aggregate x (35) first, then matmul 64->352 with bias+relu
  k_agg_x<<<6250, 256, 0, stream>>>(x, rowptr, cw, dinv, aggx);
  k_mm<64, 352, 336, 64, true, true><<<1564, 256, 0, stream>>>(aggx, wb1, b1, h1);

  // conv2: matmul 352->192, then aggregate with bias+relu
  k_mm<352, 192, 168, 352, false, false><<<1564, 256, 0, stream>>>(h1, wb2, nullptr, t2);
  k_agg<192, 168, true><<<6250, 256, 0, stream>>>(t2, h2, rowptr, cw, dinv, b2);

  // conv3
  k_mm<192, 96, 84, 192, false, false><<<1564, 256, 0, stream>>>(h2, wb3, nullptr, t3);
  k_agg<96, 84, true><<<6250, 256, 0, stream>>>(t3, h3, rowptr, cw, dinv, b3);

  // conv4
  k_mm<96, 64, 42, 96, false, false><<<1564, 256, 0, stream>>>(h3, wb4, nullptr, t4);
  k_agg<64, 42, true><<<6250, 256, 0, stream>>>(t4, h4, rowptr, cw, dinv, b4);

  // shared aggregation for mu/logstd heads
  k_agg<64, 42, false><<<6250, 256, 0, stream>>>(h4, aggh4, rowptr, cw, dinv, nullptr);

  k_final<<<391, 256, 0, stream>>>(aggh4, Wmu, bmu, Wls, bls, eps, (float*)d_out);
}

// Round 3
// 728.270 us; speedup vs baseline: 1.0477x; 1.0477x over previous
//
#include <hip/hip_runtime.h>

#define NN 100000
#define NE 1600000
#define MP 100096   // padded node count (multiple of 64, >= 1564*64)
#define NB 782      // ceil(NN/128) buckets of 128 nodes
#define CHUNK 8192  // edges per bin1 block

typedef short  short8 __attribute__((ext_vector_type(8)));   // 8 bf16 (4 VGPRs)
typedef float  f32x4  __attribute__((ext_vector_type(4)));

__device__ __forceinline__ unsigned short f2bf(float f){
  unsigned int u = __float_as_uint(f);
  u += 0x7fffu + ((u >> 16) & 1u);          // RNE
  return (unsigned short)(u >> 16);
}
__device__ __forceinline__ float bfl(unsigned int v){ return __uint_as_float((v & 0xffffu) << 16); }
__device__ __forceinline__ float bfh(unsigned int v){ return __uint_as_float(v & 0xffff0000u); }
__device__ __forceinline__ float bf1(unsigned short v){ return __uint_as_float(((unsigned int)v) << 16); }

// ---------------- graph build ----------------

__global__ __launch_bounds__(256) void k_hist(const int* __restrict__ dst, int* __restrict__ deg){
  int e = blockIdx.x * 256 + threadIdx.x;
  if (e < NE) atomicAdd(&deg[dst[e]], 1);
}

__global__ __launch_bounds__(256) void k_scan1(const int* __restrict__ deg, int* __restrict__ rp,
                                               int* __restrict__ part){
  __shared__ int sh[256];
  int t = threadIdx.x;
  int base = blockIdx.x * 1024 + t * 4;
  int v0 = (base     < NN) ? deg[base]     : 0;
  int v1 = (base + 1 < NN) ? deg[base + 1] : 0;
  int v2 = (base + 2 < NN) ? deg[base + 2] : 0;
  int v3 = (base + 3 < NN) ? deg[base + 3] : 0;
  int s = v0 + v1 + v2 + v3;
  sh[t] = s; __syncthreads();
  for (int off = 1; off < 256; off <<= 1){
    int val = sh[t];
    int add = (t >= off) ? sh[t - off] : 0;
    __syncthreads();
    sh[t] = val + add;
    __syncthreads();
  }
  int excl = sh[t] - s;
  if (t == 255) part[blockIdx.x] = sh[255];
  if (base     < NN) rp[base]     = excl;
  if (base + 1 < NN) rp[base + 1] = excl + v0;
  if (base + 2 < NN) rp[base + 2] = excl + v0 + v1;
  if (base + 3 < NN) rp[base + 3] = excl + v0 + v1 + v2;
}

__global__ __launch_bounds__(128) void k_scan2(int* __restrict__ part, int* __restrict__ rp, int nb){
  __shared__ int sh[128];
  int t = threadIdx.x;
  int v = (t < nb) ? part[t] : 0;
  sh[t] = v; __syncthreads();
  for (int off = 1; off < 128; off <<= 1){
    int val = sh[t];
    int add = (t >= off) ? sh[t - off] : 0;
    __syncthreads();
    sh[t] = val + add;
    __syncthreads();
  }
  if (t < nb) part[t] = sh[t] - v;     // exclusive
  if (t == 0) rp[NN] = NE;
}

__global__ __launch_bounds__(256) void k_scan3(int* __restrict__ rp, const int* __restrict__ part){
  int i = blockIdx.x * 256 + threadIdx.x;
  if (i < NN) rp[i] += part[i >> 10];
}

__global__ __launch_bounds__(256) void k_dinv(const int* __restrict__ deg, float* __restrict__ dinv){
  int i = blockIdx.x * 256 + threadIdx.x;
  if (i < NN) dinv[i] = rsqrtf((float)deg[i] + 1.0f);
}

__global__ __launch_bounds__(256) void k_binit(const int* __restrict__ rp, int* __restrict__ bcur){
  int b = blockIdx.x * 256 + threadIdx.x;
  if (b < NB) bcur[b] = rp[min(b << 7, NN)];
}

// Phase 1: bucket-sort edges into tmp (bucket = dst>>7). Per-block contiguous
// reservations => burst writes assembled into full lines in one XCD's L2.
__global__ __launch_bounds__(256) void k_bin1(const int* __restrict__ src, const int* __restrict__ dst,
                                              int* __restrict__ bcur, int2* __restrict__ tmp){
  __shared__ int cnt[NB];
  __shared__ int base[NB];
  __shared__ int pos[NB];
  int t = threadIdx.x;
  int e0 = blockIdx.x * CHUNK;
  int e1 = min(e0 + CHUNK, NE);
  for (int i = t; i < NB; i += 256){ cnt[i] = 0; pos[i] = 0; }
  __syncthreads();
  for (int e = e0 + t; e < e1; e += 256)
    atomicAdd(&cnt[dst[e] >> 7], 1);
  __syncthreads();
  for (int i = t; i < NB; i += 256){
    int c = cnt[i];
    base[i] = (c > 0) ? atomicAdd(&bcur[i], c) : 0;
  }
  __syncthreads();
  for (int e = e0 + t; e < e1; e += 256){
    int s = src[e], d = dst[e];
    int b = d >> 7;
    int p = base[b] + atomicAdd(&pos[b], 1);
    tmp[p] = make_int2(s, d);
  }
}

// Phase 2: within each bucket, place edges at final CSR slots. Per-node
// cursors in LDS (no global atomics); writes confined to the bucket's ~8KB
// window of cw => full-line evictions.
__global__ __launch_bounds__(256) void k_bin2(const int* __restrict__ rp, const int2* __restrict__ tmp,
                                              int* __restrict__ cw){
  __shared__ int cur[128];
  int b = blockIdx.x;
  int n0 = b << 7;
  int n1 = min(n0 + 128, NN);
  int t = threadIdx.x;
  int E0 = rp[n0], E1 = rp[n1];
  if (t < 128){
    int n = n0 + t;
    cur[t] = (n < NN) ? rp[n] : 0;
  }
  __syncthreads();
  for (int e = E0 + t; e < E1; e += 256){
    int2 p = tmp[e];
    int slot = atomicAdd(&cur[p.y - n0], 1);
    cw[slot] = p.x;
  }
}

// ---------------- weight repack to MFMA B-frag order ----------------
// layout: idx = ((ks*(Np/16)+nt)*64 + lane)*8 + j ; element = W[ks*32+(lane>>4)*8+j][nt*16+(lane&15)]

__global__ __launch_bounds__(256) void k_pack(const float* __restrict__ W, unsigned short* __restrict__ dst,
                                              int din, int dout, int Np, int total){
  int idx = blockIdx.x * 256 + threadIdx.x;
  if (idx >= total) return;
  int j = idx & 7;
  int l = (idx >> 3) & 63;
  int f = idx >> 9;
  int ntiles = Np >> 4;
  int nt = f % ntiles;
  int ks = f / ntiles;
  int k = ks * 32 + (l >> 4) * 8 + j;
  int n = nt * 16 + (l & 15);
  float v = (k < din && n < dout) ? W[k * dout + n] : 0.0f;
  dst[idx] = f2bf(v);
}

// ---------------- prescale conv1 input: gx = dinv*x, bf16, 64-pad ----------------

__global__ __launch_bounds__(256) void k_gx(const float* __restrict__ x, const float* __restrict__ dinv,
                                            unsigned int* __restrict__ gx){
  int idx = blockIdx.x * 256 + threadIdx.x;   // NN*32 u32 outputs
  if (idx >= NN * 32) return;
  int row = idx >> 5;
  int cu  = idx & 31;
  float di = dinv[row];
  int c0 = 2 * cu, c1 = 2 * cu + 1;
  float v0 = (c0 < 35) ? x[row * 35 + c0] * di : 0.0f;
  float v1 = (c1 < 35) ? x[row * 35 + c1] * di : 0.0f;
  gx[idx] = (unsigned int)f2bf(v0) | ((unsigned int)f2bf(v1) << 16);
}

// ---------------- aggregation: core = dinv[i]*(g[i] + sum_{j in N(i)} g[j]) ----------------
// MODE 0: out = core ; MODE 1: out = relu(core + b) ; MODE 2: out = dinv*relu(core + b)

template<int SP, int DOUT, int MODE>
__global__ __launch_bounds__(256) void k_agg(const unsigned short* __restrict__ Hin,
                                             unsigned short* __restrict__ Hout,
                                             const int* __restrict__ rp, const int* __restrict__ cw,
                                             const float* __restrict__ dinv, const float* __restrict__ bias){
  constexpr int U  = SP / 2;    // u32 per row
  constexpr int CH = U / 16;    // chunks per 16-lane group
  int g = blockIdx.x * 16 + (threadIdx.x >> 4);
  int c = threadIdx.x & 15;
  if (g >= NN) return;
  int e0 = rp[g], e1 = rp[g + 1];
  const unsigned int* H32 = (const unsigned int*)Hin;
  float ax[CH], ay[CH];
  // init with self term g[i]
  const unsigned int* sr = H32 + (size_t)g * U;
  #pragma unroll
  for (int ch = 0; ch < CH; ++ch){
    unsigned int sv = sr[ch * 16 + c];
    ax[ch] = bfl(sv);
    ay[ch] = bfh(sv);
  }
  for (int e = e0; e < e1; ++e){
    int s = cw[e];
    const unsigned int* r = H32 + (size_t)s * U;
    #pragma unroll
    for (int ch = 0; ch < CH; ++ch){
      unsigned int v = r[ch * 16 + c];
      ax[ch] += bfl(v);
      ay[ch] += bfh(v);
    }
  }
  float di = dinv[g];
  unsigned int* orow = (unsigned int*)Hout + (size_t)g * U;
  #pragma unroll
  for (int ch = 0; ch < CH; ++ch){
    float fx = ax[ch] * di;
    float fy = ay[ch] * di;
    if (MODE >= 1){
      int fidx = 2 * (ch * 16 + c);
      fx += (fidx     < DOUT) ? bias[fidx]     : 0.0f;
      fy += (fidx + 1 < DOUT) ? bias[fidx + 1] : 0.0f;
      fx = fmaxf(fx, 0.0f);
      fy = fmaxf(fy, 0.0f);
      if (MODE == 2){ fx *= di; fy *= di; }
    }
    orow[ch * 16 + c] = (unsigned int)f2bf(fx) | ((unsigned int)f2bf(fy) << 16);
  }
}

// ---------------- MFMA matmul: C[M,NP] = A[M,SPA(K)] * Bpacked ----------------
// EPI 0: bias+relu ; EPI 1: scale by dinv[row]

template<int K, int NP, int DOUT, int SPA, int EPI>
__global__ __launch_bounds__(256) void k_mm(const unsigned short* __restrict__ A,
                                            const unsigned short* __restrict__ Bp,
                                            const float* __restrict__ bias,
                                            const float* __restrict__ dinv,
                                            unsigned short* __restrict__ C){
  constexpr int NT  = NP / 16;
  constexpr int NT2 = NP / 32;   // tiles per col-wave
  int l   = threadIdx.x & 63;
  int wid = threadIdx.x >> 6;
  int wr = wid >> 1, wc = wid & 1;
  int r0 = blockIdx.x * 64 + wr * 32;
  int n0 = wc * (NP / 2);
  int lr = l & 15, lk = l >> 4;
  const short8* __restrict__ Af = (const short8*)A;
  const short8* __restrict__ Bf = (const short8*)Bp;
  f32x4 acc[2][NT2];
  #pragma unroll
  for (int m = 0; m < 2; ++m)
    #pragma unroll
    for (int t = 0; t < NT2; ++t) acc[m][t] = (f32x4){0.f, 0.f, 0.f, 0.f};

  for (int ks = 0; ks < K / 32; ++ks){
    short8 a0 = Af[((r0      + lr) * SPA + ks * 32 + lk * 8) >> 3];
    short8 a1 = Af[((r0 + 16 + lr) * SPA + ks * 32 + lk * 8) >> 3];
    const short8* bp = Bf + (ks * NT + (n0 >> 4)) * 64 + l;
    #pragma unroll
    for (int t = 0; t < NT2; ++t){
      short8 b = bp[t * 64];
      acc[0][t] = __builtin_amdgcn_mfma_f32_16x16x32_bf16(a0, b, acc[0][t], 0, 0, 0);
      acc[1][t] = __builtin_amdgcn_mfma_f32_16x16x32_bf16(a1, b, acc[1][t], 0, 0, 0);
    }
  }
  // C/D layout: col = lane&15, row = (lane>>4)*4 + j   [m89-verified]
  int rb = lk * 4;
  #pragma unroll
  for (int m = 0; m < 2; ++m){
    #pragma unroll
    for (int t = 0; t < NT2; ++t){
      int col = n0 + t * 16 + lr;
      float bv = 0.0f;
      if (EPI == 0) bv = (col < DOUT) ? bias[col] : 0.0f;
      #pragma unroll
      for (int j = 0; j < 4; ++j){
        int row = r0 + m * 16 + rb + j;
        if (row < NN){
          float v = acc[m][t][j];
          if (EPI == 0) v = fmaxf(v + bv, 0.0f);
          else          v = v * dinv[row];
          C[(size_t)row * NP + col] = f2bf(v);
        }
      }
    }
  }
}

// ---------------- final: mu/logstd matmuls + reparam + log_softmax ----------------

__global__ __launch_bounds__(256) void k_final(const unsigned short* __restrict__ aggh4,
                                               const float* __restrict__ Wmu, const float* __restrict__ bmu,
                                               const float* __restrict__ Wls, const float* __restrict__ bls,
                                               const float* __restrict__ eps, float* __restrict__ out){
  __shared__ float sWmu[42 * 21];
  __shared__ float sWls[42 * 21];
  __shared__ float sbmu[21];
  __shared__ float sbls[21];
  for (int u = threadIdx.x; u < 882; u += 256){ sWmu[u] = Wmu[u]; sWls[u] = Wls[u]; }
  if (threadIdx.x < 21){ sbmu[threadIdx.x] = bmu[threadIdx.x]; sbls[threadIdx.x] = bls[threadIdx.x]; }
  __syncthreads();

  int i = blockIdx.x * 256 + threadIdx.x;
  if (i >= NN) return;

  float mu[21], ls[21];
  #pragma unroll
  for (int j = 0; j < 21; ++j){ mu[j] = sbmu[j]; ls[j] = sbls[j]; }

  const unsigned short* arow = aggh4 + (size_t)i * 64;
  for (int k = 0; k < 42; ++k){
    float ak = bf1(arow[k]);
    #pragma unroll
    for (int j = 0; j < 21; ++j){
      mu[j] += ak * sWmu[k * 21 + j];
      ls[j] += ak * sWls[k * 21 + j];
    }
  }
  float zv[21];
  float mx = -3.4e38f;
  #pragma unroll
  for (int j = 0; j < 21; ++j){
    float l2 = fminf(ls[j], 10.0f);
    float zj = mu[j] + eps[(size_t)i * 21 + j] * __expf(l2);
    zv[j] = zj;
    mx = fmaxf(mx, zj);
  }
  float ssum = 0.f;
  #pragma unroll
  for (int j = 0; j < 21; ++j) ssum += __expf(zv[j] - mx);
  float lse = mx + __logf(ssum);
  #pragma unroll
  for (int j = 0; j < 21; ++j) out[(size_t)i * 21 + j] = zv[j] - lse;
}

// ---------------- workspace layout (bytes, 512-aligned) ----------------

constexpr size_t OFF_ROWPTR = 0;            // (NN+1)*4
constexpr size_t OFF_DEG    = 400896;
constexpr size_t OFF_DINV   = 801280;
constexpr size_t OFF_PART   = 1201664;
constexpr size_t OFF_BCUR   = 1202176;
constexpr size_t OFF_CW     = 1205760;      // NE*4 = 6,400,000
constexpr size_t OFF_TMP    = 7606272;      // NE*8 = 12,800,000
constexpr size_t OFF_WB1    = 20406784;     // 45,056
constexpr size_t OFF_WB2    = 20452352;     // 135,168
constexpr size_t OFF_WB3    = 20588032;     // 36,864
constexpr size_t OFF_WB4    = 20625408;     // 12,288
constexpr size_t OFF_GX     = 20638208;     // MP*64*2 = 12,812,288 (aggh4 reuses)
constexpr size_t OFF_AGGX   = 33451008;     // 12,812,288
constexpr size_t OFF_H1     = 46263808;     // MP*352*2 = 70,467,584 (h2 reuses)
constexpr size_t OFF_H2     = OFF_H1;       // 38,436,864 (h1 dead after mm2)
constexpr size_t OFF_P3     = 84701184;     // MP*96*2 = 19,218,432
constexpr size_t OFF_H3     = 103920128;    // 19,218,432
constexpr size_t OFF_P4     = 123139072;    // MP*64*2 = 12,812,288
constexpr size_t OFF_Q4     = 135951872;    // 12,812,288 ; ends 148,764,160
constexpr size_t OFF_P2     = 116731904;    // MP*192*2 = 38,436,864 ; ends 155,168,768
constexpr size_t OFF_AGGH4  = OFF_GX;       // gx dead after agg1

extern "C" void kernel_launch(void* const* d_in, const int* in_sizes, int n_in,
                              void* d_out, int out_size, void* d_ws, size_t ws_size,
                              hipStream_t stream){
  (void)in_sizes; (void)n_in; (void)out_size; (void)ws_size;
  const float* x    = (const float*)d_in[0];
  const int*   ei   = (const int*)d_in[1];
  const float* eps  = (const float*)d_in[2];
  const float* W1   = (const float*)d_in[3];  const float* b1  = (const float*)d_in[4];
  const float* W2   = (const float*)d_in[5];  const float* b2  = (const float*)d_in[6];
  const float* W3   = (const float*)d_in[7];  const float* b3  = (const float*)d_in[8];
  const float* W4   = (const float*)d_in[9];  const float* b4  = (const float*)d_in[10];
  const float* Wmu  = (const float*)d_in[11]; const float* bmu = (const float*)d_in[12];
  const float* Wls  = (const float*)d_in[13]; const float* bls = (const float*)d_in[14];

  char* ws = (char*)d_ws;
  int*   rowptr = (int*)(ws + OFF_ROWPTR);
  int*   deg    = (int*)(ws + OFF_DEG);
  float* dinv   = (float*)(ws + OFF_DINV);
  int*   part   = (int*)(ws + OFF_PART);
  int*   bcur   = (int*)(ws + OFF_BCUR);
  int*   cw     = (int*)(ws + OFF_CW);
  int2*  tmp    = (int2*)(ws + OFF_TMP);
  unsigned short* wb1   = (unsigned short*)(ws + OFF_WB1);
  unsigned short* wb2   = (unsigned short*)(ws + OFF_WB2);
  unsigned short* wb3   = (unsigned short*)(ws + OFF_WB3);
  unsigned short* wb4   = (unsigned short*)(ws + OFF_WB4);
  unsigned short* gx    = (unsigned short*)(ws + OFF_GX);
  unsigned short* aggx  = (unsigned short*)(ws + OFF_AGGX);
  unsigned short* h1    = (unsigned short*)(ws + OFF_H1);
  unsigned short* p2    = (unsigned short*)(ws + OFF_P2);
  unsigned short* h2    = (unsigned short*)(ws + OFF_H2);
  unsigned short* p3    = (unsigned short*)(ws + OFF_P3);
  unsigned short* h3    = (unsigned short*)(ws + OFF_H3);
  unsigned short* p4    = (unsigned short*)(ws + OFF_P4);
  unsigned short* q4    = (unsigned short*)(ws + OFF_Q4);
  unsigned short* aggh4 = (unsigned short*)(ws + OFF_AGGH4);

  const int* src = ei;
  const int* dst = ei + NE;

  hipMemsetAsync(deg, 0, NN * sizeof(int), stream);
  k_hist <<<6250, 256, 0, stream>>>(dst, deg);
  k_scan1<<<98,   256, 0, stream>>>(deg, rowptr, part);
  k_scan2<<<1,    128, 0, stream>>>(part, rowptr, 98);
  k_scan3<<<391,  256, 0, stream>>>(rowptr, part);
  k_dinv <<<391,  256, 0, stream>>>(deg, dinv);
  k_binit<<<4,    256, 0, stream>>>(rowptr, bcur);
  k_bin1 <<<196,  256, 0, stream>>>(src, dst, bcur, tmp);
  k_bin2 <<<NB,   256, 0, stream>>>(rowptr, tmp, cw);

  k_pack<<<88,  256, 0, stream>>>(W1, wb1, 35, 336, 352, 22528);
  k_pack<<<264, 256, 0, stream>>>(W2, wb2, 336, 168, 192, 67584);
  k_pack<<<72,  256, 0, stream>>>(W3, wb3, 168, 84, 96, 18432);
  k_pack<<<24,  256, 0, stream>>>(W4, wb4, 84, 42, 64, 6144);

  // conv1: prescale x, aggregate (mode0), matmul with bias+relu
  k_gx<<<12500, 256, 0, stream>>>(x, dinv, (unsigned int*)gx);
  k_agg<64, 0, 0><<<6250, 256, 0, stream>>>(gx, aggx, rowptr, cw, dinv, nullptr);
  k_mm<64, 352, 336, 64, 0><<<1564, 256, 0, stream>>>(aggx, wb1, b1, nullptr, h1);

  // conv2: matmul (scale epilogue), aggregate with bias+relu
  k_mm<352, 192, 168, 352, 1><<<1564, 256, 0, stream>>>(h1, wb2, nullptr, dinv, p2);
  k_agg<192, 168, 1><<<6250, 256, 0, stream>>>(p2, h2, rowptr, cw, dinv, b2);

  // conv3
  k_mm<192, 96, 84, 192, 1><<<1564, 256, 0, stream>>>(h2, wb3, nullptr, dinv, p3);
  k_agg<96, 84, 1><<<6250, 256, 0, stream>>>(p3, h3, rowptr, cw, dinv, b3);

  // conv4: aggregate writes q4 = dinv*h4 (mode2) so the head agg needs no weights
  k_mm<96, 64, 42, 96, 1><<<1564, 256, 0, stream>>>(h3, wb4, nullptr, dinv, p4);
  k_agg<64, 42, 2><<<6250, 256, 0, stream>>>(p4, q4, rowptr, cw, dinv, b4);

  // shared aggregation for mu/logstd heads (mode0)
  k_agg<64, 0, 0><<<6250, 256, 0, stream>>>(q4, aggh4, rowptr, cw, dinv, nullptr);

  k_final<<<391, 256, 0, stream>>>(aggh4, Wmu, bmu, Wls, bls, eps, (float*)d_out);
}

// Round 4
// 643.424 us; speedup vs baseline: 1.1859x; 1.1319x over previous
//
#include <hip/hip_runtime.h>

#define NN 100000
#define NE 1600000
#define MP 100096   // padded node count (multiple of 64, >= 1564*64)
#define NB 782      // ceil(NN/128) buckets of 128 nodes
#define CHUNK 8192  // edges per bin1 block

typedef short  short8 __attribute__((ext_vector_type(8)));   // 8 bf16 (4 VGPRs)
typedef float  f32x4  __attribute__((ext_vector_type(4)));

__device__ __forceinline__ unsigned short f2bf(float f){
  unsigned int u = __float_as_uint(f);
  u += 0x7fffu + ((u >> 16) & 1u);          // RNE
  return (unsigned short)(u >> 16);
}
__device__ __forceinline__ float bfl(unsigned int v){ return __uint_as_float((v & 0xffffu) << 16); }
__device__ __forceinline__ float bfh(unsigned int v){ return __uint_as_float(v & 0xffff0000u); }
__device__ __forceinline__ float bf1(unsigned short v){ return __uint_as_float(((unsigned int)v) << 16); }

// ---------------- graph build ----------------

__global__ __launch_bounds__(256) void k_hist(const int* __restrict__ dst, int* __restrict__ deg){
  int e = blockIdx.x * 256 + threadIdx.x;
  if (e < NE) atomicAdd(&deg[dst[e]], 1);
}

__global__ __launch_bounds__(256) void k_scan1(const int* __restrict__ deg, int* __restrict__ rp,
                                               int* __restrict__ part){
  __shared__ int sh[256];
  int t = threadIdx.x;
  int base = blockIdx.x * 1024 + t * 4;
  int v0 = (base     < NN) ? deg[base]     : 0;
  int v1 = (base + 1 < NN) ? deg[base + 1] : 0;
  int v2 = (base + 2 < NN) ? deg[base + 2] : 0;
  int v3 = (base + 3 < NN) ? deg[base + 3] : 0;
  int s = v0 + v1 + v2 + v3;
  sh[t] = s; __syncthreads();
  for (int off = 1; off < 256; off <<= 1){
    int val = sh[t];
    int add = (t >= off) ? sh[t - off] : 0;
    __syncthreads();
    sh[t] = val + add;
    __syncthreads();
  }
  int excl = sh[t] - s;
  if (t == 255) part[blockIdx.x] = sh[255];
  if (base     < NN) rp[base]     = excl;
  if (base + 1 < NN) rp[base + 1] = excl + v0;
  if (base + 2 < NN) rp[base + 2] = excl + v0 + v1;
  if (base + 3 < NN) rp[base + 3] = excl + v0 + v1 + v2;
}

__global__ __launch_bounds__(128) void k_scan2(int* __restrict__ part, int* __restrict__ rp, int nb){
  __shared__ int sh[128];
  int t = threadIdx.x;
  int v = (t < nb) ? part[t] : 0;
  sh[t] = v; __syncthreads();
  for (int off = 1; off < 128; off <<= 1){
    int val = sh[t];
    int add = (t >= off) ? sh[t - off] : 0;
    __syncthreads();
    sh[t] = val + add;
    __syncthreads();
  }
  if (t < nb) part[t] = sh[t] - v;     // exclusive
  if (t == 0) rp[NN] = NE;
}

__global__ __launch_bounds__(256) void k_scan3(int* __restrict__ rp, const int* __restrict__ part){
  int i = blockIdx.x * 256 + threadIdx.x;
  if (i < NN) rp[i] += part[i >> 10];
}

__global__ __launch_bounds__(256) void k_dinv(const int* __restrict__ deg, float* __restrict__ dinv){
  int i = blockIdx.x * 256 + threadIdx.x;
  if (i < NN) dinv[i] = rsqrtf((float)deg[i] + 1.0f);
}

__global__ __launch_bounds__(256) void k_binit(const int* __restrict__ rp, int* __restrict__ bcur){
  int b = blockIdx.x * 256 + threadIdx.x;
  if (b < NB) bcur[b] = rp[min(b << 7, NN)];
}

// Phase 1: bucket-sort edges into tmp (bucket = dst>>7). Per-block contiguous
// reservations => burst writes assembled into full lines in one XCD's L2.
__global__ __launch_bounds__(256) void k_bin1(const int* __restrict__ src, const int* __restrict__ dst,
                                              int* __restrict__ bcur, int2* __restrict__ tmp){
  __shared__ int cnt[NB];
  __shared__ int base[NB];
  __shared__ int pos[NB];
  int t = threadIdx.x;
  int e0 = blockIdx.x * CHUNK;
  int e1 = min(e0 + CHUNK, NE);
  for (int i = t; i < NB; i += 256){ cnt[i] = 0; pos[i] = 0; }
  __syncthreads();
  for (int e = e0 + t; e < e1; e += 256)
    atomicAdd(&cnt[dst[e] >> 7], 1);
  __syncthreads();
  for (int i = t; i < NB; i += 256){
    int c = cnt[i];
    base[i] = (c > 0) ? atomicAdd(&bcur[i], c) : 0;
  }
  __syncthreads();
  for (int e = e0 + t; e < e1; e += 256){
    int s = src[e], d = dst[e];
    int b = d >> 7;
    int p = base[b] + atomicAdd(&pos[b], 1);
    tmp[p] = make_int2(s, d);
  }
}

// Phase 2: within each bucket, place edges at final CSR slots. Per-node
// cursors in LDS (no global atomics); writes confined to the bucket's ~8KB
// window of cw => full-line evictions.
__global__ __launch_bounds__(256) void k_bin2(const int* __restrict__ rp, const int2* __restrict__ tmp,
                                              int* __restrict__ cw){
  __shared__ int cur[128];
  int b = blockIdx.x;
  int n0 = b << 7;
  int n1 = min(n0 + 128, NN);
  int t = threadIdx.x;
  int E0 = rp[n0], E1 = rp[n1];
  if (t < 128){
    int n = n0 + t;
    cur[t] = (n < NN) ? rp[n] : 0;
  }
  __syncthreads();
  for (int e = E0 + t; e < E1; e += 256){
    int2 p = tmp[e];
    int slot = atomicAdd(&cur[p.y - n0], 1);
    cw[slot] = p.x;
  }
}

// ---------------- weight repack to MFMA B-frag order ----------------
// layout: idx = ((ks*(Np/16)+nt)*64 + lane)*8 + j ; element = W[ks*32+(lane>>4)*8+j][nt*16+(lane&15)]

__global__ __launch_bounds__(256) void k_pack(const float* __restrict__ W, unsigned short* __restrict__ dst,
                                              int din, int dout, int Np, int total){
  int idx = blockIdx.x * 256 + threadIdx.x;
  if (idx >= total) return;
  int j = idx & 7;
  int l = (idx >> 3) & 63;
  int f = idx >> 9;
  int ntiles = Np >> 4;
  int nt = f % ntiles;
  int ks = f / ntiles;
  int k = ks * 32 + (l >> 4) * 8 + j;
  int n = nt * 16 + (l & 15);
  float v = (k < din && n < dout) ? W[k * dout + n] : 0.0f;
  dst[idx] = f2bf(v);
}

// ---------------- prescale conv1 input: gx = dinv*x, bf16, 64-pad ----------------

__global__ __launch_bounds__(256) void k_gx(const float* __restrict__ x, const float* __restrict__ dinv,
                                            unsigned int* __restrict__ gx){
  int idx = blockIdx.x * 256 + threadIdx.x;   // NN*32 u32 outputs
  if (idx >= NN * 32) return;
  int row = idx >> 5;
  int cu  = idx & 31;
  float di = dinv[row];
  int c0 = 2 * cu, c1 = 2 * cu + 1;
  float v0 = (c0 < 35) ? x[row * 35 + c0] * di : 0.0f;
  float v1 = (c1 < 35) ? x[row * 35 + c1] * di : 0.0f;
  gx[idx] = (unsigned int)f2bf(v0) | ((unsigned int)f2bf(v1) << 16);
}

// ---------------- aggregation: core = dinv[i]*(g[i] + sum_{j in N(i)} g[j]) ----------------
// MODE 0: out = core ; MODE 1: out = relu(core + b) ; MODE 2: out = dinv*relu(core + b)
// L lanes per row, uint2 (8B) granule: each L-lane chunk request = L*8 bytes.

template<int SP, int L, int DOUT, int MODE>
__global__ __launch_bounds__(256) void k_agg(const unsigned short* __restrict__ Hin,
                                             unsigned short* __restrict__ Hout,
                                             const int* __restrict__ rp, const int* __restrict__ cw,
                                             const float* __restrict__ dinv, const float* __restrict__ bias){
  constexpr int RPB = 256 / L;          // rows per block
  constexpr int U2  = SP / 4;           // uint2 per row
  constexpr int CH  = U2 / L;           // uint2 chunks per lane
  int g = blockIdx.x * RPB + (threadIdx.x / L);
  int c = threadIdx.x % L;
  if (g >= NN) return;
  int e0 = rp[g], e1 = rp[g + 1];
  const uint2* __restrict__ H = (const uint2*)Hin;

  float a0[CH], a1[CH], a2[CH], a3[CH];
  const uint2* sr = H + (size_t)g * U2;
  #pragma unroll
  for (int ch = 0; ch < CH; ++ch){
    uint2 v = sr[ch * L + c];
    a0[ch] = bfl(v.x); a1[ch] = bfh(v.x);
    a2[ch] = bfl(v.y); a3[ch] = bfh(v.y);
  }

  int e = e0;
  for (; e + 4 <= e1; e += 4){
    int s0 = cw[e], s1 = cw[e + 1], s2 = cw[e + 2], s3 = cw[e + 3];
    const uint2* r0 = H + (size_t)s0 * U2;
    const uint2* r1 = H + (size_t)s1 * U2;
    const uint2* r2 = H + (size_t)s2 * U2;
    const uint2* r3 = H + (size_t)s3 * U2;
    #pragma unroll
    for (int ch = 0; ch < CH; ++ch){
      uint2 v0 = r0[ch * L + c];
      uint2 v1 = r1[ch * L + c];
      uint2 v2 = r2[ch * L + c];
      uint2 v3 = r3[ch * L + c];
      a0[ch] += (bfl(v0.x) + bfl(v1.x)) + (bfl(v2.x) + bfl(v3.x));
      a1[ch] += (bfh(v0.x) + bfh(v1.x)) + (bfh(v2.x) + bfh(v3.x));
      a2[ch] += (bfl(v0.y) + bfl(v1.y)) + (bfl(v2.y) + bfl(v3.y));
      a3[ch] += (bfh(v0.y) + bfh(v1.y)) + (bfh(v2.y) + bfh(v3.y));
    }
  }
  for (; e < e1; ++e){
    int s = cw[e];
    const uint2* r = H + (size_t)s * U2;
    #pragma unroll
    for (int ch = 0; ch < CH; ++ch){
      uint2 v = r[ch * L + c];
      a0[ch] += bfl(v.x); a1[ch] += bfh(v.x);
      a2[ch] += bfl(v.y); a3[ch] += bfh(v.y);
    }
  }

  float di = dinv[g];
  uint2* orow = (uint2*)Hout + (size_t)g * U2;
  #pragma unroll
  for (int ch = 0; ch < CH; ++ch){
    float f0 = a0[ch] * di, f1 = a1[ch] * di, f2 = a2[ch] * di, f3 = a3[ch] * di;
    if (MODE >= 1){
      int fe = 4 * (ch * L + c);
      f0 += (fe     < DOUT) ? bias[fe]     : 0.0f;
      f1 += (fe + 1 < DOUT) ? bias[fe + 1] : 0.0f;
      f2 += (fe + 2 < DOUT) ? bias[fe + 2] : 0.0f;
      f3 += (fe + 3 < DOUT) ? bias[fe + 3] : 0.0f;
      f0 = fmaxf(f0, 0.0f); f1 = fmaxf(f1, 0.0f);
      f2 = fmaxf(f2, 0.0f); f3 = fmaxf(f3, 0.0f);
      if (MODE == 2){ f0 *= di; f1 *= di; f2 *= di; f3 *= di; }
    }
    uint2 o;
    o.x = (unsigned int)f2bf(f0) | ((unsigned int)f2bf(f1) << 16);
    o.y = (unsigned int)f2bf(f2) | ((unsigned int)f2bf(f3) << 16);
    orow[ch * L + c] = o;
  }
}

// ---------------- MFMA matmul: C[M,NP] = A[M,SPA(K)] * Bpacked ----------------
// EPI 0: bias+relu ; EPI 1: scale by dinv[row]

template<int K, int NP, int DOUT, int SPA, int EPI>
__global__ __launch_bounds__(256) void k_mm(const unsigned short* __restrict__ A,
                                            const unsigned short* __restrict__ Bp,
                                            const float* __restrict__ bias,
                                            const float* __restrict__ dinv,
                                            unsigned short* __restrict__ C){
  constexpr int NT  = NP / 16;
  constexpr int NT2 = NP / 32;   // tiles per col-wave
  int l   = threadIdx.x & 63;
  int wid = threadIdx.x >> 6;
  int wr = wid >> 1, wc = wid & 1;
  int r0 = blockIdx.x * 64 + wr * 32;
  int n0 = wc * (NP / 2);
  int lr = l & 15, lk = l >> 4;
  const short8* __restrict__ Af = (const short8*)A;
  const short8* __restrict__ Bf = (const short8*)Bp;
  f32x4 acc[2][NT2];
  #pragma unroll
  for (int m = 0; m < 2; ++m)
    #pragma unroll
    for (int t = 0; t < NT2; ++t) acc[m][t] = (f32x4){0.f, 0.f, 0.f, 0.f};

  for (int ks = 0; ks < K / 32; ++ks){
    short8 a0 = Af[((r0      + lr) * SPA + ks * 32 + lk * 8) >> 3];
    short8 a1 = Af[((r0 + 16 + lr) * SPA + ks * 32 + lk * 8) >> 3];
    const short8* bp = Bf + (ks * NT + (n0 >> 4)) * 64 + l;
    #pragma unroll
    for (int t = 0; t < NT2; ++t){
      short8 b = bp[t * 64];
      acc[0][t] = __builtin_amdgcn_mfma_f32_16x16x32_bf16(a0, b, acc[0][t], 0, 0, 0);
      acc[1][t] = __builtin_amdgcn_mfma_f32_16x16x32_bf16(a1, b, acc[1][t], 0, 0, 0);
    }
  }
  // C/D layout: col = lane&15, row = (lane>>4)*4 + j   [m89-verified]
  int rb = lk * 4;
  #pragma unroll
  for (int m = 0; m < 2; ++m){
    #pragma unroll
    for (int t = 0; t < NT2; ++t){
      int col = n0 + t * 16 + lr;
      float bv = 0.0f;
      if (EPI == 0) bv = (col < DOUT) ? bias[col] : 0.0f;
      #pragma unroll
      for (int j = 0; j < 4; ++j){
        int row = r0 + m * 16 + rb + j;
        if (row < NN){
          float v = acc[m][t][j];
          if (EPI == 0) v = fmaxf(v + bv, 0.0f);
          else          v = v * dinv[row];
          C[(size_t)row * NP + col] = f2bf(v);
        }
      }
    }
  }
}

// ---------------- final: mu/logstd matmuls + reparam + log_softmax ----------------

__global__ __launch_bounds__(256) void k_final(const unsigned short* __restrict__ aggh4,
                                               const float* __restrict__ Wmu, const float* __restrict__ bmu,
                                               const float* __restrict__ Wls, const float* __restrict__ bls,
                                               const float* __restrict__ eps, float* __restrict__ out){
  __shared__ float sWmu[42 * 21];
  __shared__ float sWls[42 * 21];
  __shared__ float sbmu[21];
  __shared__ float sbls[21];
  for (int u = threadIdx.x; u < 882; u += 256){ sWmu[u] = Wmu[u]; sWls[u] = Wls[u]; }
  if (threadIdx.x < 21){ sbmu[threadIdx.x] = bmu[threadIdx.x]; sbls[threadIdx.x] = bls[threadIdx.x]; }
  __syncthreads();

  int i = blockIdx.x * 256 + threadIdx.x;
  if (i >= NN) return;

  float mu[21], ls[21];
  #pragma unroll
  for (int j = 0; j < 21; ++j){ mu[j] = sbmu[j]; ls[j] = sbls[j]; }

  const unsigned short* arow = aggh4 + (size_t)i * 64;
  for (int k = 0; k < 42; ++k){
    float ak = bf1(arow[k]);
    #pragma unroll
    for (int j = 0; j < 21; ++j){
      mu[j] += ak * sWmu[k * 21 + j];
      ls[j] += ak * sWls[k * 21 + j];
    }
  }
  float zv[21];
  float mx = -3.4e38f;
  #pragma unroll
  for (int j = 0; j < 21; ++j){
    float l2 = fminf(ls[j], 10.0f);
    float zj = mu[j] + eps[(size_t)i * 21 + j] * __expf(l2);
    zv[j] = zj;
    mx = fmaxf(mx, zj);
  }
  float ssum = 0.f;
  #pragma unroll
  for (int j = 0; j < 21; ++j) ssum += __expf(zv[j] - mx);
  float lse = mx + __logf(ssum);
  #pragma unroll
  for (int j = 0; j < 21; ++j) out[(size_t)i * 21 + j] = zv[j] - lse;
}

// ---------------- workspace layout (bytes, 512-aligned) ----------------

constexpr size_t OFF_ROWPTR = 0;            // (NN+1)*4
constexpr size_t OFF_DEG    = 400896;
constexpr size_t OFF_DINV   = 801280;
constexpr size_t OFF_PART   = 1201664;
constexpr size_t OFF_BCUR   = 1202176;
constexpr size_t OFF_CW     = 1205760;      // NE*4 = 6,400,000
constexpr size_t OFF_TMP    = 7606272;      // NE*8 = 12,800,000
constexpr size_t OFF_WB1    = 20406784;     // 45,056
constexpr size_t OFF_WB2    = 20452352;     // 135,168
constexpr size_t OFF_WB3    = 20588032;     // 36,864
constexpr size_t OFF_WB4    = 20625408;     // 12,288
constexpr size_t OFF_GX     = 20638208;     // MP*64*2 = 12,812,288 (aggh4 reuses)
constexpr size_t OFF_AGGX   = 33451008;     // 12,812,288
constexpr size_t OFF_H1     = 46263808;     // MP*352*2 = 70,467,584 (h2 reuses)
constexpr size_t OFF_H2     = OFF_H1;       // 38,436,864 (h1 dead after mm2)
constexpr size_t OFF_P3     = 84701184;     // MP*96*2 = 19,218,432
constexpr size_t OFF_H3     = 103920128;    // 19,218,432
constexpr size_t OFF_P4     = 123139072;    // MP*64*2 = 12,812,288
constexpr size_t OFF_Q4     = 135951872;    // 12,812,288 ; ends 148,764,160
constexpr size_t OFF_P2     = 116731904;    // MP*192*2 = 38,436,864 ; ends 155,168,768
constexpr size_t OFF_AGGH4  = OFF_GX;       // gx dead after agg1

extern "C" void kernel_launch(void* const* d_in, const int* in_sizes, int n_in,
                              void* d_out, int out_size, void* d_ws, size_t ws_size,
                              hipStream_t stream){
  (void)in_sizes; (void)n_in; (void)out_size; (void)ws_size;
  const float* x    = (const float*)d_in[0];
  const int*   ei   = (const int*)d_in[1];
  const float* eps  = (const float*)d_in[2];
  const float* W1   = (const float*)d_in[3];  const float* b1  = (const float*)d_in[4];
  const float* W2   = (const float*)d_in[5];  const float* b2  = (const float*)d_in[6];
  const float* W3   = (const float*)d_in[7];  const float* b3  = (const float*)d_in[8];
  const float* W4   = (const float*)d_in[9];  const float* b4  = (const float*)d_in[10];
  const float* Wmu  = (const float*)d_in[11]; const float* bmu = (const float*)d_in[12];
  const float* Wls  = (const float*)d_in[13]; const float* bls = (const float*)d_in[14];

  char* ws = (char*)d_ws;
  int*   rowptr = (int*)(ws + OFF_ROWPTR);
  int*   deg    = (int*)(ws + OFF_DEG);
  float* dinv   = (float*)(ws + OFF_DINV);
  int*   part   = (int*)(ws + OFF_PART);
  int*   bcur   = (int*)(ws + OFF_BCUR);
  int*   cw     = (int*)(ws + OFF_CW);
  int2*  tmp    = (int2*)(ws + OFF_TMP);
  unsigned short* wb1   = (unsigned short*)(ws + OFF_WB1);
  unsigned short* wb2   = (unsigned short*)(ws + OFF_WB2);
  unsigned short* wb3   = (unsigned short*)(ws + OFF_WB3);
  unsigned short* wb4   = (unsigned short*)(ws + OFF_WB4);
  unsigned short* gx    = (unsigned short*)(ws + OFF_GX);
  unsigned short* aggx  = (unsigned short*)(ws + OFF_AGGX);
  unsigned short* h1    = (unsigned short*)(ws + OFF_H1);
  unsigned short* p2    = (unsigned short*)(ws + OFF_P2);
  unsigned short* h2    = (unsigned short*)(ws + OFF_H2);
  unsigned short* p3    = (unsigned short*)(ws + OFF_P3);
  unsigned short* h3    = (unsigned short*)(ws + OFF_H3);
  unsigned short* p4    = (unsigned short*)(ws + OFF_P4);
  unsigned short* q4    = (unsigned short*)(ws + OFF_Q4);
  unsigned short* aggh4 = (unsigned short*)(ws + OFF_AGGH4);

  const int* src = ei;
  const int* dst = ei + NE;

  hipMemsetAsync(deg, 0, NN * sizeof(int), stream);
  k_hist <<<6250, 256, 0, stream>>>(dst, deg);
  k_scan1<<<98,   256, 0, stream>>>(deg, rowptr, part);
  k_scan2<<<1,    128, 0, stream>>>(part, rowptr, 98);
  k_scan3<<<391,  256, 0, stream>>>(rowptr, part);
  k_dinv <<<391,  256, 0, stream>>>(deg, dinv);
  k_binit<<<4,    256, 0, stream>>>(rowptr, bcur);
  k_bin1 <<<196,  256, 0, stream>>>(src, dst, bcur, tmp);
  k_bin2 <<<NB,   256, 0, stream>>>(rowptr, tmp, cw);

  k_pack<<<88,  256, 0, stream>>>(W1, wb1, 35, 336, 352, 22528);
  k_pack<<<264, 256, 0, stream>>>(W2, wb2, 336, 168, 192, 67584);
  k_pack<<<72,  256, 0, stream>>>(W3, wb3, 168, 84, 96, 18432);
  k_pack<<<24,  256, 0, stream>>>(W4, wb4, 84, 42, 64, 6144);

  // conv1: prescale x, aggregate (mode0), matmul with bias+relu
  k_gx<<<12500, 256, 0, stream>>>(x, dinv, (unsigned int*)gx);
  k_agg<64, 16, 0, 0><<<6250, 256, 0, stream>>>(gx, aggx, rowptr, cw, dinv, nullptr);
  k_mm<64, 352, 336, 64, 0><<<1564, 256, 0, stream>>>(aggx, wb1, b1, nullptr, h1);

  // conv2: matmul (scale epilogue), aggregate with bias+relu
  k_mm<352, 192, 168, 352, 1><<<1564, 256, 0, stream>>>(h1, wb2, nullptr, dinv, p2);
  k_agg<192, 16, 168, 1><<<6250, 256, 0, stream>>>(p2, h2, rowptr, cw, dinv, b2);

  // conv3
  k_mm<192, 96, 84, 192, 1><<<1564, 256, 0, stream>>>(h2, wb3, nullptr, dinv, p3);
  k_agg<96, 8, 84, 1><<<3125, 256, 0, stream>>>(p3, h3, rowptr, cw, dinv, b3);

  // conv4: aggregate writes q4 = dinv*relu(...) (mode2) so the head agg needs no weights
  k_mm<96, 64, 42, 96, 1><<<1564, 256, 0, stream>>>(h3, wb4, nullptr, dinv, p4);
  k_agg<64, 16, 42, 2><<<6250, 256, 0, stream>>>(p4, q4, rowptr, cw, dinv, b4);

  // shared aggregation for mu/logstd heads (mode0)
  k_agg<64, 16, 0, 0><<<6250, 256, 0, stream>>>(q4, aggh4, rowptr, cw, dinv, nullptr);

  k_final<<<391, 256, 0, stream>>>(aggh4, Wmu, bmu, Wls, bls, eps, (float*)d_out);
}

// Round 5
// 634.631 us; speedup vs baseline: 1.2023x; 1.0139x over previous
//
#include <hip/hip_runtime.h>

#define NN 100000
#define NE 1600000
#define MP 100096   // padded node count (multiple of 64, >= 1564*64)
#define NB 782      // ceil(NN/128) buckets of 128 nodes
#define CHUNK 8192  // edges per bin1 block

typedef short  short8 __attribute__((ext_vector_type(8)));   // 8 bf16 (4 VGPRs)
typedef float  f32x4  __attribute__((ext_vector_type(4)));

__device__ __forceinline__ unsigned short f2bf(float f){
  unsigned int u = __float_as_uint(f);
  u += 0x7fffu + ((u >> 16) & 1u);          // RNE
  return (unsigned short)(u >> 16);
}
__device__ __forceinline__ float bfl(unsigned int v){ return __uint_as_float((v & 0xffffu) << 16); }
__device__ __forceinline__ float bfh(unsigned int v){ return __uint_as_float(v & 0xffff0000u); }
__device__ __forceinline__ float bf1(unsigned short v){ return __uint_as_float(((unsigned int)v) << 16); }

// ---------------- graph build ----------------

__global__ __launch_bounds__(256) void k_hist(const int* __restrict__ dst, int* __restrict__ deg){
  int e = blockIdx.x * 256 + threadIdx.x;
  if (e < NE) atomicAdd(&deg[dst[e]], 1);
}

__global__ __launch_bounds__(256) void k_scan1(const int* __restrict__ deg, int* __restrict__ rp,
                                               int* __restrict__ part){
  __shared__ int sh[256];
  int t = threadIdx.x;
  int base = blockIdx.x * 1024 + t * 4;
  int v0 = (base     < NN) ? deg[base]     : 0;
  int v1 = (base + 1 < NN) ? deg[base + 1] : 0;
  int v2 = (base + 2 < NN) ? deg[base + 2] : 0;
  int v3 = (base + 3 < NN) ? deg[base + 3] : 0;
  int s = v0 + v1 + v2 + v3;
  sh[t] = s; __syncthreads();
  for (int off = 1; off < 256; off <<= 1){
    int val = sh[t];
    int add = (t >= off) ? sh[t - off] : 0;
    __syncthreads();
    sh[t] = val + add;
    __syncthreads();
  }
  int excl = sh[t] - s;
  if (t == 255) part[blockIdx.x] = sh[255];
  if (base     < NN) rp[base]     = excl;
  if (base + 1 < NN) rp[base + 1] = excl + v0;
  if (base + 2 < NN) rp[base + 2] = excl + v0 + v1;
  if (base + 3 < NN) rp[base + 3] = excl + v0 + v1 + v2;
}

__global__ __launch_bounds__(128) void k_scan2(int* __restrict__ part, int* __restrict__ rp, int nb){
  __shared__ int sh[128];
  int t = threadIdx.x;
  int v = (t < nb) ? part[t] : 0;
  sh[t] = v; __syncthreads();
  for (int off = 1; off < 128; off <<= 1){
    int val = sh[t];
    int add = (t >= off) ? sh[t - off] : 0;
    __syncthreads();
    sh[t] = val + add;
    __syncthreads();
  }
  if (t < nb) part[t] = sh[t] - v;     // exclusive
  if (t == 0) rp[NN] = NE;
}

// fused: scan3 apply + dinv + binit + gx prescale (independent element ranges)
__global__ __launch_bounds__(256) void k_aux(int* __restrict__ rp, const int* __restrict__ part,
                                             const int* __restrict__ deg, const float* __restrict__ x,
                                             float* __restrict__ dinv, int* __restrict__ bcur,
                                             unsigned int* __restrict__ gx){
  if (blockIdx.x < 391){
    int i = blockIdx.x * 256 + threadIdx.x;
    if (i < NN){
      int v = rp[i] + part[i >> 10];
      rp[i] = v;
      dinv[i] = rsqrtf((float)deg[i] + 1.0f);
      if ((i & 127) == 0) bcur[i >> 7] = v;
    }
  } else {
    int idx = (blockIdx.x - 391) * 256 + threadIdx.x;   // NN*32 u32 outputs
    if (idx >= NN * 32) return;
    int row = idx >> 5;
    int cu  = idx & 31;
    float di = rsqrtf((float)deg[row] + 1.0f);
    int c0 = 2 * cu, c1 = 2 * cu + 1;
    float v0 = (c0 < 35) ? x[row * 35 + c0] * di : 0.0f;
    float v1 = (c1 < 35) ? x[row * 35 + c1] * di : 0.0f;
    gx[idx] = (unsigned int)f2bf(v0) | ((unsigned int)f2bf(v1) << 16);
  }
}

// Phase 1: bucket-sort edges into tmp (bucket = dst>>7). Per-block contiguous
// reservations => burst writes assembled into full lines in one XCD's L2.
__global__ __launch_bounds__(256) void k_bin1(const int* __restrict__ src, const int* __restrict__ dst,
                                              int* __restrict__ bcur, int2* __restrict__ tmp){
  __shared__ int cnt[NB];
  __shared__ int base[NB];
  __shared__ int pos[NB];
  int t = threadIdx.x;
  int e0 = blockIdx.x * CHUNK;
  int e1 = min(e0 + CHUNK, NE);
  for (int i = t; i < NB; i += 256){ cnt[i] = 0; pos[i] = 0; }
  __syncthreads();
  for (int e = e0 + t; e < e1; e += 256)
    atomicAdd(&cnt[dst[e] >> 7], 1);
  __syncthreads();
  for (int i = t; i < NB; i += 256){
    int c = cnt[i];
    base[i] = (c > 0) ? atomicAdd(&bcur[i], c) : 0;
  }
  __syncthreads();
  for (int e = e0 + t; e < e1; e += 256){
    int s = src[e], d = dst[e];
    int b = d >> 7;
    int p = base[b] + atomicAdd(&pos[b], 1);
    tmp[p] = make_int2(s, d);
  }
}

// Phase 2: within each bucket, place edges at final CSR slots. Per-node
// cursors in LDS (no global atomics); writes confined to the bucket's ~8KB
// window of cw => full-line evictions.
__global__ __launch_bounds__(256) void k_bin2(const int* __restrict__ rp, const int2* __restrict__ tmp,
                                              int* __restrict__ cw){
  __shared__ int cur[128];
  int b = blockIdx.x;
  int n0 = b << 7;
  int n1 = min(n0 + 128, NN);
  int t = threadIdx.x;
  int E0 = rp[n0], E1 = rp[n1];
  if (t < 128){
    int n = n0 + t;
    cur[t] = (n < NN) ? rp[n] : 0;
  }
  __syncthreads();
  for (int e = E0 + t; e < E1; e += 256){
    int2 p = tmp[e];
    int slot = atomicAdd(&cur[p.y - n0], 1);
    cw[slot] = p.x;
  }
}

// ---------------- weight repack to MFMA B-frag order (all 4 weights, fused) ----------------
// layout: idx = ((ks*(Np/16)+nt)*64 + lane)*8 + j ; element = W[ks*32+(lane>>4)*8+j][nt*16+(lane&15)]

__device__ __forceinline__ void pack1(const float* __restrict__ W, unsigned short* __restrict__ dst,
                                      int din, int dout, int Np, int idx){
  int j = idx & 7;
  int l = (idx >> 3) & 63;
  int f = idx >> 9;
  int ntiles = Np >> 4;
  int nt = f % ntiles;
  int ks = f / ntiles;
  int k = ks * 32 + (l >> 4) * 8 + j;
  int n = nt * 16 + (l & 15);
  float v = (k < din && n < dout) ? W[k * dout + n] : 0.0f;
  dst[idx] = f2bf(v);
}

__global__ __launch_bounds__(256) void k_packall(const float* __restrict__ W1, unsigned short* __restrict__ d1,
                                                 const float* __restrict__ W2, unsigned short* __restrict__ d2,
                                                 const float* __restrict__ W3, unsigned short* __restrict__ d3,
                                                 const float* __restrict__ W4, unsigned short* __restrict__ d4){
  int idx = blockIdx.x * 256 + threadIdx.x;
  if      (idx < 22528)  pack1(W1, d1, 35, 336, 352, idx);
  else if (idx < 90112)  pack1(W2, d2, 336, 168, 192, idx - 22528);
  else if (idx < 108544) pack1(W3, d3, 168, 84, 96, idx - 90112);
  else if (idx < 114688) pack1(W4, d4, 84, 42, 64, idx - 108544);
}

// ---------------- aggregation: core = dinv[i]*(g[i] + sum_{j in N(i)} g[j]) ----------------
// MODE 0: out = core ; MODE 1: out = relu(core + b) ; MODE 2: out = dinv*relu(core + b)
// L lanes per row, uint2 granule. Software-pipelined: next cw batch prefetched
// before current rows are accumulated (breaks the cw->gather serial chain).

template<int SP, int L, int DOUT, int MODE>
__global__ __launch_bounds__(256) void k_agg(const unsigned short* __restrict__ Hin,
                                             unsigned short* __restrict__ Hout,
                                             const int* __restrict__ rp, const int* __restrict__ cw,
                                             const float* __restrict__ dinv, const float* __restrict__ bias){
  constexpr int RPB = 256 / L;          // rows per block
  constexpr int U2  = SP / 4;           // uint2 per row
  constexpr int CH  = U2 / L;           // uint2 chunks per lane
  constexpr int UN  = (CH == 1) ? 8 : 4;
  int g = blockIdx.x * RPB + (threadIdx.x / L);
  int c = threadIdx.x % L;
  if (g >= NN) return;
  int e0 = rp[g], e1 = rp[g + 1];
  const uint2* __restrict__ H = (const uint2*)Hin;

  float a0[CH], a1[CH], a2[CH], a3[CH];
  const uint2* sr = H + (size_t)g * U2;
  #pragma unroll
  for (int ch = 0; ch < CH; ++ch){
    uint2 v = sr[ch * L + c];
    a0[ch] = bfl(v.x); a1[ch] = bfh(v.x);
    a2[ch] = bfl(v.y); a3[ch] = bfh(v.y);
  }

  int e = e0;
  if (e + UN <= e1){
    int s[UN];
    #pragma unroll
    for (int u = 0; u < UN; ++u) s[u] = cw[e + u];
    while (true){
      uint2 v[UN][CH];
      #pragma unroll
      for (int u = 0; u < UN; ++u){
        const uint2* r = H + (size_t)s[u] * U2;
        #pragma unroll
        for (int ch = 0; ch < CH; ++ch) v[u][ch] = r[ch * L + c];
      }
      int e2 = e + UN;
      bool more = (e2 + UN <= e1);
      int s2[UN];
      if (more){
        #pragma unroll
        for (int u = 0; u < UN; ++u) s2[u] = cw[e2 + u];
      }
      #pragma unroll
      for (int u = 0; u < UN; ++u){
        #pragma unroll
        for (int ch = 0; ch < CH; ++ch){
          a0[ch] += bfl(v[u][ch].x); a1[ch] += bfh(v[u][ch].x);
          a2[ch] += bfl(v[u][ch].y); a3[ch] += bfh(v[u][ch].y);
        }
      }
      e = e2;
      if (!more) break;
      #pragma unroll
      for (int u = 0; u < UN; ++u) s[u] = s2[u];
    }
  }
  for (; e < e1; ++e){
    int s = cw[e];
    const uint2* r = H + (size_t)s * U2;
    #pragma unroll
    for (int ch = 0; ch < CH; ++ch){
      uint2 v = r[ch * L + c];
      a0[ch] += bfl(v.x); a1[ch] += bfh(v.x);
      a2[ch] += bfl(v.y); a3[ch] += bfh(v.y);
    }
  }

  float di = dinv[g];
  uint2* orow = (uint2*)Hout + (size_t)g * U2;
  #pragma unroll
  for (int ch = 0; ch < CH; ++ch){
    float f0 = a0[ch] * di, f1 = a1[ch] * di, f2 = a2[ch] * di, f3 = a3[ch] * di;
    if (MODE >= 1){
      int fe = 4 * (ch * L + c);
      f0 += (fe     < DOUT) ? bias[fe]     : 0.0f;
      f1 += (fe + 1 < DOUT) ? bias[fe + 1] : 0.0f;
      f2 += (fe + 2 < DOUT) ? bias[fe + 2] : 0.0f;
      f3 += (fe + 3 < DOUT) ? bias[fe + 3] : 0.0f;
      f0 = fmaxf(f0, 0.0f); f1 = fmaxf(f1, 0.0f);
      f2 = fmaxf(f2, 0.0f); f3 = fmaxf(f3, 0.0f);
      if (MODE == 2){ f0 *= di; f1 *= di; f2 *= di; f3 *= di; }
    }
    uint2 o;
    o.x = (unsigned int)f2bf(f0) | ((unsigned int)f2bf(f1) << 16);
    o.y = (unsigned int)f2bf(f2) | ((unsigned int)f2bf(f3) << 16);
    orow[ch * L + c] = o;
  }
}

// ---------------- MFMA matmul: C[M,NP] = A[M,SPA(K)] * Bpacked ----------------
// EPI 0: bias+relu ; EPI 1: scale by dinv[row]

template<int K, int NP, int DOUT, int SPA, int EPI>
__global__ __launch_bounds__(256) void k_mm(const unsigned short* __restrict__ A,
                                            const unsigned short* __restrict__ Bp,
                                            const float* __restrict__ bias,
                                            const float* __restrict__ dinv,
                                            unsigned short* __restrict__ C){
  constexpr int NT  = NP / 16;
  constexpr int NT2 = NP / 32;   // tiles per col-wave
  int l   = threadIdx.x & 63;
  int wid = threadIdx.x >> 6;
  int wr = wid >> 1, wc = wid & 1;
  int r0 = blockIdx.x * 64 + wr * 32;
  int n0 = wc * (NP / 2);
  int lr = l & 15, lk = l >> 4;
  const short8* __restrict__ Af = (const short8*)A;
  const short8* __restrict__ Bf = (const short8*)Bp;
  f32x4 acc[2][NT2];
  #pragma unroll
  for (int m = 0; m < 2; ++m)
    #pragma unroll
    for (int t = 0; t < NT2; ++t) acc[m][t] = (f32x4){0.f, 0.f, 0.f, 0.f};

  for (int ks = 0; ks < K / 32; ++ks){
    short8 a0 = Af[((r0      + lr) * SPA + ks * 32 + lk * 8) >> 3];
    short8 a1 = Af[((r0 + 16 + lr) * SPA + ks * 32 + lk * 8) >> 3];
    const short8* bp = Bf + (ks * NT + (n0 >> 4)) * 64 + l;
    #pragma unroll
    for (int t = 0; t < NT2; ++t){
      short8 b = bp[t * 64];
      acc[0][t] = __builtin_amdgcn_mfma_f32_16x16x32_bf16(a0, b, acc[0][t], 0, 0, 0);
      acc[1][t] = __builtin_amdgcn_mfma_f32_16x16x32_bf16(a1, b, acc[1][t], 0, 0, 0);
    }
  }
  // C/D layout: col = lane&15, row = (lane>>4)*4 + j   [m89-verified]
  int rb = lk * 4;
  #pragma unroll
  for (int m = 0; m < 2; ++m){
    #pragma unroll
    for (int t = 0; t < NT2; ++t){
      int col = n0 + t * 16 + lr;
      float bv = 0.0f;
      if (EPI == 0) bv = (col < DOUT) ? bias[col] : 0.0f;
      #pragma unroll
      for (int j = 0; j < 4; ++j){
        int row = r0 + m * 16 + rb + j;
        if (row < NN){
          float v = acc[m][t][j];
          if (EPI == 0) v = fmaxf(v + bv, 0.0f);
          else          v = v * dinv[row];
          C[(size_t)row * NP + col] = f2bf(v);
        }
      }
    }
  }
}

// ---------------- final: mu/logstd matmuls + reparam + log_softmax ----------------

__global__ __launch_bounds__(256) void k_final(const unsigned short* __restrict__ aggh4,
                                               const float* __restrict__ Wmu, const float* __restrict__ bmu,
                                               const float* __restrict__ Wls, const float* __restrict__ bls,
                                               const float* __restrict__ eps, float* __restrict__ out){
  __shared__ float sWmu[42 * 21];
  __shared__ float sWls[42 * 21];
  __shared__ float sbmu[21];
  __shared__ float sbls[21];
  for (int u = threadIdx.x; u < 882; u += 256){ sWmu[u] = Wmu[u]; sWls[u] = Wls[u]; }
  if (threadIdx.x < 21){ sbmu[threadIdx.x] = bmu[threadIdx.x]; sbls[threadIdx.x] = bls[threadIdx.x]; }
  __syncthreads();

  int i = blockIdx.x * 256 + threadIdx.x;
  if (i >= NN) return;

  float mu[21], ls[21];
  #pragma unroll
  for (int j = 0; j < 21; ++j){ mu[j] = sbmu[j]; ls[j] = sbls[j]; }

  const unsigned short* arow = aggh4 + (size_t)i * 64;
  for (int k = 0; k < 42; ++k){
    float ak = bf1(arow[k]);
    #pragma unroll
    for (int j = 0; j < 21; ++j){
      mu[j] += ak * sWmu[k * 21 + j];
      ls[j] += ak * sWls[k * 21 + j];
    }
  }
  float zv[21];
  float mx = -3.4e38f;
  #pragma unroll
  for (int j = 0; j < 21; ++j){
    float l2 = fminf(ls[j], 10.0f);
    float zj = mu[j] + eps[(size_t)i * 21 + j] * __expf(l2);
    zv[j] = zj;
    mx = fmaxf(mx, zj);
  }
  float ssum = 0.f;
  #pragma unroll
  for (int j = 0; j < 21; ++j) ssum += __expf(zv[j] - mx);
  float lse = mx + __logf(ssum);
  #pragma unroll
  for (int j = 0; j < 21; ++j) out[(size_t)i * 21 + j] = zv[j] - lse;
}

// ---------------- workspace layout (bytes, 512-aligned) ----------------

constexpr size_t OFF_ROWPTR = 0;            // (NN+1)*4
constexpr size_t OFF_DEG    = 400896;
constexpr size_t OFF_DINV   = 801280;
constexpr size_t OFF_PART   = 1201664;
constexpr size_t OFF_BCUR   = 1202176;
constexpr size_t OFF_CW     = 1205760;      // NE*4 = 6,400,000
constexpr size_t OFF_TMP    = 7606272;      // NE*8 = 12,800,000
constexpr size_t OFF_WB1    = 20406784;     // 45,056
constexpr size_t OFF_WB2    = 20452352;     // 135,168
constexpr size_t OFF_WB3    = 20588032;     // 36,864
constexpr size_t OFF_WB4    = 20625408;     // 12,288
constexpr size_t OFF_GX     = 20638208;     // MP*64*2 = 12,812,288 (aggh4 reuses)
constexpr size_t OFF_AGGX   = 33451008;     // 12,812,288
constexpr size_t OFF_H1     = 46263808;     // MP*352*2 = 70,467,584 (h2 reuses)
constexpr size_t OFF_H2     = OFF_H1;       // 38,436,864 (h1 dead after mm2)
constexpr size_t OFF_P3     = 84701184;     // MP*96*2 = 19,218,432
constexpr size_t OFF_H3     = 103920128;    // 19,218,432
constexpr size_t OFF_P4     = 123139072;    // MP*64*2 = 12,812,288
constexpr size_t OFF_Q4     = 135951872;    // 12,812,288 ; ends 148,764,160
constexpr size_t OFF_P2     = 116731904;    // MP*192*2 = 38,436,864 ; ends 155,168,768
constexpr size_t OFF_AGGH4  = OFF_GX;       // gx dead after agg1

extern "C" void kernel_launch(void* const* d_in, const int* in_sizes, int n_in,
                              void* d_out, int out_size, void* d_ws, size_t ws_size,
                              hipStream_t stream){
  (void)in_sizes; (void)n_in; (void)out_size; (void)ws_size;
  const float* x    = (const float*)d_in[0];
  const int*   ei   = (const int*)d_in[1];
  const float* eps  = (const float*)d_in[2];
  const float* W1   = (const float*)d_in[3];  const float* b1  = (const float*)d_in[4];
  const float* W2   = (const float*)d_in[5];  const float* b2  = (const float*)d_in[6];
  const float* W3   = (const float*)d_in[7];  const float* b3  = (const float*)d_in[8];
  const float* W4   = (const float*)d_in[9];  const float* b4  = (const float*)d_in[10];
  const float* Wmu  = (const float*)d_in[11]; const float* bmu = (const float*)d_in[12];
  const float* Wls  = (const float*)d_in[13]; const float* bls = (const float*)d_in[14];

  char* ws = (char*)d_ws;
  int*   rowptr = (int*)(ws + OFF_ROWPTR);
  int*   deg    = (int*)(ws + OFF_DEG);
  float* dinv   = (float*)(ws + OFF_DINV);
  int*   part   = (int*)(ws + OFF_PART);
  int*   bcur   = (int*)(ws + OFF_BCUR);
  int*   cw     = (int*)(ws + OFF_CW);
  int2*  tmp    = (int2*)(ws + OFF_TMP);
  unsigned short* wb1   = (unsigned short*)(ws + OFF_WB1);
  unsigned short* wb2   = (unsigned short*)(ws + OFF_WB2);
  unsigned short* wb3   = (unsigned short*)(ws + OFF_WB3);
  unsigned short* wb4   = (unsigned short*)(ws + OFF_WB4);
  unsigned short* gx    = (unsigned short*)(ws + OFF_GX);
  unsigned short* aggx  = (unsigned short*)(ws + OFF_AGGX);
  unsigned short* h1    = (unsigned short*)(ws + OFF_H1);
  unsigned short* p2    = (unsigned short*)(ws + OFF_P2);
  unsigned short* h2    = (unsigned short*)(ws + OFF_H2);
  unsigned short* p3    = (unsigned short*)(ws + OFF_P3);
  unsigned short* h3    = (unsigned short*)(ws + OFF_H3);
  unsigned short* p4    = (unsigned short*)(ws + OFF_P4);
  unsigned short* q4    = (unsigned short*)(ws + OFF_Q4);
  unsigned short* aggh4 = (unsigned short*)(ws + OFF_AGGH4);

  const int* src = ei;
  const int* dst = ei + NE;

  hipMemsetAsync(deg, 0, NN * sizeof(int), stream);
  k_hist   <<<6250,  256, 0, stream>>>(dst, deg);
  k_scan1  <<<98,    256, 0, stream>>>(deg, rowptr, part);
  k_scan2  <<<1,     128, 0, stream>>>(part, rowptr, 98);
  k_aux    <<<12891, 256, 0, stream>>>(rowptr, part, deg, x, dinv, bcur, (unsigned int*)gx);
  k_bin1   <<<196,   256, 0, stream>>>(src, dst, bcur, tmp);
  k_bin2   <<<NB,    256, 0, stream>>>(rowptr, tmp, cw);
  k_packall<<<449,   256, 0, stream>>>(W1, wb1, W2, wb2, W3, wb3, W4, wb4);

  // conv1: aggregate prescaled x (mode0), matmul with bias+relu
  k_agg<64, 16, 0, 0><<<6250, 256, 0, stream>>>(gx, aggx, rowptr, cw, dinv, nullptr);
  k_mm<64, 352, 336, 64, 0><<<1564, 256, 0, stream>>>(aggx, wb1, b1, nullptr, h1);

  // conv2: matmul (scale epilogue), aggregate with bias+relu
  k_mm<352, 192, 168, 352, 1><<<1564, 256, 0, stream>>>(h1, wb2, nullptr, dinv, p2);
  k_agg<192, 16, 168, 1><<<6250, 256, 0, stream>>>(p2, h2, rowptr, cw, dinv, b2);

  // conv3
  k_mm<192, 96, 84, 192, 1><<<1564, 256, 0, stream>>>(h2, wb3, nullptr, dinv, p3);
  k_agg<96, 8, 84, 1><<<3125, 256, 0, stream>>>(p3, h3, rowptr, cw, dinv, b3);

  // conv4: aggregate writes q4 = dinv*relu(...) (mode2) so the head agg needs no weights
  k_mm<96, 64, 42, 96, 1><<<1564, 256, 0, stream>>>(h3, wb4, nullptr, dinv, p4);
  k_agg<64, 16, 42, 2><<<6250, 256, 0, stream>>>(p4, q4, rowptr, cw, dinv, b4);

  // shared aggregation for mu/logstd heads (mode0)
  k_agg<64, 16, 0, 0><<<6250, 256, 0, stream>>>(q4, aggh4, rowptr, cw, dinv, nullptr);

  k_final<<<391, 256, 0, stream>>>(aggh4, Wmu, bmu, Wls, bls, eps, (float*)d_out);
}

// Round 6
// 560.972 us; speedup vs baseline: 1.3602x; 1.1313x over previous
//
#include <hip/hip_runtime.h>

#define NN 100000
#define NE 1600000
#define MP 100096   // padded node count (multiple of 64, >= 1564*64)
#define NB 782      // ceil(NN/128) buckets of 128 nodes
#define CHUNK 8192  // edges per bin1 block

typedef short  short8 __attribute__((ext_vector_type(8)));   // 8 bf16 (4 VGPRs)
typedef float  f32x4  __attribute__((ext_vector_type(4)));
typedef float  f32x2  __attribute__((ext_vector_type(2)));

#if defined(__has_builtin)
# if __has_builtin(__builtin_amdgcn_cvt_pk_f32_fp8) && __has_builtin(__builtin_amdgcn_cvt_pk_fp8_f32)
#  define HW_FP8 1
# endif
#endif

__device__ __forceinline__ unsigned short f2bf(float f){
  unsigned int u = __float_as_uint(f);
  u += 0x7fffu + ((u >> 16) & 1u);          // RNE
  return (unsigned short)(u >> 16);
}
__device__ __forceinline__ float bfl(unsigned int v){ return __uint_as_float((v & 0xffffu) << 16); }
__device__ __forceinline__ float bfh(unsigned int v){ return __uint_as_float(v & 0xffff0000u); }
__device__ __forceinline__ float bf1(unsigned short v){ return __uint_as_float(((unsigned int)v) << 16); }

// ---------------- fp8 e4m3 (OCP) helpers ----------------

__device__ __forceinline__ void dec4(unsigned int v, float f[4]){
#ifdef HW_FP8
  f32x2 lo = __builtin_amdgcn_cvt_pk_f32_fp8((int)v, false);
  f32x2 hi = __builtin_amdgcn_cvt_pk_f32_fp8((int)v, true);
  f[0] = lo[0]; f[1] = lo[1]; f[2] = hi[0]; f[3] = hi[1];
#else
  #pragma unroll
  for (int k = 0; k < 4; ++k){
    unsigned b = (v >> (8 * k)) & 0xffu;
    int em = b & 0x7f;
    float m = (em < 8) ? (float)em * 0.001953125f
                       : __uint_as_float((unsigned)((((em >> 3) + 120) << 23) | ((em & 7) << 20)));
    f[k] = (b & 0x80) ? -m : m;
  }
#endif
}

#ifndef HW_FP8
__device__ __forceinline__ unsigned int enc1m(float v){
  unsigned u = __float_as_uint(v);
  unsigned s = (u >> 24) & 0x80u;
  float av = fabsf(v);
  if (!(av >= 0.0009765625f)) return s;            // underflow -> +-0
  if (av >= 448.0f) return s | 0x7eu;              // clamp to max normal
  if (av < 0.015625f){                             // denormal, step 2^-9
    int q = (int)rintf(av * 512.0f);
    return s | (unsigned)q;
  }
  unsigned au = u & 0x7fffffffu;
  au += 0x7ffffu + ((au >> 20) & 1u);              // RNE into 3-bit mantissa
  int ex = (int)(au >> 23) - 127;
  unsigned man = (au >> 20) & 7u;
  if (ex > 8) return s | 0x7eu;
  return s | (unsigned)((ex + 7) << 3) | man;
}
#endif

__device__ __forceinline__ unsigned int enc1(float v){
#ifdef HW_FP8
  return (unsigned int)__builtin_amdgcn_cvt_pk_fp8_f32(v, 0.0f, 0, false) & 0xffu;
#else
  return enc1m(v);
#endif
}

__device__ __forceinline__ unsigned int enc4(float a, float b, float c, float d){
#ifdef HW_FP8
  int lo = __builtin_amdgcn_cvt_pk_fp8_f32(a, b, 0, false);
  return (unsigned int)__builtin_amdgcn_cvt_pk_fp8_f32(c, d, lo, true);
#else
  return enc1m(a) | (enc1m(b) << 8) | (enc1m(c) << 16) | (enc1m(d) << 24);
#endif
}

// ---------------- graph build ----------------

__global__ __launch_bounds__(256) void k_hist(const int* __restrict__ dst, int* __restrict__ deg){
  int e = blockIdx.x * 256 + threadIdx.x;
  if (e < NE) atomicAdd(&deg[dst[e]], 1);
}

__global__ __launch_bounds__(256) void k_scan1(const int* __restrict__ deg, int* __restrict__ rp,
                                               int* __restrict__ part){
  __shared__ int sh[256];
  int t = threadIdx.x;
  int base = blockIdx.x * 1024 + t * 4;
  int v0 = (base     < NN) ? deg[base]     : 0;
  int v1 = (base + 1 < NN) ? deg[base + 1] : 0;
  int v2 = (base + 2 < NN) ? deg[base + 2] : 0;
  int v3 = (base + 3 < NN) ? deg[base + 3] : 0;
  int s = v0 + v1 + v2 + v3;
  sh[t] = s; __syncthreads();
  for (int off = 1; off < 256; off <<= 1){
    int val = sh[t];
    int add = (t >= off) ? sh[t - off] : 0;
    __syncthreads();
    sh[t] = val + add;
    __syncthreads();
  }
  int excl = sh[t] - s;
  if (t == 255) part[blockIdx.x] = sh[255];
  if (base     < NN) rp[base]     = excl;
  if (base + 1 < NN) rp[base + 1] = excl + v0;
  if (base + 2 < NN) rp[base + 2] = excl + v0 + v1;
  if (base + 3 < NN) rp[base + 3] = excl + v0 + v1 + v2;
}

__global__ __launch_bounds__(128) void k_scan2(int* __restrict__ part, int* __restrict__ rp, int nb){
  __shared__ int sh[128];
  int t = threadIdx.x;
  int v = (t < nb) ? part[t] : 0;
  sh[t] = v; __syncthreads();
  for (int off = 1; off < 128; off <<= 1){
    int val = sh[t];
    int add = (t >= off) ? sh[t - off] : 0;
    __syncthreads();
    sh[t] = val + add;
    __syncthreads();
  }
  if (t < nb) part[t] = sh[t] - v;     // exclusive
  if (t == 0) rp[NN] = NE;
}

// weight repack helper: MFMA B-frag order
// idx = ((ks*(Np/16)+nt)*64 + lane)*8 + j ; element = W[ks*32+(lane>>4)*8+j][nt*16+(lane&15)]
__device__ __forceinline__ void pack1(const float* __restrict__ W, unsigned short* __restrict__ dst,
                                      int din, int dout, int Np, int idx){
  int j = idx & 7;
  int l = (idx >> 3) & 63;
  int f = idx >> 9;
  int ntiles = Np >> 4;
  int nt = f % ntiles;
  int ks = f / ntiles;
  int k = ks * 32 + (l >> 4) * 8 + j;
  int n = nt * 16 + (l & 15);
  float v = (k < din && n < dout) ? W[k * dout + n] : 0.0f;
  dst[idx] = f2bf(v);
}

// fused: scan3 apply + dinv + binit  |  gx prescale (fp8)  |  weight repack
__global__ __launch_bounds__(256) void k_aux(int* __restrict__ rp, const int* __restrict__ part,
                                             const int* __restrict__ deg, const float* __restrict__ x,
                                             float* __restrict__ dinv, int* __restrict__ bcur,
                                             unsigned int* __restrict__ gx,
                                             const float* __restrict__ W1, unsigned short* __restrict__ d1,
                                             const float* __restrict__ W2, unsigned short* __restrict__ d2,
                                             const float* __restrict__ W3, unsigned short* __restrict__ d3,
                                             const float* __restrict__ W4, unsigned short* __restrict__ d4){
  if (blockIdx.x < 391){
    int i = blockIdx.x * 256 + threadIdx.x;
    if (i < NN){
      int v = rp[i] + part[i >> 10];
      rp[i] = v;
      dinv[i] = rsqrtf((float)deg[i] + 1.0f);
      if ((i & 127) == 0) bcur[i >> 7] = v;
    }
  } else if (blockIdx.x < 6641){
    int idx = (blockIdx.x - 391) * 256 + threadIdx.x;   // NN*16 u32 outputs (4 fp8 each)
    if (idx >= NN * 16) return;
    int row = idx >> 4;
    int cu  = idx & 15;
    float di = rsqrtf((float)deg[row] + 1.0f);
    float v[4];
    #pragma unroll
    for (int k = 0; k < 4; ++k){
      int c = 4 * cu + k;
      v[k] = (c < 35) ? x[row * 35 + c] * di : 0.0f;
    }
    gx[idx] = enc4(v[0], v[1], v[2], v[3]);
  } else {
    int idx = (blockIdx.x - 6641) * 256 + threadIdx.x;
    if      (idx < 22528)  pack1(W1, d1, 35, 336, 352, idx);
    else if (idx < 90112)  pack1(W2, d2, 336, 168, 192, idx - 22528);
    else if (idx < 108544) pack1(W3, d3, 168, 84, 96, idx - 90112);
    else if (idx < 114688) pack1(W4, d4, 84, 42, 64, idx - 108544);
  }
}

// Phase 1: bucket-sort edges into tmp (bucket = dst>>7).
__global__ __launch_bounds__(256) void k_bin1(const int* __restrict__ src, const int* __restrict__ dst,
                                              int* __restrict__ bcur, int2* __restrict__ tmp){
  __shared__ int cnt[NB];
  __shared__ int base[NB];
  __shared__ int pos[NB];
  int t = threadIdx.x;
  int e0 = blockIdx.x * CHUNK;
  int e1 = min(e0 + CHUNK, NE);
  for (int i = t; i < NB; i += 256){ cnt[i] = 0; pos[i] = 0; }
  __syncthreads();
  for (int e = e0 + t; e < e1; e += 256)
    atomicAdd(&cnt[dst[e] >> 7], 1);
  __syncthreads();
  for (int i = t; i < NB; i += 256){
    int c = cnt[i];
    base[i] = (c > 0) ? atomicAdd(&bcur[i], c) : 0;
  }
  __syncthreads();
  for (int e = e0 + t; e < e1; e += 256){
    int s = src[e], d = dst[e];
    int b = d >> 7;
    int p = base[b] + atomicAdd(&pos[b], 1);
    tmp[p] = make_int2(s, d);
  }
}

// Phase 2: place edges at final CSR slots (per-node cursors in LDS).
__global__ __launch_bounds__(256) void k_bin2(const int* __restrict__ rp, const int2* __restrict__ tmp,
                                              int* __restrict__ cw){
  __shared__ int cur[128];
  int b = blockIdx.x;
  int n0 = b << 7;
  int n1 = min(n0 + 128, NN);
  int t = threadIdx.x;
  int E0 = rp[n0], E1 = rp[n1];
  if (t < 128){
    int n = n0 + t;
    cur[t] = (n < NN) ? rp[n] : 0;
  }
  __syncthreads();
  for (int e = E0 + t; e < E1; e += 256){
    int2 p = tmp[e];
    int slot = atomicAdd(&cur[p.y - n0], 1);
    cw[slot] = p.x;
  }
}

// ---------------- fp8-input aggregation ----------------
// core = dinv[i]*(g[i] + sum_{j in N(i)} g[j])
// MODE 0: out = core ; MODE 1: out = relu(core + b) ; MODE 2: out = dinv*relu(core + b)
// input rows SPB bytes fp8; output rows OUTC cols bf16. 16 lanes/row, u32 granule.

template<int SPB, int OUTC, int DOUT, int MODE>
__global__ __launch_bounds__(256) void k_aggf8(const unsigned char* __restrict__ Pin,
                                               unsigned short* __restrict__ Hout,
                                               const int* __restrict__ rp, const int* __restrict__ cw,
                                               const float* __restrict__ dinv, const float* __restrict__ bias){
  constexpr int L  = 16;
  constexpr int U  = SPB / 4;           // u32 per row
  constexpr int CH = U / L;             // u32 chunks per lane
  constexpr int UN = (CH == 1) ? 8 : 4;
  int g = blockIdx.x * 16 + (threadIdx.x >> 4);
  int c = threadIdx.x & 15;
  if (g >= NN) return;
  int e0 = rp[g], e1 = rp[g + 1];
  const unsigned int* __restrict__ P = (const unsigned int*)Pin;

  float a[CH][4];
  {
    const unsigned int* r = P + (size_t)g * U;
    #pragma unroll
    for (int ch = 0; ch < CH; ++ch) dec4(r[ch * L + c], a[ch]);
  }

  int e = e0;
  if (e + UN <= e1){
    int s[UN];
    #pragma unroll
    for (int u = 0; u < UN; ++u) s[u] = cw[e + u];
    while (true){
      unsigned int v[UN][CH];
      #pragma unroll
      for (int u = 0; u < UN; ++u){
        const unsigned int* r = P + (size_t)s[u] * U;
        #pragma unroll
        for (int ch = 0; ch < CH; ++ch) v[u][ch] = r[ch * L + c];
      }
      int e2 = e + UN;
      bool more = (e2 + UN <= e1);
      int s2[UN];
      if (more){
        #pragma unroll
        for (int u = 0; u < UN; ++u) s2[u] = cw[e2 + u];
      }
      #pragma unroll
      for (int u = 0; u < UN; ++u){
        #pragma unroll
        for (int ch = 0; ch < CH; ++ch){
          float f[4]; dec4(v[u][ch], f);
          a[ch][0] += f[0]; a[ch][1] += f[1]; a[ch][2] += f[2]; a[ch][3] += f[3];
        }
      }
      e = e2;
      if (!more) break;
      #pragma unroll
      for (int u = 0; u < UN; ++u) s[u] = s2[u];
    }
  }
  for (; e < e1; ++e){
    const unsigned int* r = P + (size_t)cw[e] * U;
    #pragma unroll
    for (int ch = 0; ch < CH; ++ch){
      float f[4]; dec4(r[ch * L + c], f);
      a[ch][0] += f[0]; a[ch][1] += f[1]; a[ch][2] += f[2]; a[ch][3] += f[3];
    }
  }

  float di = dinv[g];
  uint2* orow = (uint2*)Hout + (size_t)g * (OUTC / 4);
  #pragma unroll
  for (int ch = 0; ch < CH; ++ch){
    int colbase = (ch * L + c) * 4;
    float f0 = a[ch][0] * di, f1 = a[ch][1] * di, f2 = a[ch][2] * di, f3 = a[ch][3] * di;
    if (MODE >= 1){
      f0 += (colbase     < DOUT) ? bias[colbase]     : 0.0f;
      f1 += (colbase + 1 < DOUT) ? bias[colbase + 1] : 0.0f;
      f2 += (colbase + 2 < DOUT) ? bias[colbase + 2] : 0.0f;
      f3 += (colbase + 3 < DOUT) ? bias[colbase + 3] : 0.0f;
      f0 = fmaxf(f0, 0.0f); f1 = fmaxf(f1, 0.0f);
      f2 = fmaxf(f2, 0.0f); f3 = fmaxf(f3, 0.0f);
      if (MODE == 2){ f0 *= di; f1 *= di; f2 *= di; f3 *= di; }
    }
    if (colbase < OUTC){
      uint2 o;
      o.x = (unsigned int)f2bf(f0) | ((unsigned int)f2bf(f1) << 16);
      o.y = (unsigned int)f2bf(f2) | ((unsigned int)f2bf(f3) << 16);
      orow[ch * L + c] = o;
    }
  }
}

// ---------------- bf16-input aggregation (heads path) ----------------

template<int SP, int L, int DOUT, int MODE>
__global__ __launch_bounds__(256) void k_agg(const unsigned short* __restrict__ Hin,
                                             unsigned short* __restrict__ Hout,
                                             const int* __restrict__ rp, const int* __restrict__ cw,
                                             const float* __restrict__ dinv, const float* __restrict__ bias){
  constexpr int RPB = 256 / L;
  constexpr int U2  = SP / 4;
  constexpr int CH  = U2 / L;
  constexpr int UN  = (CH == 1) ? 8 : 4;
  int g = blockIdx.x * RPB + (threadIdx.x / L);
  int c = threadIdx.x % L;
  if (g >= NN) return;
  int e0 = rp[g], e1 = rp[g + 1];
  const uint2* __restrict__ H = (const uint2*)Hin;

  float a0[CH], a1[CH], a2[CH], a3[CH];
  const uint2* sr = H + (size_t)g * U2;
  #pragma unroll
  for (int ch = 0; ch < CH; ++ch){
    uint2 v = sr[ch * L + c];
    a0[ch] = bfl(v.x); a1[ch] = bfh(v.x);
    a2[ch] = bfl(v.y); a3[ch] = bfh(v.y);
  }

  int e = e0;
  if (e + UN <= e1){
    int s[UN];
    #pragma unroll
    for (int u = 0; u < UN; ++u) s[u] = cw[e + u];
    while (true){
      uint2 v[UN][CH];
      #pragma unroll
      for (int u = 0; u < UN; ++u){
        const uint2* r = H + (size_t)s[u] * U2;
        #pragma unroll
        for (int ch = 0; ch < CH; ++ch) v[u][ch] = r[ch * L + c];
      }
      int e2 = e + UN;
      bool more = (e2 + UN <= e1);
      int s2[UN];
      if (more){
        #pragma unroll
        for (int u = 0; u < UN; ++u) s2[u] = cw[e2 + u];
      }
      #pragma unroll
      for (int u = 0; u < UN; ++u){
        #pragma unroll
        for (int ch = 0; ch < CH; ++ch){
          a0[ch] += bfl(v[u][ch].x); a1[ch] += bfh(v[u][ch].x);
          a2[ch] += bfl(v[u][ch].y); a3[ch] += bfh(v[u][ch].y);
        }
      }
      e = e2;
      if (!more) break;
      #pragma unroll
      for (int u = 0; u < UN; ++u) s[u] = s2[u];
    }
  }
  for (; e < e1; ++e){
    const uint2* r = H + (size_t)cw[e] * U2;
    #pragma unroll
    for (int ch = 0; ch < CH; ++ch){
      uint2 v = r[ch * L + c];
      a0[ch] += bfl(v.x); a1[ch] += bfh(v.x);
      a2[ch] += bfl(v.y); a3[ch] += bfh(v.y);
    }
  }

  float di = dinv[g];
  uint2* orow = (uint2*)Hout + (size_t)g * U2;
  #pragma unroll
  for (int ch = 0; ch < CH; ++ch){
    float f0 = a0[ch] * di, f1 = a1[ch] * di, f2 = a2[ch] * di, f3 = a3[ch] * di;
    if (MODE >= 1){
      int fe = 4 * (ch * L + c);
      f0 += (fe     < DOUT) ? bias[fe]     : 0.0f;
      f1 += (fe + 1 < DOUT) ? bias[fe + 1] : 0.0f;
      f2 += (fe + 2 < DOUT) ? bias[fe + 2] : 0.0f;
      f3 += (fe + 3 < DOUT) ? bias[fe + 3] : 0.0f;
      f0 = fmaxf(f0, 0.0f); f1 = fmaxf(f1, 0.0f);
      f2 = fmaxf(f2, 0.0f); f3 = fmaxf(f3, 0.0f);
      if (MODE == 2){ f0 *= di; f1 *= di; f2 *= di; f3 *= di; }
    }
    uint2 o;
    o.x = (unsigned int)f2bf(f0) | ((unsigned int)f2bf(f1) << 16);
    o.y = (unsigned int)f2bf(f2) | ((unsigned int)f2bf(f3) << 16);
    orow[ch * L + c] = o;
  }
}

// ---------------- MFMA matmul: C[M,NP] = A[M,SPA(K)] * Bpacked ----------------
// EPI 0: bias+relu ; EPI 1: scale by dinv[row].  F8: fp8 byte out. CSTB: C row stride bytes.

template<int K, int NP, int DOUT, int SPA, int EPI, int F8, int CSTB>
__global__ __launch_bounds__(256) void k_mm(const unsigned short* __restrict__ A,
                                            const unsigned short* __restrict__ Bp,
                                            const float* __restrict__ bias,
                                            const float* __restrict__ dinv,
                                            unsigned char* __restrict__ C){
  constexpr int NT  = NP / 16;
  constexpr int NT2 = NP / 32;
  int l   = threadIdx.x & 63;
  int wid = threadIdx.x >> 6;
  int wr = wid >> 1, wc = wid & 1;
  int r0 = blockIdx.x * 64 + wr * 32;
  int n0 = wc * (NP / 2);
  int lr = l & 15, lk = l >> 4;
  const short8* __restrict__ Af = (const short8*)A;
  const short8* __restrict__ Bf = (const short8*)Bp;
  f32x4 acc[2][NT2];
  #pragma unroll
  for (int m = 0; m < 2; ++m)
    #pragma unroll
    for (int t = 0; t < NT2; ++t) acc[m][t] = (f32x4){0.f, 0.f, 0.f, 0.f};

  for (int ks = 0; ks < K / 32; ++ks){
    short8 a0 = Af[((r0      + lr) * SPA + ks * 32 + lk * 8) >> 3];
    short8 a1 = Af[((r0 + 16 + lr) * SPA + ks * 32 + lk * 8) >> 3];
    const short8* bp = Bf + (ks * NT + (n0 >> 4)) * 64 + l;
    #pragma unroll
    for (int t = 0; t < NT2; ++t){
      short8 b = bp[t * 64];
      acc[0][t] = __builtin_amdgcn_mfma_f32_16x16x32_bf16(a0, b, acc[0][t], 0, 0, 0);
      acc[1][t] = __builtin_amdgcn_mfma_f32_16x16x32_bf16(a1, b, acc[1][t], 0, 0, 0);
    }
  }
  // C/D layout: col = lane&15, row = (lane>>4)*4 + j   [m89-verified]
  int rb = lk * 4;
  #pragma unroll
  for (int m = 0; m < 2; ++m){
    #pragma unroll
    for (int t = 0; t < NT2; ++t){
      int col = n0 + t * 16 + lr;
      float bv = 0.0f;
      if (EPI == 0) bv = (col < DOUT) ? bias[col] : 0.0f;
      #pragma unroll
      for (int j = 0; j < 4; ++j){
        int row = r0 + m * 16 + rb + j;
        if (row < NN){
          float v = acc[m][t][j];
          if (EPI == 0) v = fmaxf(v + bv, 0.0f);
          else          v = v * dinv[row];
          if (F8) C[(size_t)row * CSTB + col] = (unsigned char)enc1(v);
          else    *(unsigned short*)(C + (size_t)row * CSTB + 2 * col) = f2bf(v);
        }
      }
    }
  }
}

// ---------------- final: mu/logstd matmuls + reparam + log_softmax ----------------

__global__ __launch_bounds__(256) void k_final(const unsigned short* __restrict__ aggh4,
                                               const float* __restrict__ Wmu, const float* __restrict__ bmu,
                                               const float* __restrict__ Wls, const float* __restrict__ bls,
                                               const float* __restrict__ eps, float* __restrict__ out){
  __shared__ float sWmu[42 * 21];
  __shared__ float sWls[42 * 21];
  __shared__ float sbmu[21];
  __shared__ float sbls[21];
  for (int u = threadIdx.x; u < 882; u += 256){ sWmu[u] = Wmu[u]; sWls[u] = Wls[u]; }
  if (threadIdx.x < 21){ sbmu[threadIdx.x] = bmu[threadIdx.x]; sbls[threadIdx.x] = bls[threadIdx.x]; }
  __syncthreads();

  int i = blockIdx.x * 256 + threadIdx.x;
  if (i >= NN) return;

  float mu[21], ls[21];
  #pragma unroll
  for (int j = 0; j < 21; ++j){ mu[j] = sbmu[j]; ls[j] = sbls[j]; }

  const unsigned short* arow = aggh4 + (size_t)i * 64;
  for (int k = 0; k < 42; ++k){
    float ak = bf1(arow[k]);
    #pragma unroll
    for (int j = 0; j < 21; ++j){
      mu[j] += ak * sWmu[k * 21 + j];
      ls[j] += ak * sWls[k * 21 + j];
    }
  }
  float zv[21];
  float mx = -3.4e38f;
  #pragma unroll
  for (int j = 0; j < 21; ++j){
    float l2 = fminf(ls[j], 10.0f);
    float zj = mu[j] + eps[(size_t)i * 21 + j] * __expf(l2);
    zv[j] = zj;
    mx = fmaxf(mx, zj);
  }
  float ssum = 0.f;
  #pragma unroll
  for (int j = 0; j < 21; ++j) ssum += __expf(zv[j] - mx);
  float lse = mx + __logf(ssum);
  #pragma unroll
  for (int j = 0; j < 21; ++j) out[(size_t)i * 21 + j] = zv[j] - lse;
}

// ---------------- workspace layout (bytes, 512-aligned) ----------------

constexpr size_t OFF_ROWPTR = 0;           // 401,408
constexpr size_t OFF_DEG    = 401408;      // 400,896
constexpr size_t OFF_DINV   = 802304;      // 400,896
constexpr size_t OFF_PART   = 1203200;     // 512
constexpr size_t OFF_BCUR   = 1203712;     // 3,584
constexpr size_t OFF_CW     = 1207296;     // 6,400,512
constexpr size_t OFF_TMP    = 13607808;    // 12,800,512
constexpr size_t OFF_WB1    = 26408320;    // 45,056
constexpr size_t OFF_WB2    = 26453376;    // 135,168
constexpr size_t OFF_WB3    = 26588544;    // 36,864
constexpr size_t OFF_WB4    = 26625408;    // 12,288
// region A [26637696, 45856640): gx fp8 (aux->agg1) ; p2 fp8 (mm2->agg2) ; q4 bf16 (agg4->agg5)
constexpr size_t OFF_GX     = 26637696;    // MP*64   = 6,406,144
constexpr size_t OFF_P2     = 26637696;    // MP*192  = 19,218,432
constexpr size_t OFF_Q4     = 26637696;    // MP*64*2 = 12,812,288
constexpr size_t OFF_AGGX   = 33044352;    // MP*64*2 (aux/agg1->mm1; dead before mm2)
// region B [45857152, ...): h1 (mm1->mm2) ; then h2 (agg2->mm3) ; then aggh4 (agg5->final)
constexpr size_t OFF_H1     = 45857152;    // MP*352*2 = 70,468,096 reserved
constexpr size_t OFF_H2     = 45857152;    // MP*192*2 = 38,436,864
constexpr size_t OFF_AGGH4  = 45857152;    // MP*64*2
constexpr size_t OFF_P3     = 84294528;    // MP*128 = 12,812,800 (mm3->agg3); p4 reuses
constexpr size_t OFF_P4     = 84294528;    // MP*64
constexpr size_t OFF_H3     = 97107328;    // MP*96*2 = 19,218,944 ; end ~116.3 MB

extern "C" void kernel_launch(void* const* d_in, const int* in_sizes, int n_in,
                              void* d_out, int out_size, void* d_ws, size_t ws_size,
                              hipStream_t stream){
  (void)in_sizes; (void)n_in; (void)out_size; (void)ws_size;
  const float* x    = (const float*)d_in[0];
  const int*   ei   = (const int*)d_in[1];
  const float* eps  = (const float*)d_in[2];
  const float* W1   = (const float*)d_in[3];  const float* b1  = (const float*)d_in[4];
  const float* W2   = (const float*)d_in[5];  const float* b2  = (const float*)d_in[6];
  const float* W3   = (const float*)d_in[7];  const float* b3  = (const float*)d_in[8];
  const float* W4   = (const float*)d_in[9];  const float* b4  = (const float*)d_in[10];
  const float* Wmu  = (const float*)d_in[11]; const float* bmu = (const float*)d_in[12];
  const float* Wls  = (const float*)d_in[13]; const float* bls = (const float*)d_in[14];

  char* ws = (char*)d_ws;
  int*   rowptr = (int*)(ws + OFF_ROWPTR);
  int*   deg    = (int*)(ws + OFF_DEG);
  float* dinv   = (float*)(ws + OFF_DINV);
  int*   part   = (int*)(ws + OFF_PART);
  int*   bcur   = (int*)(ws + OFF_BCUR);
  int*   cw     = (int*)(ws + OFF_CW);
  int2*  tmp    = (int2*)(ws + OFF_TMP);
  unsigned short* wb1   = (unsigned short*)(ws + OFF_WB1);
  unsigned short* wb2   = (unsigned short*)(ws + OFF_WB2);
  unsigned short* wb3   = (unsigned short*)(ws + OFF_WB3);
  unsigned short* wb4   = (unsigned short*)(ws + OFF_WB4);
  unsigned char*  gx    = (unsigned char*)(ws + OFF_GX);
  unsigned short* aggx  = (unsigned short*)(ws + OFF_AGGX);
  unsigned short* h1    = (unsigned short*)(ws + OFF_H1);
  unsigned char*  p2    = (unsigned char*)(ws + OFF_P2);
  unsigned short* h2    = (unsigned short*)(ws + OFF_H2);
  unsigned char*  p3    = (unsigned char*)(ws + OFF_P3);
  unsigned short* h3    = (unsigned short*)(ws + OFF_H3);
  unsigned char*  p4    = (unsigned char*)(ws + OFF_P4);
  unsigned short* q4    = (unsigned short*)(ws + OFF_Q4);
  unsigned short* aggh4 = (unsigned short*)(ws + OFF_AGGH4);

  const int* src = ei;
  const int* dst = ei + NE;

  hipMemsetAsync(deg, 0, NN * sizeof(int), stream);
  k_hist <<<6250, 256, 0, stream>>>(dst, deg);
  k_scan1<<<98,   256, 0, stream>>>(deg, rowptr, part);
  k_scan2<<<1,    128, 0, stream>>>(part, rowptr, 98);
  k_aux  <<<7090, 256, 0, stream>>>(rowptr, part, deg, x, dinv, bcur, (unsigned int*)gx,
                                    W1, wb1, W2, wb2, W3, wb3, W4, wb4);
  k_bin1 <<<196,  256, 0, stream>>>(src, dst, bcur, tmp);
  k_bin2 <<<NB,   256, 0, stream>>>(rowptr, tmp, cw);

  // conv1: aggregate fp8-prescaled x, matmul with bias+relu (bf16 out)
  k_aggf8<64, 64, 0, 0><<<6250, 256, 0, stream>>>(gx, aggx, rowptr, cw, dinv, nullptr);
  k_mm<64, 352, 336, 64, 0, 0, 704><<<1564, 256, 0, stream>>>(aggx, wb1, b1, nullptr, (unsigned char*)h1);

  // conv2: matmul (dinv epilogue, fp8 out), aggregate fp8 -> bf16 h2
  k_mm<352, 192, 168, 352, 1, 1, 192><<<1564, 256, 0, stream>>>(h1, wb2, nullptr, dinv, p2);
  k_aggf8<192, 192, 168, 1><<<6250, 256, 0, stream>>>(p2, h2, rowptr, cw, dinv, b2);

  // conv3: fp8 rows padded to 128B (pad bytes decoded+discarded)
  k_mm<192, 96, 84, 192, 1, 1, 128><<<1564, 256, 0, stream>>>(h2, wb3, nullptr, dinv, p3);
  k_aggf8<128, 96, 84, 1><<<6250, 256, 0, stream>>>(p3, h3, rowptr, cw, dinv, b3);

  // conv4: fp8 64B rows; agg writes q4 = dinv*relu(core+b4) in bf16
  k_mm<96, 64, 42, 96, 1, 1, 64><<<1564, 256, 0, stream>>>(h3, wb4, nullptr, dinv, p4);
  k_aggf8<64, 64, 42, 2><<<6250, 256, 0, stream>>>(p4, q4, rowptr, cw, dinv, b4);

  // heads aggregation stays bf16
  k_agg<64, 16, 0, 0><<<6250, 256, 0, stream>>>(q4, aggh4, rowptr, cw, dinv, nullptr);

  k_final<<<391, 256, 0, stream>>>(aggh4, Wmu, bmu, Wls, bls, eps, (float*)d_out);
}

// Round 7
// 496.452 us; speedup vs baseline: 1.5370x; 1.1300x over previous
//
#include <hip/hip_runtime.h>

#define NN 100000
#define NE 1600000
#define MP 100096   // padded node count (multiple of 64, >= 1564*64)
#define NB 782      // ceil(NN/128) buckets of 128 nodes
#define BSL 3072    // fixed tmp slots per bucket (mean 2046, std ~45)
#define CHUNK 8192  // edges per bin1 block

typedef short  short8 __attribute__((ext_vector_type(8)));   // 8 bf16 (4 VGPRs)
typedef float  f32x4  __attribute__((ext_vector_type(4)));
typedef float  f32x2  __attribute__((ext_vector_type(2)));

#if defined(__has_builtin)
# if __has_builtin(__builtin_amdgcn_cvt_pk_f32_fp8) && __has_builtin(__builtin_amdgcn_cvt_pk_fp8_f32)
#  define HW_FP8 1
# endif
#endif

__device__ __forceinline__ unsigned short f2bf(float f){
  unsigned int u = __float_as_uint(f);
  u += 0x7fffu + ((u >> 16) & 1u);          // RNE
  return (unsigned short)(u >> 16);
}
__device__ __forceinline__ float bfl(unsigned int v){ return __uint_as_float((v & 0xffffu) << 16); }
__device__ __forceinline__ float bfh(unsigned int v){ return __uint_as_float(v & 0xffff0000u); }
__device__ __forceinline__ float bf1(unsigned short v){ return __uint_as_float(((unsigned int)v) << 16); }

// ---------------- fp8 e4m3 (OCP) helpers ----------------

__device__ __forceinline__ void dec4(unsigned int v, float f[4]){
#ifdef HW_FP8
  f32x2 lo = __builtin_amdgcn_cvt_pk_f32_fp8((int)v, false);
  f32x2 hi = __builtin_amdgcn_cvt_pk_f32_fp8((int)v, true);
  f[0] = lo[0]; f[1] = lo[1]; f[2] = hi[0]; f[3] = hi[1];
#else
  #pragma unroll
  for (int k = 0; k < 4; ++k){
    unsigned b = (v >> (8 * k)) & 0xffu;
    int em = b & 0x7f;
    float m = (em < 8) ? (float)em * 0.001953125f
                       : __uint_as_float((unsigned)((((em >> 3) + 120) << 23) | ((em & 7) << 20)));
    f[k] = (b & 0x80) ? -m : m;
  }
#endif
}

#ifndef HW_FP8
__device__ __forceinline__ unsigned int enc1m(float v){
  unsigned u = __float_as_uint(v);
  unsigned s = (u >> 24) & 0x80u;
  float av = fabsf(v);
  if (!(av >= 0.0009765625f)) return s;            // underflow -> +-0
  if (av >= 448.0f) return s | 0x7eu;              // clamp to max normal
  if (av < 0.015625f){                             // denormal, step 2^-9
    int q = (int)rintf(av * 512.0f);
    return s | (unsigned)q;
  }
  unsigned au = u & 0x7fffffffu;
  au += 0x7ffffu + ((au >> 20) & 1u);              // RNE into 3-bit mantissa
  int ex = (int)(au >> 23) - 127;
  unsigned man = (au >> 20) & 7u;
  if (ex > 8) return s | 0x7eu;
  return s | (unsigned)((ex + 7) << 3) | man;
}
#endif

__device__ __forceinline__ unsigned int enc1(float v){
#ifdef HW_FP8
  return (unsigned int)__builtin_amdgcn_cvt_pk_fp8_f32(v, 0.0f, 0, false) & 0xffu;
#else
  return enc1m(v);
#endif
}

__device__ __forceinline__ unsigned int enc4(float a, float b, float c, float d){
#ifdef HW_FP8
  int lo = __builtin_amdgcn_cvt_pk_fp8_f32(a, b, 0, false);
  return (unsigned int)__builtin_amdgcn_cvt_pk_fp8_f32(c, d, lo, true);
#else
  return enc1m(a) | (enc1m(b) << 8) | (enc1m(c) << 16) | (enc1m(d) << 24);
#endif
}

// ---------------- graph build (no node-level global atomics anywhere) ----------------

// Phase 1: bucket-sort edges into fixed 3072-slot regions of tmp (bucket = dst>>7).
// Per-block LDS counts -> one global atomicAdd per (block,bucket) -> burst writes.
__global__ __launch_bounds__(256) void k_bin1(const int* __restrict__ src, const int* __restrict__ dst,
                                              int* __restrict__ bcur, int2* __restrict__ tmp){
  __shared__ int cnt[NB];
  __shared__ int base[NB];
  __shared__ int pos[NB];
  int t = threadIdx.x;
  int e0 = blockIdx.x * CHUNK;
  int e1 = min(e0 + CHUNK, NE);
  for (int i = t; i < NB; i += 256){ cnt[i] = 0; pos[i] = 0; }
  __syncthreads();
  for (int e = e0 + t; e < e1; e += 256)
    atomicAdd(&cnt[dst[e] >> 7], 1);
  __syncthreads();
  for (int i = t; i < NB; i += 256){
    int c = cnt[i];
    base[i] = (c > 0) ? atomicAdd(&bcur[i], c) : 0;
  }
  __syncthreads();
  for (int e = e0 + t; e < e1; e += 256){
    int s = src[e], d = dst[e];
    int b = d >> 7;
    int p = b * BSL + base[b] + atomicAdd(&pos[b], 1);
    tmp[p] = make_int2(s, d);
  }
}

// exclusive scan of the 782 bucket counts -> CSR bucket bases
__global__ __launch_bounds__(256) void k_bscan(const int* __restrict__ bcur, int* __restrict__ bbase,
                                               int* __restrict__ rp){
  __shared__ int sh[256];
  int t = threadIdx.x;
  int b0 = t * 4;
  int v0 = (b0     < NB) ? bcur[b0]     : 0;
  int v1 = (b0 + 1 < NB) ? bcur[b0 + 1] : 0;
  int v2 = (b0 + 2 < NB) ? bcur[b0 + 2] : 0;
  int v3 = (b0 + 3 < NB) ? bcur[b0 + 3] : 0;
  int s = v0 + v1 + v2 + v3;
  sh[t] = s; __syncthreads();
  for (int off = 1; off < 256; off <<= 1){
    int val = sh[t];
    int add = (t >= off) ? sh[t - off] : 0;
    __syncthreads();
    sh[t] = val + add;
    __syncthreads();
  }
  int excl = sh[t] - s;
  if (b0     < NB) bbase[b0]     = excl;
  if (b0 + 1 < NB) bbase[b0 + 1] = excl + v0;
  if (b0 + 2 < NB) bbase[b0 + 2] = excl + v0 + v1;
  if (b0 + 3 < NB) bbase[b0 + 3] = excl + v0 + v1 + v2;
  if (t == 255){ bbase[NB] = sh[255]; rp[NN] = NE; }
}

// Phase 2: per bucket: LDS 128-bin histogram + LDS scan -> rowptr/dinv slices,
// then place edges into cw (per-node cursors in LDS; dense bucket-local writes).
__global__ __launch_bounds__(256) void k_bin2(const int2* __restrict__ tmp, const int* __restrict__ bbase,
                                              int* __restrict__ rp, float* __restrict__ dinv,
                                              int* __restrict__ cw){
  __shared__ int hist[128];
  __shared__ int cur[128];
  int b = blockIdx.x;
  int n0 = b << 7;
  int nn = min(128, NN - n0);
  int t = threadIdx.x;
  int B0 = bbase[b];
  int C  = bbase[b + 1] - B0;
  int E0 = b * BSL;
  if (t < 128) hist[t] = 0;
  __syncthreads();
  for (int e = t; e < C; e += 256)
    atomicAdd(&hist[tmp[E0 + e].y - n0], 1);
  __syncthreads();
  int val = (t < 128) ? hist[t] : 0;
  for (int off = 1; off < 128; off <<= 1){
    int add = (t < 128 && t >= off) ? hist[t - off] : 0;
    __syncthreads();
    if (t < 128) hist[t] += add;
    __syncthreads();
  }
  if (t < 128){
    int excl = hist[t] - val;
    int rpv = B0 + excl;
    cur[t] = rpv;
    if (t < nn){
      rp[n0 + t] = rpv;
      dinv[n0 + t] = rsqrtf((float)val + 1.0f);
    }
  }
  __syncthreads();
  for (int e = t; e < C; e += 256){
    int2 p = tmp[E0 + e];
    int slot = atomicAdd(&cur[p.y - n0], 1);
    cw[slot] = p.x;
  }
}

// ---------------- weight repack + gx prescale (fused) ----------------
// pack layout: idx = ((ks*(Np/16)+nt)*64 + lane)*8 + j ; element = W[ks*32+(lane>>4)*8+j][nt*16+(lane&15)]

__device__ __forceinline__ void pack1(const float* __restrict__ W, unsigned short* __restrict__ dst,
                                      int din, int dout, int Np, int idx){
  int j = idx & 7;
  int l = (idx >> 3) & 63;
  int f = idx >> 9;
  int ntiles = Np >> 4;
  int nt = f % ntiles;
  int ks = f / ntiles;
  int k = ks * 32 + (l >> 4) * 8 + j;
  int n = nt * 16 + (l & 15);
  float v = (k < din && n < dout) ? W[k * dout + n] : 0.0f;
  dst[idx] = f2bf(v);
}

__global__ __launch_bounds__(256) void k_gxpack(const float* __restrict__ x, const float* __restrict__ dinv,
                                                unsigned int* __restrict__ gx,
                                                const float* __restrict__ W1, unsigned short* __restrict__ d1,
                                                const float* __restrict__ W2, unsigned short* __restrict__ d2,
                                                const float* __restrict__ W3, unsigned short* __restrict__ d3,
                                                const float* __restrict__ W4, unsigned short* __restrict__ d4){
  if (blockIdx.x < 6250){
    int idx = blockIdx.x * 256 + threadIdx.x;   // NN*16 u32 outputs (4 fp8 each)
    if (idx >= NN * 16) return;
    int row = idx >> 4;
    int cu  = idx & 15;
    float di = dinv[row];
    float v[4];
    #pragma unroll
    for (int k = 0; k < 4; ++k){
      int c = 4 * cu + k;
      v[k] = (c < 35) ? x[row * 35 + c] * di : 0.0f;
    }
    gx[idx] = enc4(v[0], v[1], v[2], v[3]);
  } else {
    int idx = (blockIdx.x - 6250) * 256 + threadIdx.x;
    if      (idx < 22528)  pack1(W1, d1, 35, 336, 352, idx);
    else if (idx < 90112)  pack1(W2, d2, 336, 168, 192, idx - 22528);
    else if (idx < 108544) pack1(W3, d3, 168, 84, 96, idx - 90112);
    else if (idx < 114688) pack1(W4, d4, 84, 42, 64, idx - 108544);
  }
}

// ---------------- fp8-input aggregation ----------------
// core = dinv[i]*(g[i] + sum_{j in N(i)} g[j])
// MODE 0: out = core ; MODE 1: out = relu(core + b) ; MODE 2: out = dinv*relu(core + b)
// input rows SPB bytes fp8; output: bf16 (OUTF8=0) or fp8 (OUTF8=1), OUTC cols.

template<int SPB, int OUTC, int DOUT, int MODE, int OUTF8>
__global__ __launch_bounds__(256) void k_aggf8(const unsigned char* __restrict__ Pin,
                                               void* __restrict__ Hout,
                                               const int* __restrict__ rp, const int* __restrict__ cw,
                                               const float* __restrict__ dinv, const float* __restrict__ bias){
  constexpr int L  = 16;
  constexpr int U  = SPB / 4;           // u32 per row
  constexpr int CH = U / L;             // u32 chunks per lane
  constexpr int UN = (CH == 1) ? 8 : 4;
  int g = blockIdx.x * 16 + (threadIdx.x >> 4);
  int c = threadIdx.x & 15;
  if (g >= NN) return;
  int e0 = rp[g], e1 = rp[g + 1];
  const unsigned int* __restrict__ P = (const unsigned int*)Pin;

  float a[CH][4];
  {
    const unsigned int* r = P + (size_t)g * U;
    #pragma unroll
    for (int ch = 0; ch < CH; ++ch) dec4(r[ch * L + c], a[ch]);
  }

  int e = e0;
  if (e + UN <= e1){
    int s[UN];
    #pragma unroll
    for (int u = 0; u < UN; ++u) s[u] = cw[e + u];
    while (true){
      unsigned int v[UN][CH];
      #pragma unroll
      for (int u = 0; u < UN; ++u){
        const unsigned int* r = P + (size_t)s[u] * U;
        #pragma unroll
        for (int ch = 0; ch < CH; ++ch) v[u][ch] = r[ch * L + c];
      }
      int e2 = e + UN;
      bool more = (e2 + UN <= e1);
      int s2[UN];
      if (more){
        #pragma unroll
        for (int u = 0; u < UN; ++u) s2[u] = cw[e2 + u];
      }
      #pragma unroll
      for (int u = 0; u < UN; ++u){
        #pragma unroll
        for (int ch = 0; ch < CH; ++ch){
          float f[4]; dec4(v[u][ch], f);
          a[ch][0] += f[0]; a[ch][1] += f[1]; a[ch][2] += f[2]; a[ch][3] += f[3];
        }
      }
      e = e2;
      if (!more) break;
      #pragma unroll
      for (int u = 0; u < UN; ++u) s[u] = s2[u];
    }
  }
  for (; e < e1; ++e){
    const unsigned int* r = P + (size_t)cw[e] * U;
    #pragma unroll
    for (int ch = 0; ch < CH; ++ch){
      float f[4]; dec4(r[ch * L + c], f);
      a[ch][0] += f[0]; a[ch][1] += f[1]; a[ch][2] += f[2]; a[ch][3] += f[3];
    }
  }

  float di = dinv[g];
  #pragma unroll
  for (int ch = 0; ch < CH; ++ch){
    int colbase = (ch * L + c) * 4;
    float f0 = a[ch][0] * di, f1 = a[ch][1] * di, f2 = a[ch][2] * di, f3 = a[ch][3] * di;
    if (MODE >= 1){
      f0 += (colbase     < DOUT) ? bias[colbase]     : 0.0f;
      f1 += (colbase + 1 < DOUT) ? bias[colbase + 1] : 0.0f;
      f2 += (colbase + 2 < DOUT) ? bias[colbase + 2] : 0.0f;
      f3 += (colbase + 3 < DOUT) ? bias[colbase + 3] : 0.0f;
      f0 = fmaxf(f0, 0.0f); f1 = fmaxf(f1, 0.0f);
      f2 = fmaxf(f2, 0.0f); f3 = fmaxf(f3, 0.0f);
      if (MODE == 2){ f0 *= di; f1 *= di; f2 *= di; f3 *= di; }
    }
    if (colbase < OUTC){
      if (OUTF8){
        unsigned int* orow = (unsigned int*)Hout + (size_t)g * (OUTC / 4);
        orow[ch * L + c] = enc4(f0, f1, f2, f3);
      } else {
        uint2* orow = (uint2*)Hout + (size_t)g * (OUTC / 4);
        uint2 o;
        o.x = (unsigned int)f2bf(f0) | ((unsigned int)f2bf(f1) << 16);
        o.y = (unsigned int)f2bf(f2) | ((unsigned int)f2bf(f3) << 16);
        orow[ch * L + c] = o;
      }
    }
  }
}

// ---------------- MFMA matmul: C[M,NP] = A[M,SPA(K)] * Bpacked ----------------
// EPI 0: bias+relu ; EPI 1: scale by dinv[row].  F8: fp8 byte out. CSTB: C row stride bytes.

template<int K, int NP, int DOUT, int SPA, int EPI, int F8, int CSTB>
__global__ __launch_bounds__(256) void k_mm(const unsigned short* __restrict__ A,
                                            const unsigned short* __restrict__ Bp,
                                            const float* __restrict__ bias,
                                            const float* __restrict__ dinv,
                                            unsigned char* __restrict__ C){
  constexpr int NT  = NP / 16;
  constexpr int NT2 = NP / 32;
  int l   = threadIdx.x & 63;
  int wid = threadIdx.x >> 6;
  int wr = wid >> 1, wc = wid & 1;
  int r0 = blockIdx.x * 64 + wr * 32;
  int n0 = wc * (NP / 2);
  int lr = l & 15, lk = l >> 4;
  const short8* __restrict__ Af = (const short8*)A;
  const short8* __restrict__ Bf = (const short8*)Bp;
  f32x4 acc[2][NT2];
  #pragma unroll
  for (int m = 0; m < 2; ++m)
    #pragma unroll
    for (int t = 0; t < NT2; ++t) acc[m][t] = (f32x4){0.f, 0.f, 0.f, 0.f};

  for (int ks = 0; ks < K / 32; ++ks){
    short8 a0 = Af[((r0      + lr) * SPA + ks * 32 + lk * 8) >> 3];
    short8 a1 = Af[((r0 + 16 + lr) * SPA + ks * 32 + lk * 8) >> 3];
    const short8* bp = Bf + (ks * NT + (n0 >> 4)) * 64 + l;
    #pragma unroll
    for (int t = 0; t < NT2; ++t){
      short8 b = bp[t * 64];
      acc[0][t] = __builtin_amdgcn_mfma_f32_16x16x32_bf16(a0, b, acc[0][t], 0, 0, 0);
      acc[1][t] = __builtin_amdgcn_mfma_f32_16x16x32_bf16(a1, b, acc[1][t], 0, 0, 0);
    }
  }
  // C/D layout: col = lane&15, row = (lane>>4)*4 + j   [m89-verified]
  int rb = lk * 4;
  #pragma unroll
  for (int m = 0; m < 2; ++m){
    #pragma unroll
    for (int t = 0; t < NT2; ++t){
      int col = n0 + t * 16 + lr;
      float bv = 0.0f;
      if (EPI == 0) bv = (col < DOUT) ? bias[col] : 0.0f;
      #pragma unroll
      for (int j = 0; j < 4; ++j){
        int row = r0 + m * 16 + rb + j;
        if (row < NN){
          float v = acc[m][t][j];
          if (EPI == 0) v = fmaxf(v + bv, 0.0f);
          else          v = v * dinv[row];
          if (F8) C[(size_t)row * CSTB + col] = (unsigned char)enc1(v);
          else    *(unsigned short*)(C + (size_t)row * CSTB + 2 * col) = f2bf(v);
        }
      }
    }
  }
}

// ---------------- final: mu/logstd matmuls + reparam + log_softmax ----------------

__global__ __launch_bounds__(256) void k_final(const unsigned short* __restrict__ aggh4,
                                               const float* __restrict__ Wmu, const float* __restrict__ bmu,
                                               const float* __restrict__ Wls, const float* __restrict__ bls,
                                               const float* __restrict__ eps, float* __restrict__ out){
  __shared__ float sWmu[42 * 21];
  __shared__ float sWls[42 * 21];
  __shared__ float sbmu[21];
  __shared__ float sbls[21];
  for (int u = threadIdx.x; u < 882; u += 256){ sWmu[u] = Wmu[u]; sWls[u] = Wls[u]; }
  if (threadIdx.x < 21){ sbmu[threadIdx.x] = bmu[threadIdx.x]; sbls[threadIdx.x] = bls[threadIdx.x]; }
  __syncthreads();

  int i = blockIdx.x * 256 + threadIdx.x;
  if (i >= NN) return;

  float mu[21], ls[21];
  #pragma unroll
  for (int j = 0; j < 21; ++j){ mu[j] = sbmu[j]; ls[j] = sbls[j]; }

  const unsigned short* arow = aggh4 + (size_t)i * 64;
  for (int k = 0; k < 42; ++k){
    float ak = bf1(arow[k]);
    #pragma unroll
    for (int j = 0; j < 21; ++j){
      mu[j] += ak * sWmu[k * 21 + j];
      ls[j] += ak * sWls[k * 21 + j];
    }
  }
  float zv[21];
  float mx = -3.4e38f;
  #pragma unroll
  for (int j = 0; j < 21; ++j){
    float l2 = fminf(ls[j], 10.0f);
    float zj = mu[j] + eps[(size_t)i * 21 + j] * __expf(l2);
    zv[j] = zj;
    mx = fmaxf(mx, zj);
  }
  float ssum = 0.f;
  #pragma unroll
  for (int j = 0; j < 21; ++j) ssum += __expf(zv[j] - mx);
  float lse = mx + __logf(ssum);
  #pragma unroll
  for (int j = 0; j < 21; ++j) out[(size_t)i * 21 + j] = zv[j] - lse;
}

// ---------------- workspace layout (bytes, 512-aligned) ----------------

constexpr size_t OFF_ROWPTR = 0;           // 401,408
constexpr size_t OFF_DINV   = 401408;      // 401,408
constexpr size_t OFF_BCUR   = 802816;      // 3,584
constexpr size_t OFF_BBASE  = 806400;      // 3,584
constexpr size_t OFF_CW     = 809984;      // 6,400,512
constexpr size_t OFF_TMP    = 7210496;     // NB*BSL*8 = 19,218,432 ; ends 26,428,928
constexpr size_t OFF_WB1    = 26429440;    // 45,056
constexpr size_t OFF_WB2    = 26474496;    // 135,168
constexpr size_t OFF_WB3    = 26609664;    // 36,864
constexpr size_t OFF_WB4    = 26646528;    // 12,288 ; ends 26,658,816
// region A: gx fp8 (gxpack->agg1) ; p2 fp8 (mm2->agg2) ; q4 fp8 (agg4->agg5)
constexpr size_t OFF_GX     = 26659328;    // MP*64   = 6,406,144
constexpr size_t OFF_P2     = 26659328;    // MP*192  = 19,218,432 ; region ends 45,877,760
constexpr size_t OFF_Q4     = 26659328;    // MP*64
constexpr size_t OFF_AGGX   = 45878272;    // MP*64*2 = 12,812,288 ; ends 58,690,560
// region B: h1 (mm1->mm2) ; h2 (agg2->mm3) ; aggh4 (agg5->final)
constexpr size_t OFF_H1     = 58691072;    // MP*352*2 = 70,467,584 ; ends 129,158,656
constexpr size_t OFF_H2     = 58691072;    // MP*192*2
constexpr size_t OFF_AGGH4  = 58691072;    // MP*64*2
constexpr size_t OFF_P3     = 129159168;   // MP*128 = 12,812,288 (mm3->agg3); p4 alias
constexpr size_t OFF_P4     = 129159168;   // MP*64
constexpr size_t OFF_H3     = 141971968;   // MP*96*2 = 19,218,432 ; ends 161,190,400

extern "C" void kernel_launch(void* const* d_in, const int* in_sizes, int n_in,
                              void* d_out, int out_size, void* d_ws, size_t ws_size,
                              hipStream_t stream){
  (void)in_sizes; (void)n_in; (void)out_size; (void)ws_size;
  const float* x    = (const float*)d_in[0];
  const int*   ei   = (const int*)d_in[1];
  const float* eps  = (const float*)d_in[2];
  const float* W1   = (const float*)d_in[3];  const float* b1  = (const float*)d_in[4];
  const float* W2   = (const float*)d_in[5];  const float* b2  = (const float*)d_in[6];
  const float* W3   = (const float*)d_in[7];  const float* b3  = (const float*)d_in[8];
  const float* W4   = (const float*)d_in[9];  const float* b4  = (const float*)d_in[10];
  const float* Wmu  = (const float*)d_in[11]; const float* bmu = (const float*)d_in[12];
  const float* Wls  = (const float*)d_in[13]; const float* bls = (const float*)d_in[14];

  char* ws = (char*)d_ws;
  int*   rowptr = (int*)(ws + OFF_ROWPTR);
  float* dinv   = (float*)(ws + OFF_DINV);
  int*   bcur   = (int*)(ws + OFF_BCUR);
  int*   bbase  = (int*)(ws + OFF_BBASE);
  int*   cw     = (int*)(ws + OFF_CW);
  int2*  tmp    = (int2*)(ws + OFF_TMP);
  unsigned short* wb1   = (unsigned short*)(ws + OFF_WB1);
  unsigned short* wb2   = (unsigned short*)(ws + OFF_WB2);
  unsigned short* wb3   = (unsigned short*)(ws + OFF_WB3);
  unsigned short* wb4   = (unsigned short*)(ws + OFF_WB4);
  unsigned char*  gx    = (unsigned char*)(ws + OFF_GX);
  unsigned short* aggx  = (unsigned short*)(ws + OFF_AGGX);
  unsigned short* h1    = (unsigned short*)(ws + OFF_H1);
  unsigned char*  p2    = (unsigned char*)(ws + OFF_P2);
  unsigned short* h2    = (unsigned short*)(ws + OFF_H2);
  unsigned char*  p3    = (unsigned char*)(ws + OFF_P3);
  unsigned short* h3    = (unsigned short*)(ws + OFF_H3);
  unsigned char*  p4    = (unsigned char*)(ws + OFF_P4);
  unsigned char*  q4    = (unsigned char*)(ws + OFF_Q4);
  unsigned short* aggh4 = (unsigned short*)(ws + OFF_AGGH4);

  const int* src = ei;
  const int* dst = ei + NE;

  hipMemsetAsync(bcur, 0, NB * sizeof(int), stream);
  k_bin1 <<<196, 256, 0, stream>>>(src, dst, bcur, tmp);
  k_bscan<<<1,   256, 0, stream>>>(bcur, bbase, rowptr);
  k_bin2 <<<NB,  256, 0, stream>>>(tmp, bbase, rowptr, dinv, cw);
  k_gxpack<<<6698, 256, 0, stream>>>(x, dinv, (unsigned int*)gx,
                                     W1, wb1, W2, wb2, W3, wb3, W4, wb4);

  // conv1: aggregate fp8-prescaled x, matmul with bias+relu (bf16 out)
  k_aggf8<64, 64, 0, 0, 0><<<6250, 256, 0, stream>>>(gx, aggx, rowptr, cw, dinv, nullptr);
  k_mm<64, 352, 336, 64, 0, 0, 704><<<1564, 256, 0, stream>>>(aggx, wb1, b1, nullptr, (unsigned char*)h1);

  // conv2: matmul (dinv epilogue, fp8 out), aggregate fp8 -> bf16 h2
  k_mm<352, 192, 168, 352, 1, 1, 192><<<1564, 256, 0, stream>>>(h1, wb2, nullptr, dinv, p2);
  k_aggf8<192, 192, 168, 1, 0><<<6250, 256, 0, stream>>>(p2, h2, rowptr, cw, dinv, b2);

  // conv3: fp8 rows padded to 128B (pad bytes decoded+discarded)
  k_mm<192, 96, 84, 192, 1, 1, 128><<<1564, 256, 0, stream>>>(h2, wb3, nullptr, dinv, p3);
  k_aggf8<128, 96, 84, 1, 0><<<6250, 256, 0, stream>>>(p3, h3, rowptr, cw, dinv, b3);

  // conv4: fp8 64B rows; agg writes q4 = dinv*relu(core+b4) as fp8
  k_mm<96, 64, 42, 96, 1, 1, 64><<<1564, 256, 0, stream>>>(h3, wb4, nullptr, dinv, p4);
  k_aggf8<64, 64, 42, 2, 1><<<6250, 256, 0, stream>>>(p4, q4, rowptr, cw, dinv, b4);

  // heads aggregation: fp8 q4 -> bf16 aggh4
  k_aggf8<64, 64, 0, 0, 0><<<6250, 256, 0, stream>>>(q4, aggh4, rowptr, cw, dinv, nullptr);

  k_final<<<391, 256, 0, stream>>>(aggh4, Wmu, bmu, Wls, bls, eps, (float*)d_out);
}

// Round 8
// 460.349 us; speedup vs baseline: 1.6575x; 1.0784x over previous
//
#include <hip/hip_runtime.h>

#define NN 100000
#define NE 1600000
#define MP 100096   // padded node count (multiple of 64, >= 1564*64)
#define NB 782      // ceil(NN/128) buckets of 128 nodes
#define BSL 3072    // fixed tmp slots per bucket (mean 2046, std ~45)
#define CHUNK 8192  // edges per bin1 block

typedef short  short8 __attribute__((ext_vector_type(8)));   // 8 bf16 (4 VGPRs)
typedef float  f32x4  __attribute__((ext_vector_type(4)));
typedef float  f32x2  __attribute__((ext_vector_type(2)));

#if defined(__has_builtin)
# if __has_builtin(__builtin_amdgcn_cvt_pk_f32_fp8) && __has_builtin(__builtin_amdgcn_cvt_pk_fp8_f32)
#  define HW_FP8 1
# endif
#endif

__device__ __forceinline__ unsigned short f2bf(float f){
  unsigned int u = __float_as_uint(f);
  u += 0x7fffu + ((u >> 16) & 1u);          // RNE
  return (unsigned short)(u >> 16);
}
__device__ __forceinline__ float bfl(unsigned int v){ return __uint_as_float((v & 0xffffu) << 16); }
__device__ __forceinline__ float bfh(unsigned int v){ return __uint_as_float(v & 0xffff0000u); }
__device__ __forceinline__ float bf1(unsigned short v){ return __uint_as_float(((unsigned int)v) << 16); }

// ---------------- fp8 e4m3 (OCP) helpers ----------------

__device__ __forceinline__ void dec4(unsigned int v, float f[4]){
#ifdef HW_FP8
  f32x2 lo = __builtin_amdgcn_cvt_pk_f32_fp8((int)v, false);
  f32x2 hi = __builtin_amdgcn_cvt_pk_f32_fp8((int)v, true);
  f[0] = lo[0]; f[1] = lo[1]; f[2] = hi[0]; f[3] = hi[1];
#else
  #pragma unroll
  for (int k = 0; k < 4; ++k){
    unsigned b = (v >> (8 * k)) & 0xffu;
    int em = b & 0x7f;
    float m = (em < 8) ? (float)em * 0.001953125f
                       : __uint_as_float((unsigned)((((em >> 3) + 120) << 23) | ((em & 7) << 20)));
    f[k] = (b & 0x80) ? -m : m;
  }
#endif
}

#ifndef HW_FP8
__device__ __forceinline__ unsigned int enc1m(float v){
  unsigned u = __float_as_uint(v);
  unsigned s = (u >> 24) & 0x80u;
  float av = fabsf(v);
  if (!(av >= 0.0009765625f)) return s;            // underflow -> +-0
  if (av >= 448.0f) return s | 0x7eu;              // clamp to max normal
  if (av < 0.015625f){                             // denormal, step 2^-9
    int q = (int)rintf(av * 512.0f);
    return s | (unsigned)q;
  }
  unsigned au = u & 0x7fffffffu;
  au += 0x7ffffu + ((au >> 20) & 1u);              // RNE into 3-bit mantissa
  int ex = (int)(au >> 23) - 127;
  unsigned man = (au >> 20) & 7u;
  if (ex > 8) return s | 0x7eu;
  return s | (unsigned)((ex + 7) << 3) | man;
}
#endif

__device__ __forceinline__ unsigned int enc1(float v){
#ifdef HW_FP8
  return (unsigned int)__builtin_amdgcn_cvt_pk_fp8_f32(v, 0.0f, 0, false) & 0xffu;
#else
  return enc1m(v);
#endif
}

__device__ __forceinline__ unsigned int enc4(float a, float b, float c, float d){
#ifdef HW_FP8
  int lo = __builtin_amdgcn_cvt_pk_fp8_f32(a, b, 0, false);
  return (unsigned int)__builtin_amdgcn_cvt_pk_fp8_f32(c, d, lo, true);
#else
  return enc1m(a) | (enc1m(b) << 8) | (enc1m(c) << 16) | (enc1m(d) << 24);
#endif
}

// ---------------- graph build (no node-level global atomics anywhere) ----------------

__global__ __launch_bounds__(256) void k_bin1(const int* __restrict__ src, const int* __restrict__ dst,
                                              int* __restrict__ bcur, int2* __restrict__ tmp){
  __shared__ int cnt[NB];
  __shared__ int base[NB];
  __shared__ int pos[NB];
  int t = threadIdx.x;
  int e0 = blockIdx.x * CHUNK;
  int e1 = min(e0 + CHUNK, NE);
  for (int i = t; i < NB; i += 256){ cnt[i] = 0; pos[i] = 0; }
  __syncthreads();
  for (int e = e0 + t; e < e1; e += 256)
    atomicAdd(&cnt[dst[e] >> 7], 1);
  __syncthreads();
  for (int i = t; i < NB; i += 256){
    int c = cnt[i];
    base[i] = (c > 0) ? atomicAdd(&bcur[i], c) : 0;
  }
  __syncthreads();
  for (int e = e0 + t; e < e1; e += 256){
    int s = src[e], d = dst[e];
    int b = d >> 7;
    int p = b * BSL + base[b] + atomicAdd(&pos[b], 1);
    tmp[p] = make_int2(s, d);
  }
}

__global__ __launch_bounds__(256) void k_bscan(const int* __restrict__ bcur, int* __restrict__ bbase,
                                               int* __restrict__ rp){
  __shared__ int sh[256];
  int t = threadIdx.x;
  int b0 = t * 4;
  int v0 = (b0     < NB) ? bcur[b0]     : 0;
  int v1 = (b0 + 1 < NB) ? bcur[b0 + 1] : 0;
  int v2 = (b0 + 2 < NB) ? bcur[b0 + 2] : 0;
  int v3 = (b0 + 3 < NB) ? bcur[b0 + 3] : 0;
  int s = v0 + v1 + v2 + v3;
  sh[t] = s; __syncthreads();
  for (int off = 1; off < 256; off <<= 1){
    int val = sh[t];
    int add = (t >= off) ? sh[t - off] : 0;
    __syncthreads();
    sh[t] = val + add;
    __syncthreads();
  }
  int excl = sh[t] - s;
  if (b0     < NB) bbase[b0]     = excl;
  if (b0 + 1 < NB) bbase[b0 + 1] = excl + v0;
  if (b0 + 2 < NB) bbase[b0 + 2] = excl + v0 + v1;
  if (b0 + 3 < NB) bbase[b0 + 3] = excl + v0 + v1 + v2;
  if (t == 255){ bbase[NB] = sh[255]; rp[NN] = NE; }
}

__global__ __launch_bounds__(256) void k_bin2(const int2* __restrict__ tmp, const int* __restrict__ bbase,
                                              int* __restrict__ rp, float* __restrict__ dinv,
                                              int* __restrict__ cw){
  __shared__ int hist[128];
  __shared__ int cur[128];
  int b = blockIdx.x;
  int n0 = b << 7;
  int nn = min(128, NN - n0);
  int t = threadIdx.x;
  int B0 = bbase[b];
  int C  = bbase[b + 1] - B0;
  int E0 = b * BSL;
  if (t < 128) hist[t] = 0;
  __syncthreads();
  for (int e = t; e < C; e += 256)
    atomicAdd(&hist[tmp[E0 + e].y - n0], 1);
  __syncthreads();
  int val = (t < 128) ? hist[t] : 0;
  for (int off = 1; off < 128; off <<= 1){
    int add = (t < 128 && t >= off) ? hist[t - off] : 0;
    __syncthreads();
    if (t < 128) hist[t] += add;
    __syncthreads();
  }
  if (t < 128){
    int excl = hist[t] - val;
    int rpv = B0 + excl;
    cur[t] = rpv;
    if (t < nn){
      rp[n0 + t] = rpv;
      dinv[n0 + t] = rsqrtf((float)val + 1.0f);
    }
  }
  __syncthreads();
  for (int e = t; e < C; e += 256){
    int2 p = tmp[E0 + e];
    int slot = atomicAdd(&cur[p.y - n0], 1);
    cw[slot] = p.x;
  }
}

// ---------------- weight repack + gx prescale (fused) ----------------
// pack layout: idx = ((ks*(Np/16)+nt)*64 + lane)*8 + j ; element = W[ks*32+(lane>>4)*8+j][nt*16+(lane&15)]

__device__ __forceinline__ void pack1(const float* __restrict__ W, unsigned short* __restrict__ dst,
                                      int din, int dout, int Np, int idx){
  int j = idx & 7;
  int l = (idx >> 3) & 63;
  int f = idx >> 9;
  int ntiles = Np >> 4;
  int nt = f % ntiles;
  int ks = f / ntiles;
  int k = ks * 32 + (l >> 4) * 8 + j;
  int n = nt * 16 + (l & 15);
  float v = (k < din && n < dout) ? W[k * dout + n] : 0.0f;
  dst[idx] = f2bf(v);
}

__global__ __launch_bounds__(256) void k_gxpack(const float* __restrict__ x, const float* __restrict__ dinv,
                                                unsigned int* __restrict__ gx,
                                                const float* __restrict__ W1, unsigned short* __restrict__ d1,
                                                const float* __restrict__ W2, unsigned short* __restrict__ d2,
                                                const float* __restrict__ W3, unsigned short* __restrict__ d3,
                                                const float* __restrict__ W4, unsigned short* __restrict__ d4){
  if (blockIdx.x < 6250){
    int idx = blockIdx.x * 256 + threadIdx.x;   // NN*16 u32 outputs (4 fp8 each)
    if (idx >= NN * 16) return;
    int row = idx >> 4;
    int cu  = idx & 15;
    float di = dinv[row];
    float v[4];
    #pragma unroll
    for (int k = 0; k < 4; ++k){
      int c = 4 * cu + k;
      v[k] = (c < 35) ? x[row * 35 + c] * di : 0.0f;
    }
    gx[idx] = enc4(v[0], v[1], v[2], v[3]);
  } else {
    int idx = (blockIdx.x - 6250) * 256 + threadIdx.x;
    if      (idx < 22528)  pack1(W1, d1, 35, 336, 352, idx);
    else if (idx < 90112)  pack1(W2, d2, 336, 168, 192, idx - 22528);
    else if (idx < 108544) pack1(W3, d3, 168, 84, 96, idx - 90112);
    else if (idx < 114688) pack1(W4, d4, 84, 42, 64, idx - 108544);
  }
}

// ---------------- fp8-input aggregation ----------------

template<int SPB, int OUTC, int DOUT, int MODE, int OUTF8>
__global__ __launch_bounds__(256) void k_aggf8(const unsigned char* __restrict__ Pin,
                                               void* __restrict__ Hout,
                                               const int* __restrict__ rp, const int* __restrict__ cw,
                                               const float* __restrict__ dinv, const float* __restrict__ bias){
  constexpr int L  = 16;
  constexpr int U  = SPB / 4;           // u32 per row
  constexpr int CH = U / L;             // u32 chunks per lane
  constexpr int UN = (CH == 1) ? 8 : 4;
  int g = blockIdx.x * 16 + (threadIdx.x >> 4);
  int c = threadIdx.x & 15;
  if (g >= NN) return;
  int e0 = rp[g], e1 = rp[g + 1];
  const unsigned int* __restrict__ P = (const unsigned int*)Pin;

  float a[CH][4];
  {
    const unsigned int* r = P + (size_t)g * U;
    #pragma unroll
    for (int ch = 0; ch < CH; ++ch) dec4(r[ch * L + c], a[ch]);
  }

  int e = e0;
  if (e + UN <= e1){
    int s[UN];
    #pragma unroll
    for (int u = 0; u < UN; ++u) s[u] = cw[e + u];
    while (true){
      unsigned int v[UN][CH];
      #pragma unroll
      for (int u = 0; u < UN; ++u){
        const unsigned int* r = P + (size_t)s[u] * U;
        #pragma unroll
        for (int ch = 0; ch < CH; ++ch) v[u][ch] = r[ch * L + c];
      }
      int e2 = e + UN;
      bool more = (e2 + UN <= e1);
      int s2[UN];
      if (more){
        #pragma unroll
        for (int u = 0; u < UN; ++u) s2[u] = cw[e2 + u];
      }
      #pragma unroll
      for (int u = 0; u < UN; ++u){
        #pragma unroll
        for (int ch = 0; ch < CH; ++ch){
          float f[4]; dec4(v[u][ch], f);
          a[ch][0] += f[0]; a[ch][1] += f[1]; a[ch][2] += f[2]; a[ch][3] += f[3];
        }
      }
      e = e2;
      if (!more) break;
      #pragma unroll
      for (int u = 0; u < UN; ++u) s[u] = s2[u];
    }
  }
  for (; e < e1; ++e){
    const unsigned int* r = P + (size_t)cw[e] * U;
    #pragma unroll
    for (int ch = 0; ch < CH; ++ch){
      float f[4]; dec4(r[ch * L + c], f);
      a[ch][0] += f[0]; a[ch][1] += f[1]; a[ch][2] += f[2]; a[ch][3] += f[3];
    }
  }

  float di = dinv[g];
  #pragma unroll
  for (int ch = 0; ch < CH; ++ch){
    int colbase = (ch * L + c) * 4;
    float f0 = a[ch][0] * di, f1 = a[ch][1] * di, f2 = a[ch][2] * di, f3 = a[ch][3] * di;
    if (MODE >= 1){
      f0 += (colbase     < DOUT) ? bias[colbase]     : 0.0f;
      f1 += (colbase + 1 < DOUT) ? bias[colbase + 1] : 0.0f;
      f2 += (colbase + 2 < DOUT) ? bias[colbase + 2] : 0.0f;
      f3 += (colbase + 3 < DOUT) ? bias[colbase + 3] : 0.0f;
      f0 = fmaxf(f0, 0.0f); f1 = fmaxf(f1, 0.0f);
      f2 = fmaxf(f2, 0.0f); f3 = fmaxf(f3, 0.0f);
      if (MODE == 2){ f0 *= di; f1 *= di; f2 *= di; f3 *= di; }
    }
    if (colbase < OUTC){
      if (OUTF8){
        unsigned int* orow = (unsigned int*)Hout + (size_t)g * (OUTC / 4);
        orow[ch * L + c] = enc4(f0, f1, f2, f3);
      } else {
        uint2* orow = (uint2*)Hout + (size_t)g * (OUTC / 4);
        uint2 o;
        o.x = (unsigned int)f2bf(f0) | ((unsigned int)f2bf(f1) << 16);
        o.y = (unsigned int)f2bf(f2) | ((unsigned int)f2bf(f3) << 16);
        orow[ch * L + c] = o;
      }
    }
  }
}

// ---------------- fused conv1+conv2 matmul: p2 = fp8(dinv * relu(aggx*W1+b1) * W2) ----------------
// h1 tile lives only in LDS (bf16, stride 360 shorts = 720B, 16B-aligned rows).

#define SROW 360

__global__ __launch_bounds__(256) void k_conv12(const unsigned short* __restrict__ aggx,
                                                const unsigned short* __restrict__ wb1,
                                                const float* __restrict__ b1,
                                                const unsigned short* __restrict__ wb2,
                                                const float* __restrict__ dinv,
                                                unsigned char* __restrict__ p2){
  __shared__ uint4 ldsv[64 * SROW * 2 / 16];       // 46080 B
  unsigned short* h1t = (unsigned short*)ldsv;
  unsigned char*  bts = (unsigned char*)ldsv;

  int l   = threadIdx.x & 63;
  int wid = threadIdx.x >> 6;
  int wr = wid >> 1, wc = wid & 1;
  int lr = l & 15, lk = l >> 4;
  int rb = lk * 4;
  int R0 = blockIdx.x * 64;

  // ---- phase 1: h1 tile = relu(aggx[64xK64] * W1 + b1), 352 cols ----
  {
    int n0 = wc * 176;
    const short8* __restrict__ Af = (const short8*)aggx;
    const short8* __restrict__ Bf = (const short8*)wb1;
    f32x4 acc[2][11];
    #pragma unroll
    for (int m = 0; m < 2; ++m)
      #pragma unroll
      for (int t = 0; t < 11; ++t) acc[m][t] = (f32x4){0.f, 0.f, 0.f, 0.f};
    #pragma unroll
    for (int ks = 0; ks < 2; ++ks){
      short8 a0 = Af[((R0 + wr * 32      + lr) * 64 + ks * 32 + lk * 8) >> 3];
      short8 a1 = Af[((R0 + wr * 32 + 16 + lr) * 64 + ks * 32 + lk * 8) >> 3];
      const short8* bp = Bf + (ks * 22 + wc * 11) * 64 + l;
      #pragma unroll
      for (int t = 0; t < 11; ++t){
        short8 b = bp[t * 64];
        acc[0][t] = __builtin_amdgcn_mfma_f32_16x16x32_bf16(a0, b, acc[0][t], 0, 0, 0);
        acc[1][t] = __builtin_amdgcn_mfma_f32_16x16x32_bf16(a1, b, acc[1][t], 0, 0, 0);
      }
    }
    #pragma unroll
    for (int m = 0; m < 2; ++m){
      #pragma unroll
      for (int t = 0; t < 11; ++t){
        int col = n0 + t * 16 + lr;
        float bv = (col < 336) ? b1[col] : 0.0f;
        #pragma unroll
        for (int j = 0; j < 4; ++j){
          int rowl = wr * 32 + m * 16 + rb + j;
          h1t[rowl * SROW + col] = f2bf(fmaxf(acc[m][t][j] + bv, 0.0f));
        }
      }
    }
  }
  __syncthreads();

  // ---- phase 2: acc2 = h1t[64x352] * W2 (K=352, 192 cols) ----
  f32x4 acc2[2][6];
  #pragma unroll
  for (int m = 0; m < 2; ++m)
    #pragma unroll
    for (int t = 0; t < 6; ++t) acc2[m][t] = (f32x4){0.f, 0.f, 0.f, 0.f};
  {
    int n0 = wc * 96;
    const short8* __restrict__ Bf = (const short8*)wb2;
    for (int ks = 0; ks < 11; ++ks){
      short8 a0 = *(const short8*)&h1t[(wr * 32      + lr) * SROW + ks * 32 + lk * 8];
      short8 a1 = *(const short8*)&h1t[(wr * 32 + 16 + lr) * SROW + ks * 32 + lk * 8];
      const short8* bp = Bf + (ks * 12 + wc * 6) * 64 + l;
      #pragma unroll
      for (int t = 0; t < 6; ++t){
        short8 b = bp[t * 64];
        acc2[0][t] = __builtin_amdgcn_mfma_f32_16x16x32_bf16(a0, b, acc2[0][t], 0, 0, 0);
        acc2[1][t] = __builtin_amdgcn_mfma_f32_16x16x32_bf16(a1, b, acc2[1][t], 0, 0, 0);
      }
    }
  }
  __syncthreads();
  // epilogue: dinv scale -> fp8 -> LDS [64][208] -> vectorized store
  {
    int n0 = wc * 96;
    #pragma unroll
    for (int m = 0; m < 2; ++m){
      #pragma unroll
      for (int j = 0; j < 4; ++j){
        int rowl = wr * 32 + m * 16 + rb + j;
        float di = dinv[R0 + rowl];
        #pragma unroll
        for (int t = 0; t < 6; ++t)
          bts[rowl * 208 + n0 + t * 16 + lr] = (unsigned char)enc1(acc2[m][t][j] * di);
      }
    }
  }
  __syncthreads();
  for (int i = threadIdx.x; i < 768; i += 256){
    int row = i / 12, off = (i % 12) * 16;
    *(uint4*)&p2[(size_t)(R0 + row) * 192 + off] = *(const uint4*)&bts[row * 208 + off];
  }
}

// ---------------- MFMA matmul with staged fp8 epilogue: C = fp8(dinv * (A*B)) ----------------

template<int K, int NP, int SPA, int CSTB>
__global__ __launch_bounds__(256) void k_mmf8(const unsigned short* __restrict__ A,
                                              const unsigned short* __restrict__ Bp,
                                              const float* __restrict__ dinv,
                                              unsigned char* __restrict__ C){
  constexpr int NT   = NP / 16;
  constexpr int NT2  = NP / 32;
  constexpr int PSTR = CSTB + 16;
  __shared__ uint4 ctv[64 * PSTR / 16];
  unsigned char* ct = (unsigned char*)ctv;

  int l   = threadIdx.x & 63;
  int wid = threadIdx.x >> 6;
  int wr = wid >> 1, wc = wid & 1;
  int lr = l & 15, lk = l >> 4;
  int rb = lk * 4;
  int R0 = blockIdx.x * 64;
  int n0 = wc * (NP / 2);
  const short8* __restrict__ Af = (const short8*)A;
  const short8* __restrict__ Bf = (const short8*)Bp;
  f32x4 acc[2][NT2];
  #pragma unroll
  for (int m = 0; m < 2; ++m)
    #pragma unroll
    for (int t = 0; t < NT2; ++t) acc[m][t] = (f32x4){0.f, 0.f, 0.f, 0.f};

  for (int ks = 0; ks < K / 32; ++ks){
    short8 a0 = Af[((R0 + wr * 32      + lr) * SPA + ks * 32 + lk * 8) >> 3];
    short8 a1 = Af[((R0 + wr * 32 + 16 + lr) * SPA + ks * 32 + lk * 8) >> 3];
    const short8* bp = Bf + (ks * NT + (n0 >> 4)) * 64 + l;
    #pragma unroll
    for (int t = 0; t < NT2; ++t){
      short8 b = bp[t * 64];
      acc[0][t] = __builtin_amdgcn_mfma_f32_16x16x32_bf16(a0, b, acc[0][t], 0, 0, 0);
      acc[1][t] = __builtin_amdgcn_mfma_f32_16x16x32_bf16(a1, b, acc[1][t], 0, 0, 0);
    }
  }
  #pragma unroll
  for (int m = 0; m < 2; ++m){
    #pragma unroll
    for (int j = 0; j < 4; ++j){
      int rowl = wr * 32 + m * 16 + rb + j;
      float di = dinv[R0 + rowl];
      #pragma unroll
      for (int t = 0; t < NT2; ++t)
        ct[rowl * PSTR + n0 + t * 16 + lr] = (unsigned char)enc1(acc[m][t][j] * di);
    }
  }
  if (CSTB > NP){
    for (int i = threadIdx.x; i < 64 * (CSTB - NP) / 16; i += 256){
      constexpr int PQ = (CSTB - NP) / 16;
      int row = i / PQ, off = NP + (i % PQ) * 16;
      *(uint4*)&ct[row * PSTR + off] = (uint4){0, 0, 0, 0};
    }
  }
  __syncthreads();
  constexpr int RQ = CSTB / 16;
  for (int i = threadIdx.x; i < 64 * RQ; i += 256){
    int row = i / RQ, off = (i % RQ) * 16;
    *(uint4*)&C[(size_t)(R0 + row) * CSTB + off] = *(const uint4*)&ct[row * PSTR + off];
  }
}

// ---------------- final: mu/logstd matmuls + reparam + log_softmax ----------------

__global__ __launch_bounds__(256) void k_final(const unsigned short* __restrict__ aggh4,
                                               const float* __restrict__ Wmu, const float* __restrict__ bmu,
                                               const float* __restrict__ Wls, const float* __restrict__ bls,
                                               const float* __restrict__ eps, float* __restrict__ out){
  __shared__ float sWmu[42 * 21];
  __shared__ float sWls[42 * 21];
  __shared__ float sbmu[21];
  __shared__ float sbls[21];
  for (int u = threadIdx.x; u < 882; u += 256){ sWmu[u] = Wmu[u]; sWls[u] = Wls[u]; }
  if (threadIdx.x < 21){ sbmu[threadIdx.x] = bmu[threadIdx.x]; sbls[threadIdx.x] = bls[threadIdx.x]; }
  __syncthreads();

  int i = blockIdx.x * 256 + threadIdx.x;
  if (i >= NN) return;

  float mu[21], ls[21];
  #pragma unroll
  for (int j = 0; j < 21; ++j){ mu[j] = sbmu[j]; ls[j] = sbls[j]; }

  const unsigned short* arow = aggh4 + (size_t)i * 64;
  for (int k = 0; k < 42; ++k){
    float ak = bf1(arow[k]);
    #pragma unroll
    for (int j = 0; j < 21; ++j){
      mu[j] += ak * sWmu[k * 21 + j];
      ls[j] += ak * sWls[k * 21 + j];
    }
  }
  float zv[21];
  float mx = -3.4e38f;
  #pragma unroll
  for (int j = 0; j < 21; ++j){
    float l2 = fminf(ls[j], 10.0f);
    float zj = mu[j] + eps[(size_t)i * 21 + j] * __expf(l2);
    zv[j] = zj;
    mx = fmaxf(mx, zj);
  }
  float ssum = 0.f;
  #pragma unroll
  for (int j = 0; j < 21; ++j) ssum += __expf(zv[j] - mx);
  float lse = mx + __logf(ssum);
  #pragma unroll
  for (int j = 0; j < 21; ++j) out[(size_t)i * 21 + j] = zv[j] - lse;
}

// ---------------- workspace layout (bytes, 512-aligned) ----------------

constexpr size_t OFF_ROWPTR = 0;           // 401,408
constexpr size_t OFF_DINV   = 401408;      // 401,408
constexpr size_t OFF_BCUR   = 802816;      // 3,584
constexpr size_t OFF_BBASE  = 806400;      // 3,584
constexpr size_t OFF_CW     = 809984;      // 6,400,512
constexpr size_t OFF_TMP    = 7210496;     // NB*BSL*8 = 19,218,432 ; ends 26,428,928
constexpr size_t OFF_WB1    = 26429440;    // 45,056
constexpr size_t OFF_WB2    = 26474496;    // 135,168
constexpr size_t OFF_WB3    = 26609664;    // 36,864
constexpr size_t OFF_WB4    = 26646528;    // 12,288 ; ends 26,658,816
// region A: gx fp8 (gxpack->agg1) ; p2 fp8 (conv12->agg2) ; q4 fp8 (agg4->agg5)
constexpr size_t OFF_GX     = 26659328;    // MP*64   = 6,406,144
constexpr size_t OFF_P2     = 26659328;    // MP*192  = 19,218,432 ; region ends 45,877,760
constexpr size_t OFF_Q4     = 26659328;    // MP*64
constexpr size_t OFF_AGGX   = 45878272;    // MP*64*2 = 12,812,288 ; ends 58,690,560
// region B: h2 (agg2->mm3) ; aggh4 (agg5->final)
constexpr size_t OFF_H2     = 58691072;    // MP*192*2 = 38,436,864
constexpr size_t OFF_AGGH4  = 58691072;    // MP*64*2
constexpr size_t OFF_P3     = 129159168;   // MP*128 = 12,812,288 (mm3->agg3); p4 alias
constexpr size_t OFF_P4     = 129159168;   // MP*64
constexpr size_t OFF_H3     = 141971968;   // MP*96*2 = 19,218,432 ; ends 161,190,400

extern "C" void kernel_launch(void* const* d_in, const int* in_sizes, int n_in,
                              void* d_out, int out_size, void* d_ws, size_t ws_size,
                              hipStream_t stream){
  (void)in_sizes; (void)n_in; (void)out_size; (void)ws_size;
  const float* x    = (const float*)d_in[0];
  const int*   ei   = (const int*)d_in[1];
  const float* eps  = (const float*)d_in[2];
  const float* W1   = (const float*)d_in[3];  const float* b1  = (const float*)d_in[4];
  const float* W2   = (const float*)d_in[5];  const float* b2  = (const float*)d_in[6];
  const float* W3   = (const float*)d_in[7];  const float* b3  = (const float*)d_in[8];
  const float* W4   = (const float*)d_in[9];  const float* b4  = (const float*)d_in[10];
  const float* Wmu  = (const float*)d_in[11]; const float* bmu = (const float*)d_in[12];
  const float* Wls  = (const float*)d_in[13]; const float* bls = (const float*)d_in[14];

  char* ws = (char*)d_ws;
  int*   rowptr = (int*)(ws + OFF_ROWPTR);
  float* dinv   = (float*)(ws + OFF_DINV);
  int*   bcur   = (int*)(ws + OFF_BCUR);
  int*   bbase  = (int*)(ws + OFF_BBASE);
  int*   cw     = (int*)(ws + OFF_CW);
  int2*  tmp    = (int2*)(ws + OFF_TMP);
  unsigned short* wb1   = (unsigned short*)(ws + OFF_WB1);
  unsigned short* wb2   = (unsigned short*)(ws + OFF_WB2);
  unsigned short* wb3   = (unsigned short*)(ws + OFF_WB3);
  unsigned short* wb4   = (unsigned short*)(ws + OFF_WB4);
  unsigned char*  gx    = (unsigned char*)(ws + OFF_GX);
  unsigned short* aggx  = (unsigned short*)(ws + OFF_AGGX);
  unsigned char*  p2    = (unsigned char*)(ws + OFF_P2);
  unsigned short* h2    = (unsigned short*)(ws + OFF_H2);
  unsigned char*  p3    = (unsigned char*)(ws + OFF_P3);
  unsigned short* h3    = (unsigned short*)(ws + OFF_H3);
  unsigned char*  p4    = (unsigned char*)(ws + OFF_P4);
  unsigned char*  q4    = (unsigned char*)(ws + OFF_Q4);
  unsigned short* aggh4 = (unsigned short*)(ws + OFF_AGGH4);

  const int* src = ei;
  const int* dst = ei + NE;

  hipMemsetAsync(bcur, 0, NB * sizeof(int), stream);
  k_bin1 <<<196, 256, 0, stream>>>(src, dst, bcur, tmp);
  k_bscan<<<1,   256, 0, stream>>>(bcur, bbase, rowptr);
  k_bin2 <<<NB,  256, 0, stream>>>(tmp, bbase, rowptr, dinv, cw);
  k_gxpack<<<6698, 256, 0, stream>>>(x, dinv, (unsigned int*)gx,
                                     W1, wb1, W2, wb2, W3, wb3, W4, wb4);

  // conv1 aggregate, then fused conv1-matmul + conv2-matmul (h1 stays in LDS)
  k_aggf8<64, 64, 0, 0, 0><<<6250, 256, 0, stream>>>(gx, aggx, rowptr, cw, dinv, nullptr);
  k_conv12<<<1564, 256, 0, stream>>>(aggx, wb1, b1, wb2, dinv, p2);

  // conv2 aggregate: fp8 p2 -> bf16 h2
  k_aggf8<192, 192, 168, 1, 0><<<6250, 256, 0, stream>>>(p2, h2, rowptr, cw, dinv, b2);

  // conv3: matmul (staged fp8 epilogue, rows padded to 128B), aggregate
  k_mmf8<192, 96, 192, 128><<<1564, 256, 0, stream>>>(h2, wb3, dinv, p3);
  k_aggf8<128, 96, 84, 1, 0><<<6250, 256, 0, stream>>>(p3, h3, rowptr, cw, dinv, b3);

  // conv4: matmul (staged fp8 epilogue), aggregate -> q4 fp8
  k_mmf8<96, 64, 96, 64><<<1564, 256, 0, stream>>>(h3, wb4, dinv, p4);
  k_aggf8<64, 64, 42, 2, 1><<<6250, 256, 0, stream>>>(p4, q4, rowptr, cw, dinv, b4);

  // heads aggregation: fp8 q4 -> bf16 aggh4
  k_aggf8<64, 64, 0, 0, 0><<<6250, 256, 0, stream>>>(q4, aggh4, rowptr, cw, dinv, nullptr);

  k_final<<<391, 256, 0, stream>>>(aggh4, Wmu, bmu, Wls, bls, eps, (float*)d_out);
}

// Round 10
// 431.336 us; speedup vs baseline: 1.7690x; 1.0673x over previous
//
#include <hip/hip_runtime.h>

#define NN 100000
#define NE 1600000
#define MP 100096   // padded node count (multiple of 64, >= 1564*64)
#define NB 782      // ceil(NN/128) buckets of 128 nodes
#define BSL 3072    // fixed tmp slots per bucket (mean 2046, std ~45)
#define CHUNK 8192  // edges per bin1 block

typedef short  short8 __attribute__((ext_vector_type(8)));   // 8 bf16 (4 VGPRs)
typedef float  f32x4  __attribute__((ext_vector_type(4)));
typedef float  f32x2  __attribute__((ext_vector_type(2)));

#if defined(__has_builtin)
# if __has_builtin(__builtin_amdgcn_cvt_pk_f32_fp8) && __has_builtin(__builtin_amdgcn_cvt_pk_fp8_f32)
#  define HW_FP8 1
# endif
#endif

__device__ __forceinline__ unsigned short f2bf(float f){
  unsigned int u = __float_as_uint(f);
  u += 0x7fffu + ((u >> 16) & 1u);          // RNE
  return (unsigned short)(u >> 16);
}
__device__ __forceinline__ float bfl(unsigned int v){ return __uint_as_float((v & 0xffffu) << 16); }
__device__ __forceinline__ float bfh(unsigned int v){ return __uint_as_float(v & 0xffff0000u); }
__device__ __forceinline__ float bf1(unsigned short v){ return __uint_as_float(((unsigned int)v) << 16); }

// ---------------- fp8 e4m3 (OCP) helpers ----------------

__device__ __forceinline__ void dec4(unsigned int v, float f[4]){
#ifdef HW_FP8
  f32x2 lo = __builtin_amdgcn_cvt_pk_f32_fp8((int)v, false);
  f32x2 hi = __builtin_amdgcn_cvt_pk_f32_fp8((int)v, true);
  f[0] = lo[0]; f[1] = lo[1]; f[2] = hi[0]; f[3] = hi[1];
#else
  #pragma unroll
  for (int k = 0; k < 4; ++k){
    unsigned b = (v >> (8 * k)) & 0xffu;
    int em = b & 0x7f;
    float m = (em < 8) ? (float)em * 0.001953125f
                       : __uint_as_float((unsigned)((((em >> 3) + 120) << 23) | ((em & 7) << 20)));
    f[k] = (b & 0x80) ? -m : m;
  }
#endif
}

#ifndef HW_FP8
__device__ __forceinline__ unsigned int enc1m(float v){
  unsigned u = __float_as_uint(v);
  unsigned s = (u >> 24) & 0x80u;
  float av = fabsf(v);
  if (!(av >= 0.0009765625f)) return s;            // underflow -> +-0
  if (av >= 448.0f) return s | 0x7eu;              // clamp to max normal
  if (av < 0.015625f){                             // denormal, step 2^-9
    int q = (int)rintf(av * 512.0f);
    return s | (unsigned)q;
  }
  unsigned au = u & 0x7fffffffu;
  au += 0x7ffffu + ((au >> 20) & 1u);              // RNE into 3-bit mantissa
  int ex = (int)(au >> 23) - 127;
  unsigned man = (au >> 20) & 7u;
  if (ex > 8) return s | 0x7eu;
  return s | (unsigned)((ex + 7) << 3) | man;
}
#endif

__device__ __forceinline__ unsigned int enc1(float v){
#ifdef HW_FP8
  return (unsigned int)__builtin_amdgcn_cvt_pk_fp8_f32(v, 0.0f, 0, false) & 0xffu;
#else
  return enc1m(v);
#endif
}

__device__ __forceinline__ unsigned int enc4(float a, float b, float c, float d){
#ifdef HW_FP8
  int lo = __builtin_amdgcn_cvt_pk_fp8_f32(a, b, 0, false);
  return (unsigned int)__builtin_amdgcn_cvt_pk_fp8_f32(c, d, lo, true);
#else
  return enc1m(a) | (enc1m(b) << 8) | (enc1m(c) << 16) | (enc1m(d) << 24);
#endif
}

// ---------------- graph build (no node-level global atomics anywhere) ----------------
// tmp payload packed: (d&127)<<17 | s   (row-in-bucket 7b, src 17b)

__global__ __launch_bounds__(256) void k_bin1(const int* __restrict__ src, const int* __restrict__ dst,
                                              int* __restrict__ bcur, unsigned int* __restrict__ tmp){
  __shared__ int cnt[NB];
  __shared__ int base[NB];
  __shared__ int pos[NB];
  int t = threadIdx.x;
  int e0 = blockIdx.x * CHUNK;
  int e1 = min(e0 + CHUNK, NE);
  for (int i = t; i < NB; i += 256){ cnt[i] = 0; pos[i] = 0; }
  __syncthreads();
  for (int e = e0 + t; e < e1; e += 256)
    atomicAdd(&cnt[dst[e] >> 7], 1);
  __syncthreads();
  for (int i = t; i < NB; i += 256){
    int c = cnt[i];
    base[i] = (c > 0) ? atomicAdd(&bcur[i], c) : 0;
  }
  __syncthreads();
  for (int e = e0 + t; e < e1; e += 256){
    int s = src[e], d = dst[e];
    int b = d >> 7;
    int p = b * BSL + base[b] + atomicAdd(&pos[b], 1);
    tmp[p] = ((unsigned int)(d & 127) << 17) | (unsigned int)s;
  }
}

__global__ __launch_bounds__(256) void k_bscan(const int* __restrict__ bcur, int* __restrict__ bbase,
                                               int* __restrict__ rp){
  __shared__ int sh[256];
  int t = threadIdx.x;
  int b0 = t * 4;
  int v0 = (b0     < NB) ? bcur[b0]     : 0;
  int v1 = (b0 + 1 < NB) ? bcur[b0 + 1] : 0;
  int v2 = (b0 + 2 < NB) ? bcur[b0 + 2] : 0;
  int v3 = (b0 + 3 < NB) ? bcur[b0 + 3] : 0;
  int s = v0 + v1 + v2 + v3;
  sh[t] = s; __syncthreads();
  for (int off = 1; off < 256; off <<= 1){
    int val = sh[t];
    int add = (t >= off) ? sh[t - off] : 0;
    __syncthreads();
    sh[t] = val + add;
    __syncthreads();
  }
  int excl = sh[t] - s;
  if (b0     < NB) bbase[b0]     = excl;
  if (b0 + 1 < NB) bbase[b0 + 1] = excl + v0;
  if (b0 + 2 < NB) bbase[b0 + 2] = excl + v0 + v1;
  if (b0 + 3 < NB) bbase[b0 + 3] = excl + v0 + v1 + v2;
  if (t == 255){ bbase[NB] = sh[255]; rp[NN] = NE; }
}

__global__ __launch_bounds__(256) void k_bin2(const unsigned int* __restrict__ tmp, const int* __restrict__ bbase,
                                              int* __restrict__ rp, float* __restrict__ dinv,
                                              int* __restrict__ cw){
  __shared__ int hist[128];
  __shared__ int cur[128];
  int b = blockIdx.x;
  int n0 = b << 7;
  int nn = min(128, NN - n0);
  int t = threadIdx.x;
  int B0 = bbase[b];
  int C  = bbase[b + 1] - B0;
  int E0 = b * BSL;
  if (t < 128) hist[t] = 0;
  __syncthreads();
  for (int e = t; e < C; e += 256)
    atomicAdd(&hist[tmp[E0 + e] >> 17], 1);
  __syncthreads();
  int val = (t < 128) ? hist[t] : 0;
  for (int off = 1; off < 128; off <<= 1){
    int add = (t < 128 && t >= off) ? hist[t - off] : 0;
    __syncthreads();
    if (t < 128) hist[t] += add;
    __syncthreads();
  }
  if (t < 128){
    int excl = hist[t] - val;
    int rpv = B0 + excl;
    cur[t] = rpv;
    if (t < nn){
      rp[n0 + t] = rpv;
      dinv[n0 + t] = rsqrtf((float)val + 1.0f);
    }
  }
  __syncthreads();
  for (int e = t; e < C; e += 256){
    unsigned int v = tmp[E0 + e];
    int slot = atomicAdd(&cur[v >> 17], 1);
    cw[slot] = (int)(v & 0x1ffffu);
  }
}

// ---------------- weight repack + gx prescale (fused) ----------------
// pack layout: idx = ((ks*(Np/16)+nt)*64 + lane)*8 + j ; element = W[ks*32+(lane>>4)*8+j][nt*16+(lane&15)]

__device__ __forceinline__ void pack1(const float* __restrict__ W, unsigned short* __restrict__ dst,
                                      int din, int dout, int Np, int idx){
  int j = idx & 7;
  int l = (idx >> 3) & 63;
  int f = idx >> 9;
  int ntiles = Np >> 4;
  int nt = f % ntiles;
  int ks = f / ntiles;
  int k = ks * 32 + (l >> 4) * 8 + j;
  int n = nt * 16 + (l & 15);
  float v = (k < din && n < dout) ? W[k * dout + n] : 0.0f;
  dst[idx] = f2bf(v);
}

__global__ __launch_bounds__(256) void k_gxpack(const float* __restrict__ x, const float* __restrict__ dinv,
                                                unsigned int* __restrict__ gx,
                                                const float* __restrict__ W1, unsigned short* __restrict__ d1,
                                                const float* __restrict__ W2, unsigned short* __restrict__ d2,
                                                const float* __restrict__ W3, unsigned short* __restrict__ d3,
                                                const float* __restrict__ W4, unsigned short* __restrict__ d4){
  if (blockIdx.x < 6250){
    int idx = blockIdx.x * 256 + threadIdx.x;   // NN*16 u32 outputs (4 fp8 each)
    if (idx >= NN * 16) return;
    int row = idx >> 4;
    int cu  = idx & 15;
    float di = dinv[row];
    float v[4];
    #pragma unroll
    for (int k = 0; k < 4; ++k){
      int c = 4 * cu + k;
      v[k] = (c < 35) ? x[row * 35 + c] * di : 0.0f;
    }
    gx[idx] = enc4(v[0], v[1], v[2], v[3]);
  } else {
    int idx = (blockIdx.x - 6250) * 256 + threadIdx.x;
    if      (idx < 22528)  pack1(W1, d1, 35, 336, 352, idx);
    else if (idx < 90112)  pack1(W2, d2, 336, 168, 192, idx - 22528);
    else if (idx < 108544) pack1(W3, d3, 168, 84, 96, idx - 90112);
    else if (idx < 114688) pack1(W4, d4, 84, 42, 64, idx - 108544);
  }
}

// ---------------- fp8-input aggregation ----------------

template<int SPB, int OUTC, int DOUT, int MODE, int OUTF8>
__global__ __launch_bounds__(256) void k_aggf8(const unsigned char* __restrict__ Pin,
                                               void* __restrict__ Hout,
                                               const int* __restrict__ rp, const int* __restrict__ cw,
                                               const float* __restrict__ dinv, const float* __restrict__ bias){
  constexpr int L  = 16;
  constexpr int U  = SPB / 4;           // u32 per row
  constexpr int CH = U / L;             // u32 chunks per lane
  constexpr int UN = (CH == 1) ? 8 : 4;
  int g = blockIdx.x * 16 + (threadIdx.x >> 4);
  int c = threadIdx.x & 15;
  if (g >= NN) return;
  int e0 = rp[g], e1 = rp[g + 1];
  const unsigned int* __restrict__ P = (const unsigned int*)Pin;

  float a[CH][4];
  {
    const unsigned int* r = P + (size_t)g * U;
    #pragma unroll
    for (int ch = 0; ch < CH; ++ch) dec4(r[ch * L + c], a[ch]);
  }

  int e = e0;
  if (e + UN <= e1){
    int s[UN];
    #pragma unroll
    for (int u = 0; u < UN; ++u) s[u] = cw[e + u];
    while (true){
      unsigned int v[UN][CH];
      #pragma unroll
      for (int u = 0; u < UN; ++u){
        const unsigned int* r = P + (size_t)s[u] * U;
        #pragma unroll
        for (int ch = 0; ch < CH; ++ch) v[u][ch] = r[ch * L + c];
      }
      int e2 = e + UN;
      bool more = (e2 + UN <= e1);
      int s2[UN];
      if (more){
        #pragma unroll
        for (int u = 0; u < UN; ++u) s2[u] = cw[e2 + u];
      }
      #pragma unroll
      for (int u = 0; u < UN; ++u){
        #pragma unroll
        for (int ch = 0; ch < CH; ++ch){
          float f[4]; dec4(v[u][ch], f);
          a[ch][0] += f[0]; a[ch][1] += f[1]; a[ch][2] += f[2]; a[ch][3] += f[3];
        }
      }
      e = e2;
      if (!more) break;
      #pragma unroll
      for (int u = 0; u < UN; ++u) s[u] = s2[u];
    }
  }
  for (; e < e1; ++e){
    const unsigned int* r = P + (size_t)cw[e] * U;
    #pragma unroll
    for (int ch = 0; ch < CH; ++ch){
      float f[4]; dec4(r[ch * L + c], f);
      a[ch][0] += f[0]; a[ch][1] += f[1]; a[ch][2] += f[2]; a[ch][3] += f[3];
    }
  }

  float di = dinv[g];
  #pragma unroll
  for (int ch = 0; ch < CH; ++ch){
    int colbase = (ch * L + c) * 4;
    float f0 = a[ch][0] * di, f1 = a[ch][1] * di, f2 = a[ch][2] * di, f3 = a[ch][3] * di;
    if (MODE >= 1){
      f0 += (colbase     < DOUT) ? bias[colbase]     : 0.0f;
      f1 += (colbase + 1 < DOUT) ? bias[colbase + 1] : 0.0f;
      f2 += (colbase + 2 < DOUT) ? bias[colbase + 2] : 0.0f;
      f3 += (colbase + 3 < DOUT) ? bias[colbase + 3] : 0.0f;
      f0 = fmaxf(f0, 0.0f); f1 = fmaxf(f1, 0.0f);
      f2 = fmaxf(f2, 0.0f); f3 = fmaxf(f3, 0.0f);
      if (MODE == 2){ f0 *= di; f1 *= di; f2 *= di; f3 *= di; }
    }
    if (colbase < OUTC){
      if (OUTF8){
        unsigned int* orow = (unsigned int*)Hout + (size_t)g * (OUTC / 4);
        orow[ch * L + c] = enc4(f0, f1, f2, f3);
      } else {
        uint2* orow = (uint2*)Hout + (size_t)g * (OUTC / 4);
        uint2 o;
        o.x = (unsigned int)f2bf(f0) | ((unsigned int)f2bf(f1) << 16);
        o.y = (unsigned int)f2bf(f2) | ((unsigned int)f2bf(f3) << 16);
        orow[ch * L + c] = o;
      }
    }
  }
}

// ---------------- fused conv1+conv2 matmul, BM=32: p2 = fp8(dinv * relu(aggx*W1+b1) * W2) ----------------
// h1 tile (32x352) lives only in LDS. 23,040 B -> up to 7 blocks/CU by LDS.

#define SROW 360

__global__ __launch_bounds__(256) void k_conv12(const unsigned short* __restrict__ aggx,
                                                const unsigned short* __restrict__ wb1,
                                                const float* __restrict__ b1,
                                                const unsigned short* __restrict__ wb2,
                                                const float* __restrict__ dinv,
                                                unsigned char* __restrict__ p2){
  __shared__ uint4 ldsv[32 * SROW * 2 / 16];       // 23040 B
  unsigned short* h1t = (unsigned short*)ldsv;
  unsigned char*  bts = (unsigned char*)ldsv;

  int l   = threadIdx.x & 63;
  int wid = threadIdx.x >> 6;
  int wr = wid >> 1, wc = wid & 1;     // wr: 16-row half, wc: col half
  int lr = l & 15, lk = l >> 4;
  int rb = lk * 4;
  int R0 = blockIdx.x * 32;

  // ---- phase 1: h1 tile = relu(aggx[32xK64] * W1 + b1), 352 cols ----
  {
    const short8* __restrict__ Af = (const short8*)aggx;
    const short8* __restrict__ Bf = (const short8*)wb1;
    f32x4 acc[11];
    #pragma unroll
    for (int t = 0; t < 11; ++t) acc[t] = (f32x4){0.f, 0.f, 0.f, 0.f};
    #pragma unroll
    for (int ks = 0; ks < 2; ++ks){
      short8 a0 = Af[((R0 + wr * 16 + lr) * 64 + ks * 32 + lk * 8) >> 3];
      const short8* bp = Bf + (ks * 22 + wc * 11) * 64 + l;
      #pragma unroll
      for (int t = 0; t < 11; ++t)
        acc[t] = __builtin_amdgcn_mfma_f32_16x16x32_bf16(a0, bp[t * 64], acc[t], 0, 0, 0);
    }
    #pragma unroll
    for (int t = 0; t < 11; ++t){
      int col = wc * 176 + t * 16 + lr;
      float bv = (col < 336) ? b1[col] : 0.0f;
      #pragma unroll
      for (int j = 0; j < 4; ++j)
        h1t[(wr * 16 + rb + j) * SROW + col] = f2bf(fmaxf(acc[t][j] + bv, 0.0f));
    }
  }
  __syncthreads();

  // ---- phase 2: acc2 = h1t[32x352] * W2 (K=352, 192 cols) ----
  f32x4 acc2[6];
  #pragma unroll
  for (int t = 0; t < 6; ++t) acc2[t] = (f32x4){0.f, 0.f, 0.f, 0.f};
  {
    const short8* __restrict__ Bf = (const short8*)wb2;
    for (int ks = 0; ks < 11; ++ks){
      short8 a0 = *(const short8*)&h1t[(wr * 16 + lr) * SROW + ks * 32 + lk * 8];
      const short8* bp = Bf + (ks * 12 + wc * 6) * 64 + l;
      #pragma unroll
      for (int t = 0; t < 6; ++t)
        acc2[t] = __builtin_amdgcn_mfma_f32_16x16x32_bf16(a0, bp[t * 64], acc2[t], 0, 0, 0);
    }
  }
  __syncthreads();
  // epilogue: dinv scale -> fp8 -> LDS [32][208] -> vectorized store
  #pragma unroll
  for (int j = 0; j < 4; ++j){
    int rowl = wr * 16 + rb + j;
    float di = dinv[R0 + rowl];
    #pragma unroll
    for (int t = 0; t < 6; ++t)
      bts[rowl * 208 + wc * 96 + t * 16 + lr] = (unsigned char)enc1(acc2[t][j] * di);
  }
  __syncthreads();
  for (int i = threadIdx.x; i < 384; i += 256){
    int row = i / 12, off = (i % 12) * 16;
    *(uint4*)&p2[(size_t)(R0 + row) * 192 + off] = *(const uint4*)&bts[row * 208 + off];
  }
}

// ---------------- MFMA matmul with staged fp8 epilogue: C = fp8(dinv * (A*B)) ----------------

template<int K, int NP, int SPA, int CSTB>
__global__ __launch_bounds__(256) void k_mmf8(const unsigned short* __restrict__ A,
                                              const unsigned short* __restrict__ Bp,
                                              const float* __restrict__ dinv,
                                              unsigned char* __restrict__ C){
  constexpr int NT   = NP / 16;
  constexpr int NT2  = NP / 32;
  constexpr int PSTR = CSTB + 16;
  __shared__ uint4 ctv[64 * PSTR / 16];
  unsigned char* ct = (unsigned char*)ctv;

  int l   = threadIdx.x & 63;
  int wid = threadIdx.x >> 6;
  int wr = wid >> 1, wc = wid & 1;
  int lr = l & 15, lk = l >> 4;
  int rb = lk * 4;
  int R0 = blockIdx.x * 64;
  int n0 = wc * (NP / 2);
  const short8* __restrict__ Af = (const short8*)A;
  const short8* __restrict__ Bf = (const short8*)Bp;
  f32x4 acc[2][NT2];
  #pragma unroll
  for (int m = 0; m < 2; ++m)
    #pragma unroll
    for (int t = 0; t < NT2; ++t) acc[m][t] = (f32x4){0.f, 0.f, 0.f, 0.f};

  for (int ks = 0; ks < K / 32; ++ks){
    short8 a0 = Af[((R0 + wr * 32      + lr) * SPA + ks * 32 + lk * 8) >> 3];
    short8 a1 = Af[((R0 + wr * 32 + 16 + lr) * SPA + ks * 32 + lk * 8) >> 3];
    const short8* bp = Bf + (ks * NT + (n0 >> 4)) * 64 + l;
    #pragma unroll
    for (int t = 0; t < NT2; ++t){
      short8 b = bp[t * 64];
      acc[0][t] = __builtin_amdgcn_mfma_f32_16x16x32_bf16(a0, b, acc[0][t], 0, 0, 0);
      acc[1][t] = __builtin_amdgcn_mfma_f32_16x16x32_bf16(a1, b, acc[1][t], 0, 0, 0);
    }
  }
  #pragma unroll
  for (int m = 0; m < 2; ++m){
    #pragma unroll
    for (int j = 0; j < 4; ++j){
      int rowl = wr * 32 + m * 16 + rb + j;
      float di = dinv[R0 + rowl];
      #pragma unroll
      for (int t = 0; t < NT2; ++t)
        ct[rowl * PSTR + n0 + t * 16 + lr] = (unsigned char)enc1(acc[m][t][j] * di);
    }
  }
  if (CSTB > NP){
    for (int i = threadIdx.x; i < 64 * (CSTB - NP) / 16; i += 256){
      constexpr int PQ = (CSTB - NP) / 16;
      int row = i / PQ, off = NP + (i % PQ) * 16;
      *(uint4*)&ct[row * PSTR + off] = (uint4){0, 0, 0, 0};
    }
  }
  __syncthreads();
  constexpr int RQ = CSTB / 16;
  for (int i = threadIdx.x; i < 64 * RQ; i += 256){
    int row = i / RQ, off = (i % RQ) * 16;
    *(uint4*)&C[(size_t)(R0 + row) * CSTB + off] = *(const uint4*)&ct[row * PSTR + off];
  }
}

// ---------------- final: mu/logstd matmuls + reparam + log_softmax ----------------

__global__ __launch_bounds__(256) void k_final(const unsigned short* __restrict__ aggh4,
                                               const float* __restrict__ Wmu, const float* __restrict__ bmu,
                                               const float* __restrict__ Wls, const float* __restrict__ bls,
                                               const float* __restrict__ eps, float* __restrict__ out){
  __shared__ float sWmu[42 * 21];
  __shared__ float sWls[42 * 21];
  __shared__ float sbmu[21];
  __shared__ float sbls[21];
  for (int u = threadIdx.x; u < 882; u += 256){ sWmu[u] = Wmu[u]; sWls[u] = Wls[u]; }
  if (threadIdx.x < 21){ sbmu[threadIdx.x] = bmu[threadIdx.x]; sbls[threadIdx.x] = bls[threadIdx.x]; }
  __syncthreads();

  int i = blockIdx.x * 256 + threadIdx.x;
  if (i >= NN) return;

  float mu[21], ls[21];
  #pragma unroll
  for (int j = 0; j < 21; ++j){ mu[j] = sbmu[j]; ls[j] = sbls[j]; }

  const unsigned short* arow = aggh4 + (size_t)i * 64;
  for (int k = 0; k < 42; ++k){
    float ak = bf1(arow[k]);
    #pragma unroll
    for (int j = 0; j < 21; ++j){
      mu[j] += ak * sWmu[k * 21 + j];
      ls[j] += ak * sWls[k * 21 + j];
    }
  }
  float zv[21];
  float mx = -3.4e38f;
  #pragma unroll
  for (int j = 0; j < 21; ++j){
    float l2 = fminf(ls[j], 10.0f);
    float zj = mu[j] + eps[(size_t)i * 21 + j] * __expf(l2);
    zv[j] = zj;
    mx = fmaxf(mx, zj);
  }
  float ssum = 0.f;
  #pragma unroll
  for (int j = 0; j < 21; ++j) ssum += __expf(zv[j] - mx);
  float lse = mx + __logf(ssum);
  #pragma unroll
  for (int j = 0; j < 21; ++j) out[(size_t)i * 21 + j] = zv[j] - lse;
}

// ---------------- workspace layout (bytes, 512-aligned) ----------------

constexpr size_t OFF_ROWPTR = 0;           // 401,408
constexpr size_t OFF_DINV   = 401408;      // 401,408
constexpr size_t OFF_BCUR   = 802816;      // 3,584
constexpr size_t OFF_BBASE  = 806400;      // 3,584
constexpr size_t OFF_CW     = 809984;      // 6,400,512
constexpr size_t OFF_TMP    = 7210496;     // NB*BSL*4 = 9,609,216 (u32 packed)
constexpr size_t OFF_WB1    = 26429440;    // 45,056
constexpr size_t OFF_WB2    = 26474496;    // 135,168
constexpr size_t OFF_WB3    = 26609664;    // 36,864
constexpr size_t OFF_WB4    = 26646528;    // 12,288 ; ends 26,658,816
// region A: gx fp8 (gxpack->agg1) ; p2 fp8 (conv12->agg2) ; q4 fp8 (agg4->agg5)
constexpr size_t OFF_GX     = 26659328;    // MP*64   = 6,406,144
constexpr size_t OFF_P2     = 26659328;    // MP*192  = 19,218,432 ; region ends 45,877,760
constexpr size_t OFF_Q4     = 26659328;    // MP*64
constexpr size_t OFF_AGGX   = 45878272;    // MP*64*2 = 12,812,288 ; ends 58,690,560
// region B: h2 (agg2->mm3) ; aggh4 (agg5->final)
constexpr size_t OFF_H2     = 58691072;    // MP*192*2 = 38,436,864
constexpr size_t OFF_AGGH4  = 58691072;    // MP*64*2
constexpr size_t OFF_P3     = 129159168;   // MP*128 = 12,812,288 (mm3->agg3); p4 alias
constexpr size_t OFF_P4     = 129159168;   // MP*64
constexpr size_t OFF_H3     = 141971968;   // MP*96*2 = 19,218,432 ; ends 161,190,400

extern "C" void kernel_launch(void* const* d_in, const int* in_sizes, int n_in,
                              void* d_out, int out_size, void* d_ws, size_t ws_size,
                              hipStream_t stream){
  (void)in_sizes; (void)n_in; (void)out_size; (void)ws_size;
  const float* x    = (const float*)d_in[0];
  const int*   ei   = (const int*)d_in[1];
  const float* eps  = (const float*)d_in[2];
  const float* W1   = (const float*)d_in[3];  const float* b1  = (const float*)d_in[4];
  const float* W2   = (const float*)d_in[5];  const float* b2  = (const float*)d_in[6];
  const float* W3   = (const float*)d_in[7];  const float* b3  = (const float*)d_in[8];
  const float* W4   = (const float*)d_in[9];  const float* b4  = (const float*)d_in[10];
  const float* Wmu  = (const float*)d_in[11]; const float* bmu = (const float*)d_in[12];
  const float* Wls  = (const float*)d_in[13]; const float* bls = (const float*)d_in[14];

  char* ws = (char*)d_ws;
  int*   rowptr = (int*)(ws + OFF_ROWPTR);
  float* dinv   = (float*)(ws + OFF_DINV);
  int*   bcur   = (int*)(ws + OFF_BCUR);
  int*   bbase  = (int*)(ws + OFF_BBASE);
  int*   cw     = (int*)(ws + OFF_CW);
  unsigned int* tmp = (unsigned int*)(ws + OFF_TMP);
  unsigned short* wb1   = (unsigned short*)(ws + OFF_WB1);
  unsigned short* wb2   = (unsigned short*)(ws + OFF_WB2);
  unsigned short* wb3   = (unsigned short*)(ws + OFF_WB3);
  unsigned short* wb4   = (unsigned short*)(ws + OFF_WB4);
  unsigned char*  gx    = (unsigned char*)(ws + OFF_GX);
  unsigned short* aggx  = (unsigned short*)(ws + OFF_AGGX);
  unsigned char*  p2    = (unsigned char*)(ws + OFF_P2);
  unsigned short* h2    = (unsigned short*)(ws + OFF_H2);
  unsigned char*  p3    = (unsigned char*)(ws + OFF_P3);
  unsigned short* h3    = (unsigned short*)(ws + OFF_H3);
  unsigned char*  p4    = (unsigned char*)(ws + OFF_P4);
  unsigned char*  q4    = (unsigned char*)(ws + OFF_Q4);
  unsigned short* aggh4 = (unsigned short*)(ws + OFF_AGGH4);

  const int* src = ei;
  const int* dst = ei + NE;

  hipMemsetAsync(bcur, 0, NB * sizeof(int), stream);
  k_bin1 <<<196, 256, 0, stream>>>(src, dst, bcur, tmp);
  k_bscan<<<1,   256, 0, stream>>>(bcur, bbase, rowptr);
  k_bin2 <<<NB,  256, 0, stream>>>(tmp, bbase, rowptr, dinv, cw);
  k_gxpack<<<6698, 256, 0, stream>>>(x, dinv, (unsigned int*)gx,
                                     W1, wb1, W2, wb2, W3, wb3, W4, wb4);

  // conv1 aggregate, then fused conv1-matmul + conv2-matmul (h1 stays in LDS, BM=32)
  k_aggf8<64, 64, 0, 0, 0><<<6250, 256, 0, stream>>>(gx, aggx, rowptr, cw, dinv, nullptr);
  k_conv12<<<3128, 256, 0, stream>>>(aggx, wb1, b1, wb2, dinv, p2);

  // conv2 aggregate: fp8 p2 -> bf16 h2
  k_aggf8<192, 192, 168, 1, 0><<<6250, 256, 0, stream>>>(p2, h2, rowptr, cw, dinv, b2);

  // conv3: matmul (staged fp8 epilogue, rows padded to 128B), aggregate
  k_mmf8<192, 96, 192, 128><<<1564, 256, 0, stream>>>(h2, wb3, dinv, p3);
  k_aggf8<128, 96, 84, 1, 0><<<6250, 256, 0, stream>>>(p3, h3, rowptr, cw, dinv, b3);

  // conv4: matmul (staged fp8 epilogue), aggregate -> q4 fp8
  k_mmf8<96, 64, 96, 64><<<1564, 256, 0, stream>>>(h3, wb4, dinv, p4);
  k_aggf8<64, 64, 42, 2, 1><<<6250, 256, 0, stream>>>(p4, q4, rowptr, cw, dinv, b4);

  // heads aggregation: fp8 q4 -> bf16 aggh4
  k_aggf8<64, 64, 0, 0, 0><<<6250, 256, 0, stream>>>(q4, aggh4, rowptr, cw, dinv, nullptr);

  k_final<<<391, 256, 0, stream>>>(aggh4, Wmu, bmu, Wls, bls, eps, (float*)d_out);
}